// Round 1
// 1790.537 us; speedup vs baseline: 1.1571x; 1.1571x over previous
//
#include <hip/hip_runtime.h>
#include <math.h>

// ---------------- problem constants ----------------
#define BB 2
#define D_ 384
#define H_ 12
#define HD 32
#define NIN 4096            // 64*64
#define NOUT 484            // 22*22
#define MOUT (BB*NOUT)      // 968
#define MIN_ (BB*NIN)       // 8192
#define QW_ 22
#define CK 18816            // D*7*7
#define NSLICE 49           // conv split-K: one slice per (ky,kx), K=384 each
#define LN_EPS 1e-5f
#define EPS_ 1.1920929e-07f

typedef short bf16x8 __attribute__((ext_vector_type(8)));
typedef float f32x4  __attribute__((ext_vector_type(4)));

__device__ __forceinline__ unsigned f2bf(float f){   // RNE fp32->bf16 bits
  unsigned u = __float_as_uint(f);
  u += 0x7fffu + ((u>>16)&1u);
  return u>>16;
}

// ---------------- ws layout (floats) ----------------
static const size_t OXOUT = 0;                     // 968*384 = 371712
static const size_t OKB   = 371712;                // K bf16: 24*4096*32 ush = 1572864 f
static const size_t OVH   = OKB + 1572864;         // V fp32: 24*4096*32   = 3145728 f
static const size_t OQB   = OVH + 3145728;         // Q bf16: 24*512*32 ush = 196608 f
static const size_t OQP   = OQB + 196608;          // 371712
static const size_t OL0   = OQP + 371712;          // 24*512 = 12288
static const size_t OCS   = OL0 + 12288;           // 24*4096 = 98304
static const size_t OLP   = OCS + 98304;           // l0 partials 24*512*16 = 196608
static const size_t OUPD  = OLP + 196608;          // 371712
static const size_t OH1   = OUPD + 371712;         // 1486848
static const size_t OH2   = OH1 + 1486848;         // 371712
static const size_t OQWB  = OH2 + 371712;          // 384*384 bf16   = 73728 f
static const size_t OW1B  = OQWB + 73728;          // 384*1536 bf16  = 294912 f
static const size_t OW2B  = OW1B + 294912;         // 1536*384 bf16  = 294912 f
// total = 8,859,648 floats = 35.4 MB (< previous 41.6 MB)

// ---------------- packing kernels ----------------
__global__ __launch_bounds__(256)
void packxk(const float* __restrict__ x, ushort* __restrict__ xb){
  int i = blockIdx.x*256 + threadIdx.x;           // one float4 per thread
  int base = i*4;
  if (base >= MIN_*D_) return;
  float4 v = *(const float4*)(x + base);
  uint2 o;
  o.x = f2bf(v.x) | (f2bf(v.y)<<16);
  o.y = f2bf(v.z) | (f2bf(v.w)<<16);
  *(uint2*)(xb + base) = o;
}

// conv_w [n][di][ky][kx] -> Wtb[kyx][n][di] (bf16)
__global__ __launch_bounds__(256)
void wtk2(const float* __restrict__ cw, ushort* __restrict__ wtb){
  int i = blockIdx.x*256 + threadIdx.x;
  if (i >= CK*D_) return;
  int n = i / CK;
  int r = i - n*CK;           // di*49 + kyx
  int di = r/49, kyx = r - di*49;
  wtb[((size_t)kyx*D_ + n)*D_ + di] = (ushort)f2bf(cw[i]);
}

// w[k][n] fp32 -> wb[n][k] bf16
__global__ __launch_bounds__(256)
void packwk(const float* __restrict__ w, ushort* __restrict__ wb, int K, int N){
  int i = blockIdx.x*256 + threadIdx.x;
  if (i >= K*N) return;
  int k = i / N, n = i - k*N;
  wb[(size_t)n*K + k] = (ushort)f2bf(w[i]);
}

// -------- MFMA conv: per-slice GEMM, 128x128 tile, 4 waves x (4x4) 16x16x32 --------
__global__ __launch_bounds__(256)
void convm(const ushort* __restrict__ xb, const ushort* __restrict__ wtb,
           float* __restrict__ part){
  __shared__ ushort As[128][40];
  __shared__ ushort Bs[128][40];
  const int t  = threadIdx.x;
  const int m0 = blockIdx.x*128, n0 = blockIdx.y*128, z = blockIdx.z;
  const int ky = z/7, kx = z - ky*7;
  const int r = t>>1, half = t&1;
  const int m = m0 + r;
  const int mq = (m < MOUT) ? m : 0;
  const int bbv = mq/NOUT, qq = mq - bbv*NOUT;
  const int oy = qq/QW_, ox = qq - oy*QW_;
  const int iy = oy*3-3+ky, ix = ox*3-3+kx;
  const bool aval = (m<MOUT) && iy>=0 && iy<64 && ix>=0 && ix<64;
  const ushort* asrc = xb + ((size_t)bbv*NIN + (aval ? iy*64+ix : 0))*D_ + half*16;
  const ushort* bsrc = wtb + ((size_t)z*D_ + n0 + r)*D_ + half*16;

  const int wv = t>>6;
  const int wr = (wv>>1)*64, wc = (wv&1)*64;
  const int ln = t&15, lq = (t>>4)&3;

  f32x4 acc[4][4];
#pragma unroll
  for (int i=0;i<4;i++)
#pragma unroll
    for (int j=0;j<4;j++) acc[i][j] = (f32x4){0.f,0.f,0.f,0.f};

  for (int dk=0; dk<D_; dk+=32){
    uint4 a0 = {0,0,0,0}, a1 = {0,0,0,0};
    if (aval){ a0 = *(const uint4*)(asrc+dk); a1 = *(const uint4*)(asrc+dk+8); }
    uint4 b0 = *(const uint4*)(bsrc+dk), b1 = *(const uint4*)(bsrc+dk+8);
    *(uint4*)&As[r][half*16]   = a0;  *(uint4*)&As[r][half*16+8] = a1;
    *(uint4*)&Bs[r][half*16]   = b0;  *(uint4*)&Bs[r][half*16+8] = b1;
    __syncthreads();
    bf16x8 af[4], bfr[4];
#pragma unroll
    for (int i=0;i<4;i++) af[i]  = *(const bf16x8*)&As[wr+i*16+ln][lq*8];
#pragma unroll
    for (int j=0;j<4;j++) bfr[j] = *(const bf16x8*)&Bs[wc+j*16+ln][lq*8];
#pragma unroll
    for (int i=0;i<4;i++)
#pragma unroll
      for (int j=0;j<4;j++)
        acc[i][j] = __builtin_amdgcn_mfma_f32_16x16x32_bf16(af[i], bfr[j], acc[i][j], 0,0,0);
    __syncthreads();
  }
#pragma unroll
  for (int i=0;i<4;i++){
    int rowb = m0 + wr + i*16 + lq*4;
#pragma unroll
    for (int j=0;j<4;j++){
      int col = n0 + wc + j*16 + ln;
#pragma unroll
      for (int rg=0; rg<4; rg++){
        int row = rowb + rg;
        if (row < MOUT) part[((size_t)z*MOUT + row)*D_ + col] = acc[i][j][rg];
      }
    }
  }
}

// -------- MFMA GEMM: C = A[M,K]*W[K,N] + bias, W pre-packed as Wb[n][k] bf16 -----
template<int ACT, bool ABF>
__global__ __launch_bounds__(256)
void gemmm(const void* __restrict__ Ain, const ushort* __restrict__ Wb,
           const float* __restrict__ bias, float* __restrict__ C,
           int M, int N, int K){
  __shared__ ushort As[128][40];
  __shared__ ushort Bs[128][40];
  const int t  = threadIdx.x;
  const int m0 = blockIdx.x*128, n0 = blockIdx.y*128;
  const int r = t>>1, half = t&1;
  const int m = m0 + r;
  const bool aval = (m < M);
  const float*  af32 = (const float*)Ain  + (size_t)(aval?m:0)*K + half*16;
  const ushort* ab16 = (const ushort*)Ain + (size_t)(aval?m:0)*K + half*16;
  const ushort* bsrc = Wb + (size_t)(n0 + r)*K + half*16;

  const int wv = t>>6;
  const int wr = (wv>>1)*64, wc = (wv&1)*64;
  const int ln = t&15, lq = (t>>4)&3;

  f32x4 acc[4][4];
#pragma unroll
  for (int i=0;i<4;i++)
#pragma unroll
    for (int j=0;j<4;j++) acc[i][j] = (f32x4){0.f,0.f,0.f,0.f};

  for (int dk=0; dk<K; dk+=32){
    uint4 a0 = {0,0,0,0}, a1 = {0,0,0,0};
    if (aval){
      if (ABF){
        a0 = *(const uint4*)(ab16+dk); a1 = *(const uint4*)(ab16+dk+8);
      } else {
        float4 f0 = *(const float4*)(af32+dk),   f1 = *(const float4*)(af32+dk+4);
        float4 f2 = *(const float4*)(af32+dk+8), f3 = *(const float4*)(af32+dk+12);
        a0.x = f2bf(f0.x)|(f2bf(f0.y)<<16); a0.y = f2bf(f0.z)|(f2bf(f0.w)<<16);
        a0.z = f2bf(f1.x)|(f2bf(f1.y)<<16); a0.w = f2bf(f1.z)|(f2bf(f1.w)<<16);
        a1.x = f2bf(f2.x)|(f2bf(f2.y)<<16); a1.y = f2bf(f2.z)|(f2bf(f2.w)<<16);
        a1.z = f2bf(f3.x)|(f2bf(f3.y)<<16); a1.w = f2bf(f3.z)|(f2bf(f3.w)<<16);
      }
    }
    uint4 b0 = *(const uint4*)(bsrc+dk), b1 = *(const uint4*)(bsrc+dk+8);
    *(uint4*)&As[r][half*16]   = a0;  *(uint4*)&As[r][half*16+8] = a1;
    *(uint4*)&Bs[r][half*16]   = b0;  *(uint4*)&Bs[r][half*16+8] = b1;
    __syncthreads();
    bf16x8 af[4], bfr[4];
#pragma unroll
    for (int i=0;i<4;i++) af[i]  = *(const bf16x8*)&As[wr+i*16+ln][lq*8];
#pragma unroll
    for (int j=0;j<4;j++) bfr[j] = *(const bf16x8*)&Bs[wc+j*16+ln][lq*8];
#pragma unroll
    for (int i=0;i<4;i++)
#pragma unroll
      for (int j=0;j<4;j++)
        acc[i][j] = __builtin_amdgcn_mfma_f32_16x16x32_bf16(af[i], bfr[j], acc[i][j], 0,0,0);
    __syncthreads();
  }
#pragma unroll
  for (int i=0;i<4;i++){
    int rowb = m0 + wr + i*16 + lq*4;
#pragma unroll
    for (int j=0;j<4;j++){
      int col = n0 + wc + j*16 + ln;
      float bv = bias[col];
#pragma unroll
      for (int rg=0; rg<4; rg++){
        int row = rowb + rg;
        if (row < M){
          float v = acc[i][j][rg] + bv;
          if (ACT==1) v = 0.5f*v*(1.f + erff(v*0.7071067811865475f));
          C[(size_t)row*N + col] = v;
        }
      }
    }
  }
}

// ---------------- block reduction over 384 threads --------------------------
__device__ __forceinline__ float block_sum_384(float v){
  __shared__ float red[6];
#pragma unroll
  for (int o=32;o>0;o>>=1) v += __shfl_down(v,o);
  const int lane = threadIdx.x & 63, w = threadIdx.x >> 6;
  __syncthreads();
  if (lane==0) red[w] = v;
  __syncthreads();
  return red[0]+red[1]+red[2]+red[3]+red[4]+red[5];
}

// LN kernel. MODE 0: in = 49 conv partials (+conv bias) -> write xout
//            MODE 1: in = upd[bh][q][hd] gathered -> xout += LN
//            MODE 2: in = h2[m][d] -> xout += LN
template<int MODE>
__global__ __launch_bounds__(384)
void lnk(const float* __restrict__ in, const float* __restrict__ cb,
         const float* __restrict__ gg, const float* __restrict__ bb,
         float* __restrict__ xout){
  const int m = blockIdx.x, d = threadIdx.x;
  float v;
  if (MODE==0){
    v = cb[d];
    for (int z=0; z<NSLICE; z++) v += in[((size_t)z*MOUT + m)*D_ + d];
  } else if (MODE==1){
    int b = m/NOUT, q = m - b*NOUT;
    int h = d>>5, dd2 = d&31;
    v = in[(((size_t)(b*H_ + h))*NOUT + q)*HD + dd2];
  } else {
    v = in[(size_t)m*D_ + d];
  }
  float mu  = block_sum_384(v) * (1.f/D_);
  float ce  = v - mu;
  float var = block_sum_384(ce*ce) * (1.f/D_);
  float o = ce * rsqrtf(var + LN_EPS) * gg[d] + bb[d];
  float* dst = xout + (size_t)m*D_ + d;
  if (MODE==0) *dst = o;
  else *dst += o;
}

// ------------- rose for K (+ temp scale, bf16 pack) and V gather ------------
__global__ __launch_bounds__(256)
void rosek(const float* __restrict__ kvbuf, const float* __restrict__ rf,
           const float* __restrict__ temp,
           ushort* __restrict__ kb, float* __restrict__ vhb){
  int idx = blockIdx.x*256 + threadIdx.x;
  if (idx >= BB*H_*NIN) return;
  int n  = idx & (NIN-1);
  int bh = idx >> 12;
  int h  = bh % H_;
  int b  = bh / H_;
  float T = temp[0];
  int iy = n >> 6, ix = n & 63;
  const float* src = kvbuf + ((size_t)b*NIN + n)*768 + h*HD;
  float xv[HD];
#pragma unroll
  for (int d4=0; d4<8; d4++){
    float4 v = *(const float4*)(src + d4*4);
    xv[d4*4]=v.x; xv[d4*4+1]=v.y; xv[d4*4+2]=v.z; xv[d4*4+3]=v.w;
  }
  float out[HD];
#pragma unroll
  for (int tp=0; tp<8; tp++){
    int s2 = tp >> 2, p2 = tp & 3;
    float coord = (s2==0) ? (float)iy : (float)ix;
    float ang = coord * rf[(h*2+s2)*4 + p2];
    float sn, cn; sincosf(ang, &sn, &cn);
    float x1 = xv[2*tp], x2 = xv[2*tp+1];
    out[2*tp]   = x1*cn - x2*sn;
    out[2*tp+1] = x1*sn + x2*cn;
  }
#pragma unroll
  for (int d=16; d<HD; d++) out[d] = xv[d];
  ushort* dk = kb + ((size_t)bh*NIN + n)*HD;
#pragma unroll
  for (int g=0; g<4; g++){
    uint4 o;
    o.x = f2bf(T*out[g*8+0]) | (f2bf(T*out[g*8+1])<<16);
    o.y = f2bf(T*out[g*8+2]) | (f2bf(T*out[g*8+3])<<16);
    o.z = f2bf(T*out[g*8+4]) | (f2bf(T*out[g*8+5])<<16);
    o.w = f2bf(T*out[g*8+6]) | (f2bf(T*out[g*8+7])<<16);
    *(uint4*)(dk + g*8) = o;
  }
  const float* vs = src + D_;
  float* dv = vhb + ((size_t)bh*NIN + n)*HD;
#pragma unroll
  for (int d4=0; d4<8; d4++)
    *(float4*)(dv + d4*4) = *(const float4*)(vs + d4*4);
}

// ------------- rose for Q (grid 22x22, spacing 3.0) -> bf16, padded to 512 --
__global__ __launch_bounds__(256)
void roseq(const float* __restrict__ qp, const float* __restrict__ rf,
           ushort* __restrict__ qb){
  int idx = blockIdx.x*256 + threadIdx.x;      // < 24*512
  int q  = idx & 511;
  int bh = idx >> 9;
  int h  = bh % H_;
  int b  = bh / H_;
  ushort* dq = qb + ((size_t)bh*512 + q)*HD;
  if (q >= NOUT){
    uint4 z = {0,0,0,0};
#pragma unroll
    for (int g=0; g<4; g++) *(uint4*)(dq + g*8) = z;
    return;
  }
  int oy = q / QW_, ox = q - oy*QW_;
  const float* src = qp + ((size_t)b*NOUT + q)*D_ + h*HD;
  float xv[HD];
#pragma unroll
  for (int d4=0; d4<8; d4++){
    float4 v = *(const float4*)(src + d4*4);
    xv[d4*4]=v.x; xv[d4*4+1]=v.y; xv[d4*4+2]=v.z; xv[d4*4+3]=v.w;
  }
  float out[HD];
#pragma unroll
  for (int tp=0; tp<8; tp++){
    int s2 = tp >> 2, p2 = tp & 3;
    float coord = (s2==0) ? 3.0f*(float)oy : 3.0f*(float)ox;
    float ang = coord * rf[(h*2+s2)*4 + p2];
    float sn, cn; sincosf(ang, &sn, &cn);
    float x1 = xv[2*tp], x2 = xv[2*tp+1];
    out[2*tp]   = x1*cn - x2*sn;
    out[2*tp+1] = x1*sn + x2*cn;
  }
#pragma unroll
  for (int d=16; d<HD; d++) out[d] = xv[d];
#pragma unroll
  for (int g=0; g<4; g++){
    uint4 o;
    o.x = f2bf(out[g*8+0]) | (f2bf(out[g*8+1])<<16);
    o.y = f2bf(out[g*8+2]) | (f2bf(out[g*8+3])<<16);
    o.z = f2bf(out[g*8+4]) | (f2bf(out[g*8+5])<<16);
    o.w = f2bf(out[g*8+6]) | (f2bf(out[g*8+7])<<16);
    *(uint4*)(dq + g*8) = o;
  }
}

// ------- qkek: MFMA QK^T (64q x 256k per block, d=32), exp, store E, rowsums -
__global__ __launch_bounds__(256)
void qkek(const ushort* __restrict__ qb, const ushort* __restrict__ kb,
          float* __restrict__ E, float* __restrict__ l0part){
  __shared__ ushort Qs[64][40];
  __shared__ ushort Ks[256][40];
  __shared__ float  red[4][64];
  const int t  = threadIdx.x;
  const int q0 = blockIdx.x*64;
  const int kt = blockIdx.y;
  const int k0 = kt*256;
  const int bh = blockIdx.z;
  {  // stage Q: 64 rows x 32 ush
    int row = t>>2, seg = t&3;
    const ushort* src = qb + ((size_t)bh*512 + q0 + row)*HD + seg*8;
    *(uint4*)&Qs[row][seg*8] = *(const uint4*)src;
  }
  {  // stage K: 256 rows x 32 ush
    const ushort* src = kb + ((size_t)bh*NIN + k0 + t)*HD;
#pragma unroll
    for (int g=0; g<4; g++)
      *(uint4*)&Ks[t][g*8] = *(const uint4*)(src + g*8);
  }
  __syncthreads();
  const int wv = t>>6;
  const int wc = wv*64;
  const int ln = t&15, lq = (t>>4)&3;
  bf16x8 af[4], bfr[4];
#pragma unroll
  for (int i=0;i<4;i++) af[i]  = *(const bf16x8*)&Qs[i*16+ln][lq*8];
#pragma unroll
  for (int j=0;j<4;j++) bfr[j] = *(const bf16x8*)&Ks[wc+j*16+ln][lq*8];
  f32x4 acc[4][4];
  const f32x4 zero = (f32x4){0.f,0.f,0.f,0.f};
#pragma unroll
  for (int i=0;i<4;i++)
#pragma unroll
    for (int j=0;j<4;j++)
      acc[i][j] = __builtin_amdgcn_mfma_f32_16x16x32_bf16(af[i], bfr[j], zero, 0,0,0);
  // exp + store E + per-(wave,row) partial sums over the 64 cols this wave owns
  float rs[4][4];
#pragma unroll
  for (int i=0;i<4;i++){
#pragma unroll
    for (int rg=0; rg<4; rg++){
      int qq = q0 + i*16 + lq*4 + rg;
      bool qok = qq < NOUT;
      float* erow = E + ((size_t)bh*NOUT + (qok?qq:0))*NIN + k0 + wc + ln;
      float s = 0.f;
#pragma unroll
      for (int j=0;j<4;j++){
        float ev = __expf(acc[i][j][rg]);
        s += ev;
        if (qok) erow[j*16] = ev;
      }
      rs[i][rg] = s;
    }
  }
#pragma unroll
  for (int i=0;i<4;i++)
#pragma unroll
    for (int rg=0;rg<4;rg++){
      float v = rs[i][rg];
      v += __shfl_xor(v,1); v += __shfl_xor(v,2);
      v += __shfl_xor(v,4); v += __shfl_xor(v,8);
      rs[i][rg] = v;
    }
  if (ln==0){
#pragma unroll
    for (int i=0;i<4;i++)
#pragma unroll
      for (int rg=0;rg<4;rg++)
        red[wv][i*16+lq*4+rg] = rs[i][rg];
  }
  __syncthreads();
  if (t < 64){
    float tot = red[0][t]+red[1][t]+red[2][t]+red[3][t];
    l0part[((size_t)bh*512 + q0 + t)*16 + kt] = tot;
  }
}

// ------- l0red: l0inv[bh][q] = 1 / sum over 16 k-tile partials --------------
__global__ __launch_bounds__(256)
void l0red(const float* __restrict__ lp, float* __restrict__ l0inv){
  int i = blockIdx.x*256 + threadIdx.x;          // < 24*512
  const float4* p = (const float4*)(lp + (size_t)i*16);
  float4 a=p[0], b=p[1], c=p[2], d=p[3];
  float s = a.x+a.y+a.z+a.w + b.x+b.y+b.z+b.w + c.x+c.y+c.z+c.w + d.x+d.y+d.z+d.w;
  l0inv[i] = 1.f/s;
}

// ------- colk: csinv[bh][k] = 1/(sum_q E*l0inv + EPS); LAST: E *= l0inv in place
template<bool LAST>
__global__ __launch_bounds__(256)
void colk(float* __restrict__ E, const float* __restrict__ l0inv,
          float* __restrict__ csinv){
  const int t   = threadIdx.x;
  const int col = blockIdx.x*256 + t;
  const int bh  = blockIdx.y;
  float* base = E + (size_t)bh*NOUT*NIN + col;
  const float* li = l0inv + (size_t)bh*512;
  float c0=0.f, c1=0.f, c2=0.f, c3=0.f;
  for (int q=0; q<NOUT; q+=4){                 // 484 = 4*121
    float e0 = base[(size_t)(q+0)*NIN];
    float e1 = base[(size_t)(q+1)*NIN];
    float e2 = base[(size_t)(q+2)*NIN];
    float e3 = base[(size_t)(q+3)*NIN];
    float p0 = e0*li[q+0], p1 = e1*li[q+1], p2 = e2*li[q+2], p3 = e3*li[q+3];
    c0+=p0; c1+=p1; c2+=p2; c3+=p3;
    if (LAST){
      base[(size_t)(q+0)*NIN]=p0; base[(size_t)(q+1)*NIN]=p1;
      base[(size_t)(q+2)*NIN]=p2; base[(size_t)(q+3)*NIN]=p3;
    }
  }
  csinv[(size_t)bh*NIN + col] = 1.f/((c0+c1)+(c2+c3) + EPS_);
}

// ------- pvk: P = E*(l0inv)*csinv; upd = P @ V; LAST: also write attnq ------
template<bool LAST>
__global__ __launch_bounds__(256)
void pvk(const float* __restrict__ E, const float* __restrict__ vh,
         const float* __restrict__ l0inv, const float* __restrict__ csinv,
         float* __restrict__ upd, float* __restrict__ attnq){
  __shared__ float Vs[128][33];
  __shared__ float Ps[32][132];
  const int t  = threadIdx.x;
  const int q0 = blockIdx.x*32;
  const int bh = blockIdx.y;
  const int pr = t>>3, seg = t&7;              // P staging: row 0..31, seg 0..7
  const int qrow = q0 + pr;
  const bool qok = qrow < NOUT;
  const float liv = LAST ? 1.f : l0inv[(size_t)bh*512 + qrow];   // LAST: folded already
  const float* erow = E + ((size_t)bh*NOUT + (qok?qrow:0))*NIN;
  float* aqrow = attnq + ((size_t)bh*NOUT + (qok?qrow:0))*NIN;
  const int dd = t&31, qg = t>>5;
  float acc[4] = {0.f,0.f,0.f,0.f};
  for (int kc=0; kc<NIN; kc+=128){
    __syncthreads();
    {  // stage V[128][32]
      int r = t>>1, dh = (t&1)<<4;
      const float* pv = vh + ((size_t)bh*NIN + kc + r)*HD + dh;
      float4 b0=*(const float4*)pv, b1=*(const float4*)(pv+4),
             b2=*(const float4*)(pv+8), b3=*(const float4*)(pv+12);
      Vs[r][dh+0]=b0.x; Vs[r][dh+1]=b0.y; Vs[r][dh+2]=b0.z; Vs[r][dh+3]=b0.w;
      Vs[r][dh+4]=b1.x; Vs[r][dh+5]=b1.y; Vs[r][dh+6]=b1.z; Vs[r][dh+7]=b1.w;
      Vs[r][dh+8]=b2.x; Vs[r][dh+9]=b2.y; Vs[r][dh+10]=b2.z; Vs[r][dh+11]=b2.w;
      Vs[r][dh+12]=b3.x; Vs[r][dh+13]=b3.y; Vs[r][dh+14]=b3.z; Vs[r][dh+15]=b3.w;
    }
    {  // stage P[32][128]: coalesced (8 consecutive lanes = 128B contiguous)
      const float* ero = erow + kc;
      const float* cio = csinv + (size_t)bh*NIN + kc;
#pragma unroll
      for (int j=0; j<4; j++){
        int c = seg*4 + j*32;
        float4 e  = qok ? *(const float4*)(ero + c) : make_float4(0.f,0.f,0.f,0.f);
        float4 ci = *(const float4*)(cio + c);
        float4 p;
        p.x = e.x*liv*ci.x; p.y = e.y*liv*ci.y;
        p.z = e.z*liv*ci.z; p.w = e.w*liv*ci.w;
        *(float4*)&Ps[pr][c] = p;
        if (LAST && qok) *(float4*)(aqrow + kc + c) = p;
      }
    }
    __syncthreads();
#pragma unroll 4
    for (int kk=0; kk<128; kk+=4){
      float v0=Vs[kk][dd], v1=Vs[kk+1][dd], v2=Vs[kk+2][dd], v3=Vs[kk+3][dd];
#pragma unroll
      for (int i=0;i<4;i++){
        float4 pfr = *(const float4*)&Ps[qg*4+i][kk];
        acc[i] += pfr.x*v0 + pfr.y*v1 + pfr.z*v2 + pfr.w*v3;
      }
    }
  }
#pragma unroll
  for (int i=0;i<4;i++){
    int q = q0 + qg*4 + i;
    if (q < NOUT) upd[((size_t)bh*NOUT + q)*HD + dd] = acc[i];
  }
}

__global__ __launch_bounds__(256)
void copyk(const float* __restrict__ src, float* __restrict__ dst, int n){
  int i = blockIdx.x*256 + threadIdx.x;
  if (i < n) dst[i] = src[i];
}

// --------------------------------------------------------------------------
extern "C" void kernel_launch(void* const* d_in, const int* in_sizes, int n_in,
                              void* d_out, int out_size, void* d_ws, size_t ws_size,
                              hipStream_t stream){
  (void)in_sizes; (void)n_in; (void)out_size; (void)ws_size;
  const float* px    = (const float*)d_in[0];
  const float* pcw   = (const float*)d_in[1];
  const float* pcb   = (const float*)d_in[2];
  const float* pkvw  = (const float*)d_in[3];
  const float* pkvb  = (const float*)d_in[4];
  const float* pqw   = (const float*)d_in[5];
  const float* pqb   = (const float*)d_in[6];
  const float* pw1   = (const float*)d_in[7];
  const float* pb1   = (const float*)d_in[8];
  const float* pw2   = (const float*)d_in[9];
  const float* pb2   = (const float*)d_in[10];
  const float* pg1   = (const float*)d_in[11];
  const float* pbe1  = (const float*)d_in[12];
  const float* pg2   = (const float*)d_in[13];
  const float* pbe2  = (const float*)d_in[14];
  const float* pg3   = (const float*)d_in[15];
  const float* pbe3  = (const float*)d_in[16];
  const float* ptemp = (const float*)d_in[17];
  const float* prf   = (const float*)d_in[18];

  float* out = (float*)d_out;
  float* ws  = (float*)d_ws;

  float* xout   = ws + OXOUT;
  ushort* kb    = (ushort*)(ws + OKB);
  float* vhb    = ws + OVH;
  ushort* qb    = (ushort*)(ws + OQB);
  float* qp     = ws + OQP;
  float* l0inv  = ws + OL0;
  float* csinv  = ws + OCS;
  float* l0part = ws + OLP;
  float* updb   = ws + OUPD;
  float* h1     = ws + OH1;
  float* h2     = ws + OH2;
  ushort* qwb   = (ushort*)(ws + OQWB);
  ushort* w1b   = (ushort*)(ws + OW1B);
  ushort* w2b   = (ushort*)(ws + OW2B);

  // d_out regions double as scratch until the attn outputs are written
  float* attnq = out + 371712;
  float* attnk = out + 371712 + 47579136;      // also serves as E = exp(S) buffer
  float* kvbuf = attnq;                         // dead before attn_q written
  float* cpart = attnq + 8388608;               // 49*968*384 f, dead after ln1
  ushort* wtb  = (ushort*)attnk;                // dead after conv (before first qkek)
  ushort* xb16 = (ushort*)(attnk + 3612672);    // dead after kv gemm
  ushort* kvwb = (ushort*)(attnk + 3612672 + 1572864);  // dead after kv gemm

  // ---- packing (loop-invariant) ----
  packxk<<<dim3((MIN_*D_/4 + 255)/256), 256, 0, stream>>>(px, xb16);
  wtk2  <<<dim3((CK*D_ + 255)/256), 256, 0, stream>>>(pcw, wtb);
  packwk<<<dim3((384*768 + 255)/256), 256, 0, stream>>>(pkvw, kvwb, 384, 768);
  packwk<<<dim3((384*384 + 255)/256), 256, 0, stream>>>(pqw,  qwb,  384, 384);
  packwk<<<dim3((384*1536 + 255)/256), 256, 0, stream>>>(pw1, w1b, 384, 1536);
  packwk<<<dim3((1536*384 + 255)/256), 256, 0, stream>>>(pw2, w2b, 1536, 384);

  // ---- precompute (loop-invariant) ----
  convm<<<dim3(8,3,NSLICE), 256, 0, stream>>>(xb16, wtb, cpart);
  lnk<0><<<dim3(MOUT), 384, 0, stream>>>(cpart, pcb, pg1, pbe1, xout);
  gemmm<0,true><<<dim3(64,6), 256, 0, stream>>>(xb16, kvwb, pkvb, kvbuf, MIN_, 768, 384);
  rosek<<<dim3((BB*H_*NIN+255)/256), 256, 0, stream>>>(kvbuf, prf, ptemp, kb, vhb);

  // ---- 3 iterations ----
  for (int it=0; it<3; ++it){
    gemmm<0,false><<<dim3(8,3), 256, 0, stream>>>(xout, qwb, pqb, qp, MOUT, 384, 384);
    roseq<<<dim3(48), 256, 0, stream>>>(qp, prf, qb);
    qkek<<<dim3(8,16,24), 256, 0, stream>>>(qb, kb, attnk, l0part);
    l0red<<<dim3(48), 256, 0, stream>>>(l0part, l0inv);
    if (it==2){
      colk<true ><<<dim3(16,24), 256, 0, stream>>>(attnk, l0inv, csinv);
      pvk<true ><<<dim3(16,24), 256, 0, stream>>>(attnk, vhb, l0inv, csinv, updb, attnq);
    } else {
      colk<false><<<dim3(16,24), 256, 0, stream>>>(attnk, l0inv, csinv);
      pvk<false><<<dim3(16,24), 256, 0, stream>>>(attnk, vhb, l0inv, csinv, updb, attnq);
    }
    lnk<1><<<dim3(MOUT), 384, 0, stream>>>(updb, pcb, pg2, pbe2, xout);
    gemmm<1,false><<<dim3(8,12), 256, 0, stream>>>(xout, w1b, pb1, h1, MOUT, 1536, 384);
    gemmm<0,false><<<dim3(8,3), 256, 0, stream>>>(h1, w2b, pb2, h2, MOUT, 384, 1536);
    lnk<2><<<dim3(MOUT), 384, 0, stream>>>(h2, pcb, pg3, pbe3, xout);
  }

  copyk<<<dim3((371712+255)/256), 256, 0, stream>>>(xout, out, 371712);
}

// Round 4
// 1431.593 us; speedup vs baseline: 1.4472x; 1.2507x over previous
//
#include <hip/hip_runtime.h>
#include <math.h>

// ---------------- problem constants ----------------
#define BB 2
#define D_ 384
#define H_ 12
#define HD 32
#define NIN 4096            // 64*64
#define NOUT 484            // 22*22
#define MOUT (BB*NOUT)      // 968
#define MIN_ (BB*NIN)       // 8192
#define QW_ 22
#define CK 18816            // D*7*7
#define NSLICE 49           // conv split-K: one slice per (ky,kx), K=384 each
#define LN_EPS 1e-5f
#define EPS_ 1.1920929e-07f

typedef short bf16x8 __attribute__((ext_vector_type(8)));
typedef float f32x4  __attribute__((ext_vector_type(4)));

__device__ __forceinline__ unsigned f2bf(float f){   // RNE fp32->bf16 bits
  unsigned u = __float_as_uint(f);
  u += 0x7fffu + ((u>>16)&1u);
  return u>>16;
}

// ---------------- ws layout (floats) ----------------
static const size_t OXOUT = 0;                       // 371712
static const size_t OKB   = 371712;                  // K bf16: 24*4096*32 ush = 1572864 f
static const size_t OVH   = OKB + 1572864;           // V fp32: 3145728
static const size_t OQB   = OVH + 3145728;           // Q bf16: 24*512*32 ush = 196608 f
static const size_t OQP   = OQB + 196608;            // 371712
static const size_t OL0   = OQP + 371712;            // 12288
static const size_t OCS   = OL0 + 12288;             // 98304
static const size_t OLP   = OCS + 98304;             // 196608
static const size_t OUPD  = OLP + 196608;            // 371712
static const size_t OH1   = OUPD + 371712;           // 1486848
static const size_t OH2   = OH1 + 1486848;           // 4*371712 = 1486848 (mlp2 split-K parts)
static const size_t OQWB  = OH2 + 1486848;           // 73728
static const size_t OW1B  = OQWB + 73728;            // 294912
static const size_t OW2B  = OW1B + 294912;           // 294912
// total = 9,974,784 floats = 39.9 MB

// ---------------- packing kernels ----------------
__global__ __launch_bounds__(256)
void packxk(const float* __restrict__ x, ushort* __restrict__ xb){
  int i = blockIdx.x*256 + threadIdx.x;
  int base = i*4;
  if (base >= MIN_*D_) return;
  float4 v = *(const float4*)(x + base);
  uint2 o;
  o.x = f2bf(v.x) | (f2bf(v.y)<<16);
  o.y = f2bf(v.z) | (f2bf(v.w)<<16);
  *(uint2*)(xb + base) = o;
}

// conv_w [n][di][ky][kx] -> Wtb[kyx][n][di] (bf16)
__global__ __launch_bounds__(256)
void wtk2(const float* __restrict__ cw, ushort* __restrict__ wtb){
  int i = blockIdx.x*256 + threadIdx.x;
  if (i >= CK*D_) return;
  int n = i / CK;
  int r = i - n*CK;           // di*49 + kyx
  int di = r/49, kyx = r - di*49;
  wtb[((size_t)kyx*D_ + n)*D_ + di] = (ushort)f2bf(cw[i]);
}

// w[k][n] fp32 -> wb[n][k] bf16
__global__ __launch_bounds__(256)
void packwk(const float* __restrict__ w, ushort* __restrict__ wb, int K, int N){
  int i = blockIdx.x*256 + threadIdx.x;
  if (i >= K*N) return;
  int k = i / N, n = i - k*N;
  wb[(size_t)n*K + k] = (ushort)f2bf(w[i]);
}

// -------- MFMA conv: per-slice GEMM, 128x128 tile, 4 waves x (4x4) 16x16x32 --------
__global__ __launch_bounds__(256)
void convm(const ushort* __restrict__ xb, const ushort* __restrict__ wtb,
           float* __restrict__ part){
  __shared__ ushort As[128][40];
  __shared__ ushort Bs[128][40];
  const int t  = threadIdx.x;
  const int m0 = blockIdx.x*128, n0 = blockIdx.y*128, z = blockIdx.z;
  const int ky = z/7, kx = z - ky*7;
  const int r = t>>1, half = t&1;
  const int m = m0 + r;
  const int mq = (m < MOUT) ? m : 0;
  const int bbv = mq/NOUT, qq = mq - bbv*NOUT;
  const int oy = qq/QW_, ox = qq - oy*QW_;
  const int iy = oy*3-3+ky, ix = ox*3-3+kx;
  const bool aval = (m<MOUT) && iy>=0 && iy<64 && ix>=0 && ix<64;
  const ushort* asrc = xb + ((size_t)bbv*NIN + (aval ? iy*64+ix : 0))*D_ + half*16;
  const ushort* bsrc = wtb + ((size_t)z*D_ + n0 + r)*D_ + half*16;

  const int wv = t>>6;
  const int wr = (wv>>1)*64, wc = (wv&1)*64;
  const int ln = t&15, lq = (t>>4)&3;

  f32x4 acc[4][4];
#pragma unroll
  for (int i=0;i<4;i++)
#pragma unroll
    for (int j=0;j<4;j++) acc[i][j] = (f32x4){0.f,0.f,0.f,0.f};

  for (int dk=0; dk<D_; dk+=32){
    uint4 a0 = {0,0,0,0}, a1 = {0,0,0,0};
    if (aval){ a0 = *(const uint4*)(asrc+dk); a1 = *(const uint4*)(asrc+dk+8); }
    uint4 b0 = *(const uint4*)(bsrc+dk), b1 = *(const uint4*)(bsrc+dk+8);
    *(uint4*)&As[r][half*16]   = a0;  *(uint4*)&As[r][half*16+8] = a1;
    *(uint4*)&Bs[r][half*16]   = b0;  *(uint4*)&Bs[r][half*16+8] = b1;
    __syncthreads();
    bf16x8 af[4], bfr[4];
#pragma unroll
    for (int i=0;i<4;i++) af[i]  = *(const bf16x8*)&As[wr+i*16+ln][lq*8];
#pragma unroll
    for (int j=0;j<4;j++) bfr[j] = *(const bf16x8*)&Bs[wc+j*16+ln][lq*8];
#pragma unroll
    for (int i=0;i<4;i++)
#pragma unroll
      for (int j=0;j<4;j++)
        acc[i][j] = __builtin_amdgcn_mfma_f32_16x16x32_bf16(af[i], bfr[j], acc[i][j], 0,0,0);
    __syncthreads();
  }
#pragma unroll
  for (int i=0;i<4;i++){
    int rowb = m0 + wr + i*16 + lq*4;
#pragma unroll
    for (int j=0;j<4;j++){
      int col = n0 + wc + j*16 + ln;
#pragma unroll
      for (int rg=0; rg<4; rg++){
        int row = rowb + rg;
        if (row < MOUT) part[((size_t)z*MOUT + row)*D_ + col] = acc[i][j][rg];
      }
    }
  }
}

// -------- MFMA GEMM: C = A[M,K]*W[K,N] + bias, W pre-packed as Wb[n][k] bf16 -----
template<int ACT, bool ABF>
__global__ __launch_bounds__(256)
void gemmm(const void* __restrict__ Ain, const ushort* __restrict__ Wb,
           const float* __restrict__ bias, float* __restrict__ C,
           int M, int N, int K){
  __shared__ ushort As[128][40];
  __shared__ ushort Bs[128][40];
  const int t  = threadIdx.x;
  const int m0 = blockIdx.x*128, n0 = blockIdx.y*128;
  const int r = t>>1, half = t&1;
  const int m = m0 + r;
  const bool aval = (m < M);
  const float*  af32 = (const float*)Ain  + (size_t)(aval?m:0)*K + half*16;
  const ushort* ab16 = (const ushort*)Ain + (size_t)(aval?m:0)*K + half*16;
  const ushort* bsrc = Wb + (size_t)(n0 + r)*K + half*16;

  const int wv = t>>6;
  const int wr = (wv>>1)*64, wc = (wv&1)*64;
  const int ln = t&15, lq = (t>>4)&3;

  f32x4 acc[4][4];
#pragma unroll
  for (int i=0;i<4;i++)
#pragma unroll
    for (int j=0;j<4;j++) acc[i][j] = (f32x4){0.f,0.f,0.f,0.f};

  for (int dk=0; dk<K; dk+=32){
    uint4 a0 = {0,0,0,0}, a1 = {0,0,0,0};
    if (aval){
      if (ABF){
        a0 = *(const uint4*)(ab16+dk); a1 = *(const uint4*)(ab16+dk+8);
      } else {
        float4 f0 = *(const float4*)(af32+dk),   f1 = *(const float4*)(af32+dk+4);
        float4 f2 = *(const float4*)(af32+dk+8), f3 = *(const float4*)(af32+dk+12);
        a0.x = f2bf(f0.x)|(f2bf(f0.y)<<16); a0.y = f2bf(f0.z)|(f2bf(f0.w)<<16);
        a0.z = f2bf(f1.x)|(f2bf(f1.y)<<16); a0.w = f2bf(f1.z)|(f2bf(f1.w)<<16);
        a1.x = f2bf(f2.x)|(f2bf(f2.y)<<16); a1.y = f2bf(f2.z)|(f2bf(f2.w)<<16);
        a1.z = f2bf(f3.x)|(f2bf(f3.y)<<16); a1.w = f2bf(f3.z)|(f2bf(f3.w)<<16);
      }
    }
    uint4 b0 = *(const uint4*)(bsrc+dk), b1 = *(const uint4*)(bsrc+dk+8);
    *(uint4*)&As[r][half*16]   = a0;  *(uint4*)&As[r][half*16+8] = a1;
    *(uint4*)&Bs[r][half*16]   = b0;  *(uint4*)&Bs[r][half*16+8] = b1;
    __syncthreads();
    bf16x8 af[4], bfr[4];
#pragma unroll
    for (int i=0;i<4;i++) af[i]  = *(const bf16x8*)&As[wr+i*16+ln][lq*8];
#pragma unroll
    for (int j=0;j<4;j++) bfr[j] = *(const bf16x8*)&Bs[wc+j*16+ln][lq*8];
#pragma unroll
    for (int i=0;i<4;i++)
#pragma unroll
      for (int j=0;j<4;j++)
        acc[i][j] = __builtin_amdgcn_mfma_f32_16x16x32_bf16(af[i], bfr[j], acc[i][j], 0,0,0);
    __syncthreads();
  }
#pragma unroll
  for (int i=0;i<4;i++){
    int rowb = m0 + wr + i*16 + lq*4;
#pragma unroll
    for (int j=0;j<4;j++){
      int col = n0 + wc + j*16 + ln;
      float bv = bias[col];
#pragma unroll
      for (int rg=0; rg<4; rg++){
        int row = rowb + rg;
        if (row < M){
          float v = acc[i][j][rg] + bv;
          if (ACT==1) v = 0.5f*v*(1.f + erff(v*0.7071067811865475f));
          C[(size_t)row*N + col] = v;
        }
      }
    }
  }
}

// -------- mlp2 split-K: part[z] = h1[:, z*384:(z+1)*384] @ W2slice (no bias) -----
__global__ __launch_bounds__(256)
void gemmsk(const float* __restrict__ Ain, const ushort* __restrict__ Wb,
            float* __restrict__ part){
  __shared__ ushort As[128][40];
  __shared__ ushort Bs[128][40];
  const int t  = threadIdx.x;
  const int m0 = blockIdx.x*128, n0 = blockIdx.y*128, z = blockIdx.z;
  const int r = t>>1, half = t&1;
  const int m = m0 + r;
  const bool aval = (m < MOUT);
  const float*  af32 = Ain + (size_t)(aval?m:0)*1536 + z*384 + half*16;
  const ushort* bsrc = Wb + (size_t)(n0 + r)*1536 + z*384 + half*16;

  const int wv = t>>6;
  const int wr = (wv>>1)*64, wc = (wv&1)*64;
  const int ln = t&15, lq = (t>>4)&3;

  f32x4 acc[4][4];
#pragma unroll
  for (int i=0;i<4;i++)
#pragma unroll
    for (int j=0;j<4;j++) acc[i][j] = (f32x4){0.f,0.f,0.f,0.f};

  for (int dk=0; dk<384; dk+=32){
    uint4 a0 = {0,0,0,0}, a1 = {0,0,0,0};
    if (aval){
      float4 f0 = *(const float4*)(af32+dk),   f1 = *(const float4*)(af32+dk+4);
      float4 f2 = *(const float4*)(af32+dk+8), f3 = *(const float4*)(af32+dk+12);
      a0.x = f2bf(f0.x)|(f2bf(f0.y)<<16); a0.y = f2bf(f0.z)|(f2bf(f0.w)<<16);
      a0.z = f2bf(f1.x)|(f2bf(f1.y)<<16); a0.w = f2bf(f1.z)|(f2bf(f1.w)<<16);
      a1.x = f2bf(f2.x)|(f2bf(f2.y)<<16); a1.y = f2bf(f2.z)|(f2bf(f2.w)<<16);
      a1.z = f2bf(f3.x)|(f2bf(f3.y)<<16); a1.w = f2bf(f3.z)|(f2bf(f3.w)<<16);
    }
    uint4 b0 = *(const uint4*)(bsrc+dk), b1 = *(const uint4*)(bsrc+dk+8);
    *(uint4*)&As[r][half*16]   = a0;  *(uint4*)&As[r][half*16+8] = a1;
    *(uint4*)&Bs[r][half*16]   = b0;  *(uint4*)&Bs[r][half*16+8] = b1;
    __syncthreads();
    bf16x8 af[4], bfr[4];
#pragma unroll
    for (int i=0;i<4;i++) af[i]  = *(const bf16x8*)&As[wr+i*16+ln][lq*8];
#pragma unroll
    for (int j=0;j<4;j++) bfr[j] = *(const bf16x8*)&Bs[wc+j*16+ln][lq*8];
#pragma unroll
    for (int i=0;i<4;i++)
#pragma unroll
      for (int j=0;j<4;j++)
        acc[i][j] = __builtin_amdgcn_mfma_f32_16x16x32_bf16(af[i], bfr[j], acc[i][j], 0,0,0);
    __syncthreads();
  }
#pragma unroll
  for (int i=0;i<4;i++){
    int rowb = m0 + wr + i*16 + lq*4;
#pragma unroll
    for (int j=0;j<4;j++){
      int col = n0 + wc + j*16 + ln;
#pragma unroll
      for (int rg=0; rg<4; rg++){
        int row = rowb + rg;
        if (row < MOUT) part[((size_t)z*MOUT + row)*D_ + col] = acc[i][j][rg];
      }
    }
  }
}

// ---------------- block reduction over 384 threads --------------------------
__device__ __forceinline__ float block_sum_384(float v){
  __shared__ float red[6];
#pragma unroll
  for (int o=32;o>0;o>>=1) v += __shfl_down(v,o);
  const int lane = threadIdx.x & 63, w = threadIdx.x >> 6;
  __syncthreads();
  if (lane==0) red[w] = v;
  __syncthreads();
  return red[0]+red[1]+red[2]+red[3]+red[4]+red[5];
}

// LN kernel. MODE 0: in = 49 conv partials (+bias cb) -> write xout
//            MODE 1: in = upd[bh][q][hd] gathered -> xout += LN
//            MODE 2: in = h2[m][d] -> xout += LN
//            MODE 3: in = 4 mlp2 partials (+bias cb) -> xout += LN
template<int MODE>
__global__ __launch_bounds__(384)
void lnk(const float* __restrict__ in, const float* __restrict__ cb,
         const float* __restrict__ gg, const float* __restrict__ bb,
         float* __restrict__ xout){
  const int m = blockIdx.x, d = threadIdx.x;
  float v;
  if (MODE==0){
    v = cb[d];
    for (int z=0; z<NSLICE; z++) v += in[((size_t)z*MOUT + m)*D_ + d];
  } else if (MODE==1){
    int b = m/NOUT, q = m - b*NOUT;
    int h = d>>5, dd2 = d&31;
    v = in[(((size_t)(b*H_ + h))*NOUT + q)*HD + dd2];
  } else if (MODE==2){
    v = in[(size_t)m*D_ + d];
  } else {
    v = cb[d];
#pragma unroll
    for (int z=0; z<4; z++) v += in[((size_t)z*MOUT + m)*D_ + d];
  }
  float mu  = block_sum_384(v) * (1.f/D_);
  float ce  = v - mu;
  float var = block_sum_384(ce*ce) * (1.f/D_);
  float o = ce * rsqrtf(var + LN_EPS) * gg[d] + bb[d];
  float* dst = xout + (size_t)m*D_ + d;
  if (MODE==0) *dst = o;
  else *dst += o;
}

// ------------- rose for K (+ temp scale, bf16 pack) and V gather ------------
__global__ __launch_bounds__(256)
void rosek(const float* __restrict__ kvbuf, const float* __restrict__ rf,
           const float* __restrict__ temp,
           ushort* __restrict__ kb, float* __restrict__ vhb){
  int idx = blockIdx.x*256 + threadIdx.x;
  if (idx >= BB*H_*NIN) return;
  int n  = idx & (NIN-1);
  int bh = idx >> 12;
  int h  = bh % H_;
  int b  = bh / H_;
  float T = temp[0];
  int iy = n >> 6, ix = n & 63;
  const float* src = kvbuf + ((size_t)b*NIN + n)*768 + h*HD;
  float xv[HD];
#pragma unroll
  for (int d4=0; d4<8; d4++){
    float4 v = *(const float4*)(src + d4*4);
    xv[d4*4]=v.x; xv[d4*4+1]=v.y; xv[d4*4+2]=v.z; xv[d4*4+3]=v.w;
  }
  float out[HD];
#pragma unroll
  for (int tp=0; tp<8; tp++){
    int s2 = tp >> 2, p2 = tp & 3;
    float coord = (s2==0) ? (float)iy : (float)ix;
    float ang = coord * rf[(h*2+s2)*4 + p2];
    float sn, cn; sincosf(ang, &sn, &cn);
    float x1 = xv[2*tp], x2 = xv[2*tp+1];
    out[2*tp]   = x1*cn - x2*sn;
    out[2*tp+1] = x1*sn + x2*cn;
  }
#pragma unroll
  for (int d=16; d<HD; d++) out[d] = xv[d];
  ushort* dk = kb + ((size_t)bh*NIN + n)*HD;
#pragma unroll
  for (int g=0; g<4; g++){
    uint4 o;
    o.x = f2bf(T*out[g*8+0]) | (f2bf(T*out[g*8+1])<<16);
    o.y = f2bf(T*out[g*8+2]) | (f2bf(T*out[g*8+3])<<16);
    o.z = f2bf(T*out[g*8+4]) | (f2bf(T*out[g*8+5])<<16);
    o.w = f2bf(T*out[g*8+6]) | (f2bf(T*out[g*8+7])<<16);
    *(uint4*)(dk + g*8) = o;
  }
  const float* vs = src + D_;
  float* dv = vhb + ((size_t)bh*NIN + n)*HD;
#pragma unroll
  for (int d4=0; d4<8; d4++)
    *(float4*)(dv + d4*4) = *(const float4*)(vs + d4*4);
}

// ------------- rose for Q (grid 22x22, spacing 3.0) -> bf16, padded to 512 --
__global__ __launch_bounds__(256)
void roseq(const float* __restrict__ qp, const float* __restrict__ rf,
           ushort* __restrict__ qb){
  int idx = blockIdx.x*256 + threadIdx.x;      // < 24*512
  int q  = idx & 511;
  int bh = idx >> 9;
  int h  = bh % H_;
  int b  = bh / H_;
  ushort* dq = qb + ((size_t)bh*512 + q)*HD;
  if (q >= NOUT){
    uint4 z = {0,0,0,0};
#pragma unroll
    for (int g=0; g<4; g++) *(uint4*)(dq + g*8) = z;
    return;
  }
  int oy = q / QW_, ox = q - oy*QW_;
  const float* src = qp + ((size_t)b*NOUT + q)*D_ + h*HD;
  float xv[HD];
#pragma unroll
  for (int d4=0; d4<8; d4++){
    float4 v = *(const float4*)(src + d4*4);
    xv[d4*4]=v.x; xv[d4*4+1]=v.y; xv[d4*4+2]=v.z; xv[d4*4+3]=v.w;
  }
  float out[HD];
#pragma unroll
  for (int tp=0; tp<8; tp++){
    int s2 = tp >> 2, p2 = tp & 3;
    float coord = (s2==0) ? 3.0f*(float)oy : 3.0f*(float)ox;
    float ang = coord * rf[(h*2+s2)*4 + p2];
    float sn, cn; sincosf(ang, &sn, &cn);
    float x1 = xv[2*tp], x2 = xv[2*tp+1];
    out[2*tp]   = x1*cn - x2*sn;
    out[2*tp+1] = x1*sn + x2*cn;
  }
#pragma unroll
  for (int d=16; d<HD; d++) out[d] = xv[d];
#pragma unroll
  for (int g=0; g<4; g++){
    uint4 o;
    o.x = f2bf(out[g*8+0]) | (f2bf(out[g*8+1])<<16);
    o.y = f2bf(out[g*8+2]) | (f2bf(out[g*8+3])<<16);
    o.z = f2bf(out[g*8+4]) | (f2bf(out[g*8+5])<<16);
    o.w = f2bf(out[g*8+6]) | (f2bf(out[g*8+7])<<16);
    *(uint4*)(dq + g*8) = o;
  }
}

// ------- rowk: MFMA QK^T (64q x 256k), exp, rowsum partials (no E store) ----
__global__ __launch_bounds__(256)
void rowk(const ushort* __restrict__ qb, const ushort* __restrict__ kb,
          float* __restrict__ l0part){
  __shared__ ushort Qs[64][40];
  __shared__ ushort Ks[256][40];
  __shared__ float  red[4][64];
  const int t  = threadIdx.x;
  const int q0 = blockIdx.x*64;
  const int kt = blockIdx.y;
  const int k0 = kt*256;
  const int bh = blockIdx.z;
  {  // stage Q: 64 rows x 32 ush
    int row = t>>2, seg = t&3;
    const ushort* src = qb + ((size_t)bh*512 + q0 + row)*HD + seg*8;
    *(uint4*)&Qs[row][seg*8] = *(const uint4*)src;
  }
  {  // stage K: 256 rows x 32 ush
    const ushort* src = kb + ((size_t)bh*NIN + k0 + t)*HD;
#pragma unroll
    for (int g=0; g<4; g++)
      *(uint4*)&Ks[t][g*8] = *(const uint4*)(src + g*8);
  }
  __syncthreads();
  const int wv = t>>6;
  const int wc = wv*64;
  const int ln = t&15, lq = (t>>4)&3;
  bf16x8 af[4], bfr[4];
#pragma unroll
  for (int i=0;i<4;i++) af[i]  = *(const bf16x8*)&Qs[i*16+ln][lq*8];
#pragma unroll
  for (int j=0;j<4;j++) bfr[j] = *(const bf16x8*)&Ks[wc+j*16+ln][lq*8];
  f32x4 acc[4][4];
  const f32x4 zero = (f32x4){0.f,0.f,0.f,0.f};
#pragma unroll
  for (int i=0;i<4;i++)
#pragma unroll
    for (int j=0;j<4;j++)
      acc[i][j] = __builtin_amdgcn_mfma_f32_16x16x32_bf16(af[i], bfr[j], zero, 0,0,0);
  float rs[4][4];
#pragma unroll
  for (int i=0;i<4;i++){
#pragma unroll
    for (int rg=0; rg<4; rg++){
      float s = 0.f;
#pragma unroll
      for (int j=0;j<4;j++) s += __expf(acc[i][j][rg]);
      rs[i][rg] = s;
    }
  }
#pragma unroll
  for (int i=0;i<4;i++)
#pragma unroll
    for (int rg=0;rg<4;rg++){
      float v = rs[i][rg];
      v += __shfl_xor(v,1); v += __shfl_xor(v,2);
      v += __shfl_xor(v,4); v += __shfl_xor(v,8);
      rs[i][rg] = v;
    }
  if (ln==0){
#pragma unroll
    for (int i=0;i<4;i++)
#pragma unroll
      for (int rg=0;rg<4;rg++)
        red[wv][i*16+lq*4+rg] = rs[i][rg];
  }
  __syncthreads();
  if (t < 64){
    float tot = red[0][t]+red[1][t]+red[2][t]+red[3][t];
    l0part[((size_t)bh*512 + q0 + t)*16 + kt] = tot;
  }
}

// ------- l0red: l0inv[bh][q] = 1 / sum over 16 k-tile partials --------------
__global__ __launch_bounds__(256)
void l0red(const float* __restrict__ lp, float* __restrict__ l0inv){
  int i = blockIdx.x*256 + threadIdx.x;          // < 24*512
  const float4* p = (const float4*)(lp + (size_t)i*16);
  float4 a=p[0], b=p[1], c=p[2], d=p[3];
  float s = a.x+a.y+a.z+a.w + b.x+b.y+b.z+b.w + c.x+c.y+c.z+c.w + d.x+d.y+d.z+d.w;
  l0inv[i] = 1.f/s;
}

// ------- colk_f: recompute S^T via MFMA (A=K, B=Q); csinv[k]=1/(sum_q E*li+EPS)
__global__ __launch_bounds__(256)
void colk_f(const ushort* __restrict__ qb, const ushort* __restrict__ kb,
            const float* __restrict__ l0inv, float* __restrict__ csinv){
  __shared__ ushort Ks[256][40];
  __shared__ ushort Qs[64][40];
  __shared__ float  lis[64];
  const int t  = threadIdx.x;
  const int k0 = blockIdx.x*256;
  const int bh = blockIdx.y;
  {  // stage K tile once: 256 rows x 32 ush
    const ushort* src = kb + ((size_t)bh*NIN + k0 + t)*HD;
#pragma unroll
    for (int g=0; g<4; g++)
      *(uint4*)&Ks[t][g*8] = *(const uint4*)(src + g*8);
  }
  const int wv = t>>6, ln = t&15, lq = (t>>4)&3;
  const f32x4 zero = (f32x4){0.f,0.f,0.f,0.f};
  f32x4 colacc[4];
#pragma unroll
  for (int i=0;i<4;i++) colacc[i] = zero;
  for (int qc=0; qc<512; qc+=64){
    __syncthreads();
    {  // stage Q chunk: 64 rows x 32 ush
      int row = t>>2, seg = t&3;
      *(uint4*)&Qs[row][seg*8] =
        *(const uint4*)(qb + ((size_t)bh*512 + qc + row)*HD + seg*8);
    }
    if (t < 64){
      int q = qc + t;
      lis[t] = (q < NOUT) ? l0inv[(size_t)bh*512 + q] : 0.f;
    }
    __syncthreads();
    bf16x8 af[4], bfr[4];
#pragma unroll
    for (int i=0;i<4;i++) af[i]  = *(const bf16x8*)&Ks[wv*64+i*16+ln][lq*8];
#pragma unroll
    for (int j=0;j<4;j++) bfr[j] = *(const bf16x8*)&Qs[j*16+ln][lq*8];
#pragma unroll
    for (int j=0;j<4;j++){
      float liv = lis[j*16+ln];
#pragma unroll
      for (int i=0;i<4;i++){
        f32x4 c = __builtin_amdgcn_mfma_f32_16x16x32_bf16(af[i], bfr[j], zero, 0,0,0);
#pragma unroll
        for (int rg=0;rg<4;rg++)
          colacc[i][rg] += __expf(c[rg]) * liv;
      }
    }
  }
#pragma unroll
  for (int i=0;i<4;i++)
#pragma unroll
    for (int rg=0;rg<4;rg++){
      float v = colacc[i][rg];
      v += __shfl_xor(v,1); v += __shfl_xor(v,2);
      v += __shfl_xor(v,4); v += __shfl_xor(v,8);
      colacc[i][rg] = v;
    }
  if (ln==0){
#pragma unroll
    for (int i=0;i<4;i++){
      float4 o;
      o.x = 1.f/(colacc[i][0] + EPS_);
      o.y = 1.f/(colacc[i][1] + EPS_);
      o.z = 1.f/(colacc[i][2] + EPS_);
      o.w = 1.f/(colacc[i][3] + EPS_);
      *(float4*)(csinv + (size_t)bh*NIN + k0 + wv*64 + i*16 + lq*4) = o;
    }
  }
}

// ------- pv_f: recompute S, P=exp(S)*li in LDS; upd = P @ (ci*V);
//         LAST: write attnk = P, attnq = P*ci (coalesced from LDS) -----------
template<bool LAST>
__global__ __launch_bounds__(256)
void pv_f(const ushort* __restrict__ qb, const ushort* __restrict__ kb,
          const float* __restrict__ vh, const float* __restrict__ l0inv,
          const float* __restrict__ csinv, float* __restrict__ upd,
          float* __restrict__ attnq, float* __restrict__ attnk){
  __shared__ ushort Qs[32][40];
  __shared__ ushort Ks[128][40];
  __shared__ float  Vs[128][33];
  __shared__ float  Ps[32][132];
  __shared__ float  lis[32];
  __shared__ float  cis[128];
  const int t  = threadIdx.x;
  const int q0 = blockIdx.x*32;
  const int bh = blockIdx.y;
  {  // stage Q bf16 once: 32 rows x 32 ush
    int row = t>>3, seg = t&7;
    *(uint2*)&Qs[row][seg*4] =
      *(const uint2*)(qb + ((size_t)bh*512 + q0 + row)*HD + seg*4);
  }
  if (t < 32){
    int q = q0 + t;
    lis[t] = (q < NOUT) ? l0inv[(size_t)bh*512 + q] : 0.f;
  }
  const int wv = t>>6, ln = t&15, lq = (t>>4)&3;
  const int dd = t&31, qg = t>>5;
  const f32x4 zero = (f32x4){0.f,0.f,0.f,0.f};
  float acc[4] = {0.f,0.f,0.f,0.f};
  for (int kc=0; kc<NIN; kc+=128){
    __syncthreads();
    {  // stage K bf16, V*ci fp32, cis
      int r = t>>1, half = t&1;
      const ushort* pk = kb + ((size_t)bh*NIN + kc + r)*HD + half*16;
      *(uint4*)&Ks[r][half*16]   = *(const uint4*)pk;
      *(uint4*)&Ks[r][half*16+8] = *(const uint4*)(pk+8);
      float civ = csinv[(size_t)bh*NIN + kc + r];
      if (half==0) cis[r] = civ;
      const float* pv = vh + ((size_t)bh*NIN + kc + r)*HD + half*16;
      float4 b0=*(const float4*)pv, b1=*(const float4*)(pv+4),
             b2=*(const float4*)(pv+8), b3=*(const float4*)(pv+12);
      int dh = half<<4;
      Vs[r][dh+0]=civ*b0.x; Vs[r][dh+1]=civ*b0.y; Vs[r][dh+2]=civ*b0.z; Vs[r][dh+3]=civ*b0.w;
      Vs[r][dh+4]=civ*b1.x; Vs[r][dh+5]=civ*b1.y; Vs[r][dh+6]=civ*b1.z; Vs[r][dh+7]=civ*b1.w;
      Vs[r][dh+8]=civ*b2.x; Vs[r][dh+9]=civ*b2.y; Vs[r][dh+10]=civ*b2.z; Vs[r][dh+11]=civ*b2.w;
      Vs[r][dh+12]=civ*b3.x; Vs[r][dh+13]=civ*b3.y; Vs[r][dh+14]=civ*b3.z; Vs[r][dh+15]=civ*b3.w;
    }
    __syncthreads();
    // MFMA S -> P = exp(S)*li staged to Ps
#pragma unroll
    for (int i=0;i<2;i++){
      bf16x8 af = *(const bf16x8*)&Qs[i*16+ln][lq*8];
#pragma unroll
      for (int j=0;j<2;j++){
        bf16x8 bfr = *(const bf16x8*)&Ks[wv*32+j*16+ln][lq*8];
        f32x4 c = __builtin_amdgcn_mfma_f32_16x16x32_bf16(af, bfr, zero, 0,0,0);
#pragma unroll
        for (int rg=0;rg<4;rg++){
          int ql = i*16 + lq*4 + rg;
          Ps[ql][wv*32 + j*16 + ln] = __expf(c[rg]) * lis[ql];
        }
      }
    }
    __syncthreads();
    if (LAST){
      int row = t>>3, seg = t&7;
      int q = q0 + row;
      if (q < NOUT){
        float* ak = attnk + ((size_t)bh*NOUT + q)*NIN + kc + seg*16;
        float* aq = attnq + ((size_t)bh*NOUT + q)*NIN + kc + seg*16;
#pragma unroll
        for (int s=0;s<4;s++){
          float4 p  = *(const float4*)&Ps[row][seg*16 + s*4];
          float4 c4 = *(const float4*)&cis[seg*16 + s*4];
          *(float4*)(ak + s*4) = p;
          float4 pq;
          pq.x = p.x*c4.x; pq.y = p.y*c4.y; pq.z = p.z*c4.z; pq.w = p.w*c4.w;
          *(float4*)(aq + s*4) = pq;
        }
      }
    }
    // PV: acc += P[q][k] * (ci*V)[k][d]
#pragma unroll 4
    for (int kk=0; kk<128; kk+=4){
      float v0=Vs[kk][dd], v1=Vs[kk+1][dd], v2=Vs[kk+2][dd], v3=Vs[kk+3][dd];
#pragma unroll
      for (int i=0;i<4;i++){
        float4 pr = *(const float4*)&Ps[qg*4+i][kk];
        acc[i] += pr.x*v0 + pr.y*v1 + pr.z*v2 + pr.w*v3;
      }
    }
  }
#pragma unroll
  for (int i=0;i<4;i++){
    int q = q0 + qg*4 + i;
    if (q < NOUT) upd[((size_t)bh*NOUT + q)*HD + dd] = acc[i];
  }
}

__global__ __launch_bounds__(256)
void copyk(const float* __restrict__ src, float* __restrict__ dst, int n){
  int i = blockIdx.x*256 + threadIdx.x;
  if (i < n) dst[i] = src[i];
}

// --------------------------------------------------------------------------
extern "C" void kernel_launch(void* const* d_in, const int* in_sizes, int n_in,
                              void* d_out, int out_size, void* d_ws, size_t ws_size,
                              hipStream_t stream){
  (void)in_sizes; (void)n_in; (void)out_size; (void)ws_size;
  const float* px    = (const float*)d_in[0];
  const float* pcw   = (const float*)d_in[1];
  const float* pcb   = (const float*)d_in[2];
  const float* pkvw  = (const float*)d_in[3];
  const float* pkvb  = (const float*)d_in[4];
  const float* pqw   = (const float*)d_in[5];
  const float* pqb   = (const float*)d_in[6];
  const float* pw1   = (const float*)d_in[7];
  const float* pb1   = (const float*)d_in[8];
  const float* pw2   = (const float*)d_in[9];
  const float* pb2   = (const float*)d_in[10];
  const float* pg1   = (const float*)d_in[11];
  const float* pbe1  = (const float*)d_in[12];
  const float* pg2   = (const float*)d_in[13];
  const float* pbe2  = (const float*)d_in[14];
  const float* pg3   = (const float*)d_in[15];
  const float* pbe3  = (const float*)d_in[16];
  const float* ptemp = (const float*)d_in[17];
  const float* prf   = (const float*)d_in[18];

  float* out = (float*)d_out;
  float* ws  = (float*)d_ws;

  float* xout   = ws + OXOUT;
  ushort* kb    = (ushort*)(ws + OKB);
  float* vhb    = ws + OVH;
  ushort* qb    = (ushort*)(ws + OQB);
  float* qp     = ws + OQP;
  float* l0inv  = ws + OL0;
  float* csinv  = ws + OCS;
  float* l0part = ws + OLP;
  float* updb   = ws + OUPD;
  float* h1     = ws + OH1;
  float* h2p    = ws + OH2;
  ushort* qwb   = (ushort*)(ws + OQWB);
  ushort* w1b   = (ushort*)(ws + OW1B);
  ushort* w2b   = (ushort*)(ws + OW2B);

  // d_out regions double as scratch until the attn outputs are written (it==2)
  float* attnq = out + 371712;
  float* attnk = out + 371712 + 47579136;
  float* kvbuf = attnq;                         // dead before attn_q written
  float* cpart = attnq + 8388608;               // 49*968*384 f, dead after ln1
  ushort* wtb  = (ushort*)attnk;                // dead after conv
  ushort* xb16 = (ushort*)(attnk + 3612672);    // dead after kv gemm
  ushort* kvwb = (ushort*)(attnk + 3612672 + 1572864);  // dead after kv gemm

  // ---- packing (loop-invariant) ----
  packxk<<<dim3((MIN_*D_/4 + 255)/256), 256, 0, stream>>>(px, xb16);
  wtk2  <<<dim3((CK*D_ + 255)/256), 256, 0, stream>>>(pcw, wtb);
  packwk<<<dim3((384*768 + 255)/256), 256, 0, stream>>>(pkvw, kvwb, 384, 768);
  packwk<<<dim3((384*384 + 255)/256), 256, 0, stream>>>(pqw,  qwb,  384, 384);
  packwk<<<dim3((384*1536 + 255)/256), 256, 0, stream>>>(pw1, w1b, 384, 1536);
  packwk<<<dim3((1536*384 + 255)/256), 256, 0, stream>>>(pw2, w2b, 1536, 384);

  // ---- precompute (loop-invariant) ----
  convm<<<dim3(8,3,NSLICE), 256, 0, stream>>>(xb16, wtb, cpart);
  lnk<0><<<dim3(MOUT), 384, 0, stream>>>(cpart, pcb, pg1, pbe1, xout);
  gemmm<0,true><<<dim3(64,6), 256, 0, stream>>>(xb16, kvwb, pkvb, kvbuf, MIN_, 768, 384);
  rosek<<<dim3((BB*H_*NIN+255)/256), 256, 0, stream>>>(kvbuf, prf, ptemp, kb, vhb);

  // ---- 3 iterations ----
  for (int it=0; it<3; ++it){
    gemmm<0,false><<<dim3(8,3), 256, 0, stream>>>(xout, qwb, pqb, qp, MOUT, 384, 384);
    roseq<<<dim3(48), 256, 0, stream>>>(qp, prf, qb);
    rowk<<<dim3(8,16,24), 256, 0, stream>>>(qb, kb, l0part);
    l0red<<<dim3(48), 256, 0, stream>>>(l0part, l0inv);
    colk_f<<<dim3(16,24), 256, 0, stream>>>(qb, kb, l0inv, csinv);
    if (it==2){
      pv_f<true ><<<dim3(16,24), 256, 0, stream>>>(qb, kb, vhb, l0inv, csinv, updb, attnq, attnk);
    } else {
      pv_f<false><<<dim3(16,24), 256, 0, stream>>>(qb, kb, vhb, l0inv, csinv, updb, attnq, attnk);
    }
    lnk<1><<<dim3(MOUT), 384, 0, stream>>>(updb, pcb, pg2, pbe2, xout);
    gemmm<1,false><<<dim3(8,12), 256, 0, stream>>>(xout, w1b, pb1, h1, MOUT, 1536, 384);
    gemmsk<<<dim3(8,3,4), 256, 0, stream>>>(h1, w2b, h2p);
    lnk<3><<<dim3(MOUT), 384, 0, stream>>>(h2p, pb2, pg3, pbe3, xout);
  }

  copyk<<<dim3((371712+255)/256), 256, 0, stream>>>(xout, out, 371712);
}

// Round 6
// 1344.415 us; speedup vs baseline: 1.5411x; 1.0648x over previous
//
#include <hip/hip_runtime.h>
#include <math.h>

// ---------------- problem constants ----------------
#define BB 2
#define D_ 384
#define H_ 12
#define HD 32
#define NIN 4096            // 64*64
#define NOUT 484            // 22*22
#define MOUT (BB*NOUT)      // 968
#define MIN_ (BB*NIN)       // 8192
#define QW_ 22
#define CK 18816            // D*7*7
#define NSLICE 49           // conv split-K: one slice per (ky,kx), K=384 each
#define LN_EPS 1e-5f
#define EPS_ 1.1920929e-07f

typedef short bf16x8 __attribute__((ext_vector_type(8)));
typedef float f32x4  __attribute__((ext_vector_type(4)));

__device__ __forceinline__ unsigned f2bf(float f){   // RNE fp32->bf16 bits
  unsigned u = __float_as_uint(f);
  u += 0x7fffu + ((u>>16)&1u);
  return u>>16;
}

// ---------------- ws layout (floats) ----------------
static const size_t OXOUT = 0;                       // 371712
static const size_t OKB   = 371712;                  // K bf16: 24*4096*32 ush = 1572864 f
static const size_t OVH   = OKB + 1572864;           // V fp32: 3145728
static const size_t OQB   = OVH + 3145728;           // Q bf16: 24*512*32 ush = 196608 f
static const size_t OQP   = OQB + 196608;            // 371712
static const size_t OL0   = OQP + 371712;            // 12288
static const size_t OCS   = OL0 + 12288;             // 98304
static const size_t OLP   = OCS + 98304;             // 196608
static const size_t OUPD  = OLP + 196608;            // 371712
static const size_t OH1   = OUPD + 371712;           // 1486848
static const size_t OH2   = OH1 + 1486848;           // 4*371712 = 1486848 (mlp2 split-K parts)
static const size_t OQWB  = OH2 + 1486848;           // 73728
static const size_t OW1B  = OQWB + 73728;            // 294912
static const size_t OW2B  = OW1B + 294912;           // 294912
// total = 9,974,784 floats = 39.9 MB

// ---------------- packing kernels ----------------
__global__ __launch_bounds__(256)
void packxk(const float* __restrict__ x, ushort* __restrict__ xb){
  int i = blockIdx.x*256 + threadIdx.x;
  int base = i*4;
  if (base >= MIN_*D_) return;
  float4 v = *(const float4*)(x + base);
  uint2 o;
  o.x = f2bf(v.x) | (f2bf(v.y)<<16);
  o.y = f2bf(v.z) | (f2bf(v.w)<<16);
  *(uint2*)(xb + base) = o;
}

// conv_w [n][di][ky][kx] -> Wtb[kyx][n][di] (bf16)
__global__ __launch_bounds__(256)
void wtk2(const float* __restrict__ cw, ushort* __restrict__ wtb){
  int i = blockIdx.x*256 + threadIdx.x;
  if (i >= CK*D_) return;
  int n = i / CK;
  int r = i - n*CK;           // di*49 + kyx
  int di = r/49, kyx = r - di*49;
  wtb[((size_t)kyx*D_ + n)*D_ + di] = (ushort)f2bf(cw[i]);
}

// w[k][n] fp32 -> wb[n][k] bf16
__global__ __launch_bounds__(256)
void packwk(const float* __restrict__ w, ushort* __restrict__ wb, int K, int N){
  int i = blockIdx.x*256 + threadIdx.x;
  if (i >= K*N) return;
  int k = i / N, n = i - k*N;
  wb[(size_t)n*K + k] = (ushort)f2bf(w[i]);
}

// -------- MFMA conv: per-slice GEMM, 128x128 tile, 4 waves x (4x4) 16x16x32 --------
__global__ __launch_bounds__(256)
void convm(const ushort* __restrict__ xb, const ushort* __restrict__ wtb,
           float* __restrict__ part){
  __shared__ ushort As[128][40];
  __shared__ ushort Bs[128][40];
  const int t  = threadIdx.x;
  const int m0 = blockIdx.x*128, n0 = blockIdx.y*128, z = blockIdx.z;
  const int ky = z/7, kx = z - ky*7;
  const int r = t>>1, half = t&1;
  const int m = m0 + r;
  const int mq = (m < MOUT) ? m : 0;
  const int bbv = mq/NOUT, qq = mq - bbv*NOUT;
  const int oy = qq/QW_, ox = qq - oy*QW_;
  const int iy = oy*3-3+ky, ix = ox*3-3+kx;
  const bool aval = (m<MOUT) && iy>=0 && iy<64 && ix>=0 && ix<64;
  const ushort* asrc = xb + ((size_t)bbv*NIN + (aval ? iy*64+ix : 0))*D_ + half*16;
  const ushort* bsrc = wtb + ((size_t)z*D_ + n0 + r)*D_ + half*16;

  const int wv = t>>6;
  const int wr = (wv>>1)*64, wc = (wv&1)*64;
  const int ln = t&15, lq = (t>>4)&3;

  f32x4 acc[4][4];
#pragma unroll
  for (int i=0;i<4;i++)
#pragma unroll
    for (int j=0;j<4;j++) acc[i][j] = (f32x4){0.f,0.f,0.f,0.f};

  for (int dk=0; dk<D_; dk+=32){
    uint4 a0 = {0,0,0,0}, a1 = {0,0,0,0};
    if (aval){ a0 = *(const uint4*)(asrc+dk); a1 = *(const uint4*)(asrc+dk+8); }
    uint4 b0 = *(const uint4*)(bsrc+dk), b1 = *(const uint4*)(bsrc+dk+8);
    *(uint4*)&As[r][half*16]   = a0;  *(uint4*)&As[r][half*16+8] = a1;
    *(uint4*)&Bs[r][half*16]   = b0;  *(uint4*)&Bs[r][half*16+8] = b1;
    __syncthreads();
    bf16x8 af[4], bfr[4];
#pragma unroll
    for (int i=0;i<4;i++) af[i]  = *(const bf16x8*)&As[wr+i*16+ln][lq*8];
#pragma unroll
    for (int j=0;j<4;j++) bfr[j] = *(const bf16x8*)&Bs[wc+j*16+ln][lq*8];
#pragma unroll
    for (int i=0;i<4;i++)
#pragma unroll
      for (int j=0;j<4;j++)
        acc[i][j] = __builtin_amdgcn_mfma_f32_16x16x32_bf16(af[i], bfr[j], acc[i][j], 0,0,0);
    __syncthreads();
  }
#pragma unroll
  for (int i=0;i<4;i++){
    int rowb = m0 + wr + i*16 + lq*4;
#pragma unroll
    for (int j=0;j<4;j++){
      int col = n0 + wc + j*16 + ln;
#pragma unroll
      for (int rg=0; rg<4; rg++){
        int row = rowb + rg;
        if (row < MOUT) part[((size_t)z*MOUT + row)*D_ + col] = acc[i][j][rg];
      }
    }
  }
}

// -------- MFMA GEMM: C = A[M,K]*W[K,N] + bias, W pre-packed as Wb[n][k] bf16 -----
template<int ACT, bool ABF>
__global__ __launch_bounds__(256)
void gemmm(const void* __restrict__ Ain, const ushort* __restrict__ Wb,
           const float* __restrict__ bias, float* __restrict__ C,
           int M, int N, int K){
  __shared__ ushort As[128][40];
  __shared__ ushort Bs[128][40];
  const int t  = threadIdx.x;
  const int m0 = blockIdx.x*128, n0 = blockIdx.y*128;
  const int r = t>>1, half = t&1;
  const int m = m0 + r;
  const bool aval = (m < M);
  const float*  af32 = (const float*)Ain  + (size_t)(aval?m:0)*K + half*16;
  const ushort* ab16 = (const ushort*)Ain + (size_t)(aval?m:0)*K + half*16;
  const ushort* bsrc = Wb + (size_t)(n0 + r)*K + half*16;

  const int wv = t>>6;
  const int wr = (wv>>1)*64, wc = (wv&1)*64;
  const int ln = t&15, lq = (t>>4)&3;

  f32x4 acc[4][4];
#pragma unroll
  for (int i=0;i<4;i++)
#pragma unroll
    for (int j=0;j<4;j++) acc[i][j] = (f32x4){0.f,0.f,0.f,0.f};

  for (int dk=0; dk<K; dk+=32){
    uint4 a0 = {0,0,0,0}, a1 = {0,0,0,0};
    if (aval){
      if (ABF){
        a0 = *(const uint4*)(ab16+dk); a1 = *(const uint4*)(ab16+dk+8);
      } else {
        float4 f0 = *(const float4*)(af32+dk),   f1 = *(const float4*)(af32+dk+4);
        float4 f2 = *(const float4*)(af32+dk+8), f3 = *(const float4*)(af32+dk+12);
        a0.x = f2bf(f0.x)|(f2bf(f0.y)<<16); a0.y = f2bf(f0.z)|(f2bf(f0.w)<<16);
        a0.z = f2bf(f1.x)|(f2bf(f1.y)<<16); a0.w = f2bf(f1.z)|(f2bf(f1.w)<<16);
        a1.x = f2bf(f2.x)|(f2bf(f2.y)<<16); a1.y = f2bf(f2.z)|(f2bf(f2.w)<<16);
        a1.z = f2bf(f3.x)|(f2bf(f3.y)<<16); a1.w = f2bf(f3.z)|(f2bf(f3.w)<<16);
      }
    }
    uint4 b0 = *(const uint4*)(bsrc+dk), b1 = *(const uint4*)(bsrc+dk+8);
    *(uint4*)&As[r][half*16]   = a0;  *(uint4*)&As[r][half*16+8] = a1;
    *(uint4*)&Bs[r][half*16]   = b0;  *(uint4*)&Bs[r][half*16+8] = b1;
    __syncthreads();
    bf16x8 af[4], bfr[4];
#pragma unroll
    for (int i=0;i<4;i++) af[i]  = *(const bf16x8*)&As[wr+i*16+ln][lq*8];
#pragma unroll
    for (int j=0;j<4;j++) bfr[j] = *(const bf16x8*)&Bs[wc+j*16+ln][lq*8];
#pragma unroll
    for (int i=0;i<4;i++)
#pragma unroll
      for (int j=0;j<4;j++)
        acc[i][j] = __builtin_amdgcn_mfma_f32_16x16x32_bf16(af[i], bfr[j], acc[i][j], 0,0,0);
    __syncthreads();
  }
#pragma unroll
  for (int i=0;i<4;i++){
    int rowb = m0 + wr + i*16 + lq*4;
#pragma unroll
    for (int j=0;j<4;j++){
      int col = n0 + wc + j*16 + ln;
      float bv = bias[col];
#pragma unroll
      for (int rg=0; rg<4; rg++){
        int row = rowb + rg;
        if (row < M){
          float v = acc[i][j][rg] + bv;
          if (ACT==1) v = 0.5f*v*(1.f + erff(v*0.7071067811865475f));
          C[(size_t)row*N + col] = v;
        }
      }
    }
  }
}

// -------- mlp2 split-K: part[z] = h1[:, z*384:(z+1)*384] @ W2slice (no bias) -----
__global__ __launch_bounds__(256)
void gemmsk(const float* __restrict__ Ain, const ushort* __restrict__ Wb,
            float* __restrict__ part){
  __shared__ ushort As[128][40];
  __shared__ ushort Bs[128][40];
  const int t  = threadIdx.x;
  const int m0 = blockIdx.x*128, n0 = blockIdx.y*128, z = blockIdx.z;
  const int r = t>>1, half = t&1;
  const int m = m0 + r;
  const bool aval = (m < MOUT);
  const float*  af32 = Ain + (size_t)(aval?m:0)*1536 + z*384 + half*16;
  const ushort* bsrc = Wb + (size_t)(n0 + r)*1536 + z*384 + half*16;

  const int wv = t>>6;
  const int wr = (wv>>1)*64, wc = (wv&1)*64;
  const int ln = t&15, lq = (t>>4)&3;

  f32x4 acc[4][4];
#pragma unroll
  for (int i=0;i<4;i++)
#pragma unroll
    for (int j=0;j<4;j++) acc[i][j] = (f32x4){0.f,0.f,0.f,0.f};

  for (int dk=0; dk<384; dk+=32){
    uint4 a0 = {0,0,0,0}, a1 = {0,0,0,0};
    if (aval){
      float4 f0 = *(const float4*)(af32+dk),   f1 = *(const float4*)(af32+dk+4);
      float4 f2 = *(const float4*)(af32+dk+8), f3 = *(const float4*)(af32+dk+12);
      a0.x = f2bf(f0.x)|(f2bf(f0.y)<<16); a0.y = f2bf(f0.z)|(f2bf(f0.w)<<16);
      a0.z = f2bf(f1.x)|(f2bf(f1.y)<<16); a0.w = f2bf(f1.z)|(f2bf(f1.w)<<16);
      a1.x = f2bf(f2.x)|(f2bf(f2.y)<<16); a1.y = f2bf(f2.z)|(f2bf(f2.w)<<16);
      a1.z = f2bf(f3.x)|(f2bf(f3.y)<<16); a1.w = f2bf(f3.z)|(f2bf(f3.w)<<16);
    }
    uint4 b0 = *(const uint4*)(bsrc+dk), b1 = *(const uint4*)(bsrc+dk+8);
    *(uint4*)&As[r][half*16]   = a0;  *(uint4*)&As[r][half*16+8] = a1;
    *(uint4*)&Bs[r][half*16]   = b0;  *(uint4*)&Bs[r][half*16+8] = b1;
    __syncthreads();
    bf16x8 af[4], bfr[4];
#pragma unroll
    for (int i=0;i<4;i++) af[i]  = *(const bf16x8*)&As[wr+i*16+ln][lq*8];
#pragma unroll
    for (int j=0;j<4;j++) bfr[j] = *(const bf16x8*)&Bs[wc+j*16+ln][lq*8];
#pragma unroll
    for (int i=0;i<4;i++)
#pragma unroll
      for (int j=0;j<4;j++)
        acc[i][j] = __builtin_amdgcn_mfma_f32_16x16x32_bf16(af[i], bfr[j], acc[i][j], 0,0,0);
    __syncthreads();
  }
#pragma unroll
  for (int i=0;i<4;i++){
    int rowb = m0 + wr + i*16 + lq*4;
#pragma unroll
    for (int j=0;j<4;j++){
      int col = n0 + wc + j*16 + ln;
#pragma unroll
      for (int rg=0; rg<4; rg++){
        int row = rowb + rg;
        if (row < MOUT) part[((size_t)z*MOUT + row)*D_ + col] = acc[i][j][rg];
      }
    }
  }
}

// ---------------- block reduction over 384 threads --------------------------
__device__ __forceinline__ float block_sum_384(float v){
  __shared__ float red[6];
#pragma unroll
  for (int o=32;o>0;o>>=1) v += __shfl_down(v,o);
  const int lane = threadIdx.x & 63, w = threadIdx.x >> 6;
  __syncthreads();
  if (lane==0) red[w] = v;
  __syncthreads();
  return red[0]+red[1]+red[2]+red[3]+red[4]+red[5];
}

// LN kernel. MODE 0: in = 49 conv partials (+bias cb) -> write xout
//            MODE 1: in = upd[bh][q][hd] gathered -> xout += LN
//            MODE 2: in = h2[m][d] -> xout += LN
//            MODE 3: in = 4 mlp2 partials (+bias cb) -> xout += LN
template<int MODE>
__global__ __launch_bounds__(384)
void lnk(const float* __restrict__ in, const float* __restrict__ cb,
         const float* __restrict__ gg, const float* __restrict__ bb,
         float* __restrict__ xout){
  const int m = blockIdx.x, d = threadIdx.x;
  float v;
  if (MODE==0){
    v = cb[d];
    for (int z=0; z<NSLICE; z++) v += in[((size_t)z*MOUT + m)*D_ + d];
  } else if (MODE==1){
    int b = m/NOUT, q = m - b*NOUT;
    int h = d>>5, dd2 = d&31;
    v = in[(((size_t)(b*H_ + h))*NOUT + q)*HD + dd2];
  } else if (MODE==2){
    v = in[(size_t)m*D_ + d];
  } else {
    v = cb[d];
#pragma unroll
    for (int z=0; z<4; z++) v += in[((size_t)z*MOUT + m)*D_ + d];
  }
  float mu  = block_sum_384(v) * (1.f/D_);
  float ce  = v - mu;
  float var = block_sum_384(ce*ce) * (1.f/D_);
  float o = ce * rsqrtf(var + LN_EPS) * gg[d] + bb[d];
  float* dst = xout + (size_t)m*D_ + d;
  if (MODE==0) *dst = o;
  else *dst += o;
}

// ------------- rose for K (+ temp scale, bf16 pack) and V gather ------------
__global__ __launch_bounds__(256)
void rosek(const float* __restrict__ kvbuf, const float* __restrict__ rf,
           const float* __restrict__ temp,
           ushort* __restrict__ kb, float* __restrict__ vhb){
  int idx = blockIdx.x*256 + threadIdx.x;
  if (idx >= BB*H_*NIN) return;
  int n  = idx & (NIN-1);
  int bh = idx >> 12;
  int h  = bh % H_;
  int b  = bh / H_;
  float T = temp[0];
  int iy = n >> 6, ix = n & 63;
  const float* src = kvbuf + ((size_t)b*NIN + n)*768 + h*HD;
  float xv[HD];
#pragma unroll
  for (int d4=0; d4<8; d4++){
    float4 v = *(const float4*)(src + d4*4);
    xv[d4*4]=v.x; xv[d4*4+1]=v.y; xv[d4*4+2]=v.z; xv[d4*4+3]=v.w;
  }
  float out[HD];
#pragma unroll
  for (int tp=0; tp<8; tp++){
    int s2 = tp >> 2, p2 = tp & 3;
    float coord = (s2==0) ? (float)iy : (float)ix;
    float ang = coord * rf[(h*2+s2)*4 + p2];
    float sn, cn; sincosf(ang, &sn, &cn);
    float x1 = xv[2*tp], x2 = xv[2*tp+1];
    out[2*tp]   = x1*cn - x2*sn;
    out[2*tp+1] = x1*sn + x2*cn;
  }
#pragma unroll
  for (int d=16; d<HD; d++) out[d] = xv[d];
  ushort* dk = kb + ((size_t)bh*NIN + n)*HD;
#pragma unroll
  for (int g=0; g<4; g++){
    uint4 o;
    o.x = f2bf(T*out[g*8+0]) | (f2bf(T*out[g*8+1])<<16);
    o.y = f2bf(T*out[g*8+2]) | (f2bf(T*out[g*8+3])<<16);
    o.z = f2bf(T*out[g*8+4]) | (f2bf(T*out[g*8+5])<<16);
    o.w = f2bf(T*out[g*8+6]) | (f2bf(T*out[g*8+7])<<16);
    *(uint4*)(dk + g*8) = o;
  }
  const float* vs = src + D_;
  float* dv = vhb + ((size_t)bh*NIN + n)*HD;
#pragma unroll
  for (int d4=0; d4<8; d4++)
    *(float4*)(dv + d4*4) = *(const float4*)(vs + d4*4);
}

// ------------- rose for Q (grid 22x22, spacing 3.0) -> bf16, padded to 512 --
__global__ __launch_bounds__(256)
void roseq(const float* __restrict__ qp, const float* __restrict__ rf,
           ushort* __restrict__ qb){
  int idx = blockIdx.x*256 + threadIdx.x;      // < 24*512
  int q  = idx & 511;
  int bh = idx >> 9;
  int h  = bh % H_;
  int b  = bh / H_;
  ushort* dq = qb + ((size_t)bh*512 + q)*HD;
  if (q >= NOUT){
    uint4 z = {0,0,0,0};
#pragma unroll
    for (int g=0; g<4; g++) *(uint4*)(dq + g*8) = z;
    return;
  }
  int oy = q / QW_, ox = q - oy*QW_;
  const float* src = qp + ((size_t)b*NOUT + q)*D_ + h*HD;
  float xv[HD];
#pragma unroll
  for (int d4=0; d4<8; d4++){
    float4 v = *(const float4*)(src + d4*4);
    xv[d4*4]=v.x; xv[d4*4+1]=v.y; xv[d4*4+2]=v.z; xv[d4*4+3]=v.w;
  }
  float out[HD];
#pragma unroll
  for (int tp=0; tp<8; tp++){
    int s2 = tp >> 2, p2 = tp & 3;
    float coord = (s2==0) ? 3.0f*(float)oy : 3.0f*(float)ox;
    float ang = coord * rf[(h*2+s2)*4 + p2];
    float sn, cn; sincosf(ang, &sn, &cn);
    float x1 = xv[2*tp], x2 = xv[2*tp+1];
    out[2*tp]   = x1*cn - x2*sn;
    out[2*tp+1] = x1*sn + x2*cn;
  }
#pragma unroll
  for (int d=16; d<HD; d++) out[d] = xv[d];
#pragma unroll
  for (int g=0; g<4; g++){
    uint4 o;
    o.x = f2bf(out[g*8+0]) | (f2bf(out[g*8+1])<<16);
    o.y = f2bf(out[g*8+2]) | (f2bf(out[g*8+3])<<16);
    o.z = f2bf(out[g*8+4]) | (f2bf(out[g*8+5])<<16);
    o.w = f2bf(out[g*8+6]) | (f2bf(out[g*8+7])<<16);
    *(uint4*)(dq + g*8) = o;
  }
}

// ------- rowk: MFMA QK^T (64q x 256k), exp, rowsum partials (no E store) ----
__global__ __launch_bounds__(256)
void rowk(const ushort* __restrict__ qb, const ushort* __restrict__ kb,
          float* __restrict__ l0part){
  __shared__ ushort Qs[64][40];
  __shared__ ushort Ks[256][40];
  __shared__ float  red[4][64];
  const int t  = threadIdx.x;
  const int q0 = blockIdx.x*64;
  const int kt = blockIdx.y;
  const int k0 = kt*256;
  const int bh = blockIdx.z;
  {  // stage Q: 64 rows x 32 ush
    int row = t>>2, seg = t&3;
    const ushort* src = qb + ((size_t)bh*512 + q0 + row)*HD + seg*8;
    *(uint4*)&Qs[row][seg*8] = *(const uint4*)src;
  }
  {  // stage K: 256 rows x 32 ush
    const ushort* src = kb + ((size_t)bh*NIN + k0 + t)*HD;
#pragma unroll
    for (int g=0; g<4; g++)
      *(uint4*)&Ks[t][g*8] = *(const uint4*)(src + g*8);
  }
  __syncthreads();
  const int wv = t>>6;
  const int wc = wv*64;
  const int ln = t&15, lq = (t>>4)&3;
  bf16x8 af[4], bfr[4];
#pragma unroll
  for (int i=0;i<4;i++) af[i]  = *(const bf16x8*)&Qs[i*16+ln][lq*8];
#pragma unroll
  for (int j=0;j<4;j++) bfr[j] = *(const bf16x8*)&Ks[wc+j*16+ln][lq*8];
  f32x4 acc[4][4];
  const f32x4 zero = (f32x4){0.f,0.f,0.f,0.f};
#pragma unroll
  for (int i=0;i<4;i++)
#pragma unroll
    for (int j=0;j<4;j++)
      acc[i][j] = __builtin_amdgcn_mfma_f32_16x16x32_bf16(af[i], bfr[j], zero, 0,0,0);
  float rs[4][4];
#pragma unroll
  for (int i=0;i<4;i++){
#pragma unroll
    for (int rg=0; rg<4; rg++){
      float s = 0.f;
#pragma unroll
      for (int j=0;j<4;j++) s += __expf(acc[i][j][rg]);
      rs[i][rg] = s;
    }
  }
#pragma unroll
  for (int i=0;i<4;i++)
#pragma unroll
    for (int rg=0;rg<4;rg++){
      float v = rs[i][rg];
      v += __shfl_xor(v,1); v += __shfl_xor(v,2);
      v += __shfl_xor(v,4); v += __shfl_xor(v,8);
      rs[i][rg] = v;
    }
  if (ln==0){
#pragma unroll
    for (int i=0;i<4;i++)
#pragma unroll
      for (int rg=0;rg<4;rg++)
        red[wv][i*16+lq*4+rg] = rs[i][rg];
  }
  __syncthreads();
  if (t < 64){
    float tot = red[0][t]+red[1][t]+red[2][t]+red[3][t];
    l0part[((size_t)bh*512 + q0 + t)*16 + kt] = tot;
  }
}

// ------- l0red: l0inv[bh][q] = 1 / sum over 16 k-tile partials --------------
__global__ __launch_bounds__(256)
void l0red(const float* __restrict__ lp, float* __restrict__ l0inv){
  int i = blockIdx.x*256 + threadIdx.x;          // < 24*512
  const float4* p = (const float4*)(lp + (size_t)i*16);
  float4 a=p[0], b=p[1], c=p[2], d=p[3];
  float s = a.x+a.y+a.z+a.w + b.x+b.y+b.z+b.w + c.x+c.y+c.z+c.w + d.x+d.y+d.z+d.w;
  l0inv[i] = 1.f/s;
}

// ------- colk_f: recompute S^T via MFMA (A=K, B=Q); csinv[k]=1/(sum_q E*li+EPS)
__global__ __launch_bounds__(256)
void colk_f(const ushort* __restrict__ qb, const ushort* __restrict__ kb,
            const float* __restrict__ l0inv, float* __restrict__ csinv){
  __shared__ ushort Ks[256][40];
  __shared__ ushort Qs[64][40];
  __shared__ float  lis[64];
  const int t  = threadIdx.x;
  const int k0 = blockIdx.x*256;
  const int bh = blockIdx.y;
  {  // stage K tile once: 256 rows x 32 ush
    const ushort* src = kb + ((size_t)bh*NIN + k0 + t)*HD;
#pragma unroll
    for (int g=0; g<4; g++)
      *(uint4*)&Ks[t][g*8] = *(const uint4*)(src + g*8);
  }
  const int wv = t>>6, ln = t&15, lq = (t>>4)&3;
  const f32x4 zero = (f32x4){0.f,0.f,0.f,0.f};
  f32x4 colacc[4];
#pragma unroll
  for (int i=0;i<4;i++) colacc[i] = zero;
  for (int qc=0; qc<512; qc+=64){
    __syncthreads();
    {  // stage Q chunk: 64 rows x 32 ush
      int row = t>>2, seg = t&3;
      *(uint4*)&Qs[row][seg*8] =
        *(const uint4*)(qb + ((size_t)bh*512 + qc + row)*HD + seg*8);
    }
    if (t < 64){
      int q = qc + t;
      lis[t] = (q < NOUT) ? l0inv[(size_t)bh*512 + q] : 0.f;
    }
    __syncthreads();
    bf16x8 af[4], bfr[4];
#pragma unroll
    for (int i=0;i<4;i++) af[i]  = *(const bf16x8*)&Ks[wv*64+i*16+ln][lq*8];
#pragma unroll
    for (int j=0;j<4;j++) bfr[j] = *(const bf16x8*)&Qs[j*16+ln][lq*8];
#pragma unroll
    for (int j=0;j<4;j++){
      float liv = lis[j*16+ln];
#pragma unroll
      for (int i=0;i<4;i++){
        f32x4 c = __builtin_amdgcn_mfma_f32_16x16x32_bf16(af[i], bfr[j], zero, 0,0,0);
#pragma unroll
        for (int rg=0;rg<4;rg++)
          colacc[i][rg] += __expf(c[rg]) * liv;
      }
    }
  }
#pragma unroll
  for (int i=0;i<4;i++)
#pragma unroll
    for (int rg=0;rg<4;rg++){
      float v = colacc[i][rg];
      v += __shfl_xor(v,1); v += __shfl_xor(v,2);
      v += __shfl_xor(v,4); v += __shfl_xor(v,8);
      colacc[i][rg] = v;
    }
  if (ln==0){
#pragma unroll
    for (int i=0;i<4;i++){
      float4 o;
      o.x = 1.f/(colacc[i][0] + EPS_);
      o.y = 1.f/(colacc[i][1] + EPS_);
      o.z = 1.f/(colacc[i][2] + EPS_);
      o.w = 1.f/(colacc[i][3] + EPS_);
      *(float4*)(csinv + (size_t)bh*NIN + k0 + wv*64 + i*16 + lq*4) = o;
    }
  }
}

// ------- pv_f: recompute S via MFMA (K frags from global/L2), Ps[k][q] in LDS,
//         register-tiled PV: thread = (wave q-oct) x (d-quad) x (k-replica 8) --
//         LAST: write attnk = P, attnq = P*ci ---------------------------------
template<bool LAST>
__global__ __launch_bounds__(256)
void pv_f(const ushort* __restrict__ qb, const ushort* __restrict__ kb,
          const float* __restrict__ vh, const float* __restrict__ l0inv,
          const float* __restrict__ csinv, float* __restrict__ upd,
          float* __restrict__ attnq, float* __restrict__ attnk){
  __shared__ ushort Qs[32][40];      // Q tile bf16
  __shared__ float  Vs[128][36];     // ci*V fp32, stride 36 (16B-aligned rows)
  __shared__ float  Ps[128][36];     // P = exp(S)*li, TRANSPOSED [k][q]
  __shared__ float  lis[32];
  __shared__ float  cis[128];
  const int t  = threadIdx.x;
  const int q0 = blockIdx.x*32;
  const int bh = blockIdx.y;
  {  // stage Q bf16 once: 32 rows x 32 ush
    int row = t>>3, seg = t&7;
    *(uint2*)&Qs[row][seg*4] =
      *(const uint2*)(qb + ((size_t)bh*512 + q0 + row)*HD + seg*4);
  }
  if (t < 32){
    int q = q0 + t;
    lis[t] = (q < NOUT) ? l0inv[(size_t)bh*512 + q] : 0.f;
  }
  __syncthreads();
  const int wv = t>>6, ln = t&15, lq = (t>>4)&3;
  const int kr = t&7, dg = (t>>3)&7, qg = wv;     // PV roles
  // hoist per-thread li values (kc-invariant)
  float lr[2][4];
#pragma unroll
  for (int i=0;i<2;i++)
#pragma unroll
    for (int rg=0;rg<4;rg++) lr[i][rg] = lis[i*16 + lq*4 + rg];
  const f32x4 zero = (f32x4){0.f,0.f,0.f,0.f};
  f32x4 acc[8];
#pragma unroll
  for (int i=0;i<8;i++) acc[i] = zero;
  const ushort* kfrag = kb + ((size_t)bh*NIN)*HD;
  for (int kc=0; kc<NIN; kc+=128){
    __syncthreads();
    {  // stage V*ci fp32 (rows stride 36), cis
      int r = t>>1, half = t&1;
      float civ = csinv[(size_t)bh*NIN + kc + r];
      if (half==0) cis[r] = civ;
      const float* pv = vh + ((size_t)bh*NIN + kc + r)*HD + half*16;
      float4 b0=*(const float4*)pv, b1=*(const float4*)(pv+4),
             b2=*(const float4*)(pv+8), b3=*(const float4*)(pv+12);
      int dh = half<<4;
      float* vr = &Vs[r][dh];
      vr[0]=civ*b0.x; vr[1]=civ*b0.y; vr[2]=civ*b0.z; vr[3]=civ*b0.w;
      vr[4]=civ*b1.x; vr[5]=civ*b1.y; vr[6]=civ*b1.z; vr[7]=civ*b1.w;
      vr[8]=civ*b2.x; vr[9]=civ*b2.y; vr[10]=civ*b2.z; vr[11]=civ*b2.w;
      vr[12]=civ*b3.x; vr[13]=civ*b3.y; vr[14]=civ*b3.z; vr[15]=civ*b3.w;
    }
    // S via MFMA: K fragments straight from global (L2-resident)
    bf16x8 af0 = *(const bf16x8*)&Qs[ln][lq*8];
    bf16x8 af1 = *(const bf16x8*)&Qs[16+ln][lq*8];
    bf16x8 bf0 = *(const bf16x8*)(kfrag + (size_t)(kc + wv*32 +      ln)*HD + lq*8);
    bf16x8 bf1 = *(const bf16x8*)(kfrag + (size_t)(kc + wv*32 + 16 + ln)*HD + lq*8);
    __syncthreads();   // Vs/cis ready; Ps of previous tile fully consumed
    {
      f32x4 c;
      float4 pw;
      c = __builtin_amdgcn_mfma_f32_16x16x32_bf16(af0, bf0, zero, 0,0,0);
      pw.x=__expf(c[0])*lr[0][0]; pw.y=__expf(c[1])*lr[0][1];
      pw.z=__expf(c[2])*lr[0][2]; pw.w=__expf(c[3])*lr[0][3];
      *(float4*)&Ps[wv*32 +      ln][      lq*4] = pw;
      c = __builtin_amdgcn_mfma_f32_16x16x32_bf16(af1, bf0, zero, 0,0,0);
      pw.x=__expf(c[0])*lr[1][0]; pw.y=__expf(c[1])*lr[1][1];
      pw.z=__expf(c[2])*lr[1][2]; pw.w=__expf(c[3])*lr[1][3];
      *(float4*)&Ps[wv*32 +      ln][16 + lq*4] = pw;
      c = __builtin_amdgcn_mfma_f32_16x16x32_bf16(af0, bf1, zero, 0,0,0);
      pw.x=__expf(c[0])*lr[0][0]; pw.y=__expf(c[1])*lr[0][1];
      pw.z=__expf(c[2])*lr[0][2]; pw.w=__expf(c[3])*lr[0][3];
      *(float4*)&Ps[wv*32 + 16 + ln][      lq*4] = pw;
      c = __builtin_amdgcn_mfma_f32_16x16x32_bf16(af1, bf1, zero, 0,0,0);
      pw.x=__expf(c[0])*lr[1][0]; pw.y=__expf(c[1])*lr[1][1];
      pw.z=__expf(c[2])*lr[1][2]; pw.w=__expf(c[3])*lr[1][3];
      *(float4*)&Ps[wv*32 + 16 + ln][16 + lq*4] = pw;
    }
    __syncthreads();
    if (LAST){
      int row = t>>3, seg = t&7;
      int q = q0 + row;
      if (q < NOUT){
        float* ak = attnk + ((size_t)bh*NOUT + q)*NIN + kc + seg*16;
        float* aq = attnq + ((size_t)bh*NOUT + q)*NIN + kc + seg*16;
#pragma unroll
        for (int s=0;s<4;s++){
          int kk = seg*16 + s*4;
          float4 p = make_float4(Ps[kk][row], Ps[kk+1][row], Ps[kk+2][row], Ps[kk+3][row]);
          float4 c4 = *(const float4*)&cis[kk];
          *(float4*)(ak + s*4) = p;
          float4 pq;
          pq.x = p.x*c4.x; pq.y = p.y*c4.y; pq.z = p.z*c4.z; pq.w = p.w*c4.w;
          *(float4*)(aq + s*4) = pq;
        }
      }
    }
    // PV: register-tiled, 8-way interleaved k-replica
#pragma unroll
    for (int ki=0; ki<16; ki++){
      int k = ki*8 + kr;
      f32x4 va = *(const f32x4*)&Vs[k][dg*4];
      f32x4 pa = *(const f32x4*)&Ps[k][qg*8];
      f32x4 pb = *(const f32x4*)&Ps[k][qg*8+4];
      acc[0] += va*pa[0]; acc[1] += va*pa[1]; acc[2] += va*pa[2]; acc[3] += va*pa[3];
      acc[4] += va*pb[0]; acc[5] += va*pb[1]; acc[6] += va*pb[2]; acc[7] += va*pb[3];
    }
  }
  // reduce across the 8 k-replicas (lanes differing in t&7)
#pragma unroll
  for (int off=1; off<8; off<<=1)
#pragma unroll
    for (int i=0;i<8;i++)
#pragma unroll
      for (int c=0;c<4;c++)
        acc[i][c] += __shfl_xor(acc[i][c], off);
  if (kr == 0){
#pragma unroll
    for (int qi=0; qi<8; qi++){
      int q = q0 + qg*8 + qi;
      if (q < NOUT){
        float4 o; o.x=acc[qi][0]; o.y=acc[qi][1]; o.z=acc[qi][2]; o.w=acc[qi][3];
        *(float4*)(upd + ((size_t)bh*NOUT + q)*HD + dg*4) = o;
      }
    }
  }
}

__global__ __launch_bounds__(256)
void copyk(const float* __restrict__ src, float* __restrict__ dst, int n){
  int i = blockIdx.x*256 + threadIdx.x;
  if (i < n) dst[i] = src[i];
}

// --------------------------------------------------------------------------
extern "C" void kernel_launch(void* const* d_in, const int* in_sizes, int n_in,
                              void* d_out, int out_size, void* d_ws, size_t ws_size,
                              hipStream_t stream){
  (void)in_sizes; (void)n_in; (void)out_size; (void)ws_size;
  const float* px    = (const float*)d_in[0];
  const float* pcw   = (const float*)d_in[1];
  const float* pcb   = (const float*)d_in[2];
  const float* pkvw  = (const float*)d_in[3];
  const float* pkvb  = (const float*)d_in[4];
  const float* pqw   = (const float*)d_in[5];
  const float* pqb   = (const float*)d_in[6];
  const float* pw1   = (const float*)d_in[7];
  const float* pb1   = (const float*)d_in[8];
  const float* pw2   = (const float*)d_in[9];
  const float* pb2   = (const float*)d_in[10];
  const float* pg1   = (const float*)d_in[11];
  const float* pbe1  = (const float*)d_in[12];
  const float* pg2   = (const float*)d_in[13];
  const float* pbe2  = (const float*)d_in[14];
  const float* pg3   = (const float*)d_in[15];
  const float* pbe3  = (const float*)d_in[16];
  const float* ptemp = (const float*)d_in[17];
  const float* prf   = (const float*)d_in[18];

  float* out = (float*)d_out;
  float* ws  = (float*)d_ws;

  float* xout   = ws + OXOUT;
  ushort* kb    = (ushort*)(ws + OKB);
  float* vhb    = ws + OVH;
  ushort* qb    = (ushort*)(ws + OQB);
  float* qp     = ws + OQP;
  float* l0inv  = ws + OL0;
  float* csinv  = ws + OCS;
  float* l0part = ws + OLP;
  float* updb   = ws + OUPD;
  float* h1     = ws + OH1;
  float* h2p    = ws + OH2;
  ushort* qwb   = (ushort*)(ws + OQWB);
  ushort* w1b   = (ushort*)(ws + OW1B);
  ushort* w2b   = (ushort*)(ws + OW2B);

  // d_out regions double as scratch until the attn outputs are written (it==2)
  float* attnq = out + 371712;
  float* attnk = out + 371712 + 47579136;
  float* kvbuf = attnq;                         // dead before attn_q written
  float* cpart = attnq + 8388608;               // 49*968*384 f, dead after ln1
  ushort* wtb  = (ushort*)attnk;                // dead after conv
  ushort* xb16 = (ushort*)(attnk + 3612672);    // dead after kv gemm
  ushort* kvwb = (ushort*)(attnk + 3612672 + 1572864);  // dead after kv gemm

  // ---- packing (loop-invariant) ----
  packxk<<<dim3((MIN_*D_/4 + 255)/256), 256, 0, stream>>>(px, xb16);
  wtk2  <<<dim3((CK*D_ + 255)/256), 256, 0, stream>>>(pcw, wtb);
  packwk<<<dim3((384*768 + 255)/256), 256, 0, stream>>>(pkvw, kvwb, 384, 768);
  packwk<<<dim3((384*384 + 255)/256), 256, 0, stream>>>(pqw,  qwb,  384, 384);
  packwk<<<dim3((384*1536 + 255)/256), 256, 0, stream>>>(pw1, w1b, 384, 1536);
  packwk<<<dim3((1536*384 + 255)/256), 256, 0, stream>>>(pw2, w2b, 1536, 384);

  // ---- precompute (loop-invariant) ----
  convm<<<dim3(8,3,NSLICE), 256, 0, stream>>>(xb16, wtb, cpart);
  lnk<0><<<dim3(MOUT), 384, 0, stream>>>(cpart, pcb, pg1, pbe1, xout);
  gemmm<0,true><<<dim3(64,6), 256, 0, stream>>>(xb16, kvwb, pkvb, kvbuf, MIN_, 768, 384);
  rosek<<<dim3((BB*H_*NIN+255)/256), 256, 0, stream>>>(kvbuf, prf, ptemp, kb, vhb);

  // ---- 3 iterations ----
  for (int it=0; it<3; ++it){
    gemmm<0,false><<<dim3(8,3), 256, 0, stream>>>(xout, qwb, pqb, qp, MOUT, 384, 384);
    roseq<<<dim3(48), 256, 0, stream>>>(qp, prf, qb);
    rowk<<<dim3(8,16,24), 256, 0, stream>>>(qb, kb, l0part);
    l0red<<<dim3(48), 256, 0, stream>>>(l0part, l0inv);
    colk_f<<<dim3(16,24), 256, 0, stream>>>(qb, kb, l0inv, csinv);
    if (it==2){
      pv_f<true ><<<dim3(16,24), 256, 0, stream>>>(qb, kb, vhb, l0inv, csinv, updb, attnq, attnk);
    } else {
      pv_f<false><<<dim3(16,24), 256, 0, stream>>>(qb, kb, vhb, l0inv, csinv, updb, attnq, attnk);
    }
    lnk<1><<<dim3(MOUT), 384, 0, stream>>>(updb, pcb, pg2, pbe2, xout);
    gemmm<1,false><<<dim3(8,12), 256, 0, stream>>>(xout, w1b, pb1, h1, MOUT, 1536, 384);
    gemmsk<<<dim3(8,3,4), 256, 0, stream>>>(h1, w2b, h2p);
    lnk<3><<<dim3(MOUT), 384, 0, stream>>>(h2p, pb2, pg3, pbe3, xout);
  }

  copyk<<<dim3((371712+255)/256), 256, 0, stream>>>(xout, out, 371712);
}

// Round 8
// 1171.411 us; speedup vs baseline: 1.7687x; 1.1477x over previous
//
#include <hip/hip_runtime.h>
#include <math.h>

// ---------------- problem constants ----------------
#define BB 2
#define D_ 384
#define H_ 12
#define HD 32
#define NIN 4096            // 64*64
#define NOUT 484            // 22*22
#define MOUT (BB*NOUT)      // 968
#define MIN_ (BB*NIN)       // 8192
#define QW_ 22
#define CK 18816            // D*7*7
#define NSLICE 49           // conv split-K: one slice per (ky,kx), K=384 each
#define LN_EPS 1e-5f
#define EPS_ 1.1920929e-07f

typedef short bf16x8 __attribute__((ext_vector_type(8)));
typedef float f32x4  __attribute__((ext_vector_type(4)));

__device__ __forceinline__ unsigned f2bf(float f){   // RNE fp32->bf16 bits
  unsigned u = __float_as_uint(f);
  u += 0x7fffu + ((u>>16)&1u);
  return u>>16;
}

// ---------------- ws layout (floats) ----------------
static const size_t OXOUT = 0;                       // 371712
static const size_t OKB   = 371712;                  // K bf16: 24*4096*32 ush = 1572864 f
static const size_t OVH   = OKB + 1572864;           // V fp32: 3145728
static const size_t OQB   = OVH + 3145728;           // Q bf16: 24*512*32 ush = 196608 f
static const size_t OQP   = OQB + 196608;            // 371712
static const size_t OL0   = OQP + 371712;            // 12288
static const size_t OCS   = OL0 + 12288;             // 98304
static const size_t OLP   = OCS + 98304;             // 196608
static const size_t OUPD  = OLP + 196608;            // 371712
static const size_t OH1   = OUPD + 371712;           // 1486848
static const size_t OH2   = OH1 + 1486848;           // 4*371712 = 1486848 (mlp2 split-K parts)
static const size_t OQWB  = OH2 + 1486848;           // 73728
static const size_t OW1B  = OQWB + 73728;            // 294912
static const size_t OW2B  = OW1B + 294912;           // 294912
// total = 9,974,784 floats = 39.9 MB

// ---------------- packing kernels ----------------
__global__ __launch_bounds__(256)
void packxk(const float* __restrict__ x, ushort* __restrict__ xb){
  int i = blockIdx.x*256 + threadIdx.x;
  int base = i*4;
  if (base >= MIN_*D_) return;
  float4 v = *(const float4*)(x + base);
  uint2 o;
  o.x = f2bf(v.x) | (f2bf(v.y)<<16);
  o.y = f2bf(v.z) | (f2bf(v.w)<<16);
  *(uint2*)(xb + base) = o;
}

// conv_w [n][di][ky][kx] -> Wtb[kyx][n][di] (bf16)
__global__ __launch_bounds__(256)
void wtk2(const float* __restrict__ cw, ushort* __restrict__ wtb){
  int i = blockIdx.x*256 + threadIdx.x;
  if (i >= CK*D_) return;
  int n = i / CK;
  int r = i - n*CK;           // di*49 + kyx
  int di = r/49, kyx = r - di*49;
  wtb[((size_t)kyx*D_ + n)*D_ + di] = (ushort)f2bf(cw[i]);
}

// w[k][n] fp32 -> wb[n][k] bf16
__global__ __launch_bounds__(256)
void packwk(const float* __restrict__ w, ushort* __restrict__ wb, int K, int N){
  int i = blockIdx.x*256 + threadIdx.x;
  if (i >= K*N) return;
  int k = i / N, n = i - k*N;
  wb[(size_t)n*K + k] = (ushort)f2bf(w[i]);
}

// -------- MFMA conv: per-slice GEMM, 128x128 tile, 4 waves x (4x4) 16x16x32 --------
__global__ __launch_bounds__(256)
void convm(const ushort* __restrict__ xb, const ushort* __restrict__ wtb,
           float* __restrict__ part){
  __shared__ ushort As[128][40];
  __shared__ ushort Bs[128][40];
  const int t  = threadIdx.x;
  const int m0 = blockIdx.x*128, n0 = blockIdx.y*128, z = blockIdx.z;
  const int ky = z/7, kx = z - ky*7;
  const int r = t>>1, half = t&1;
  const int m = m0 + r;
  const int mq = (m < MOUT) ? m : 0;
  const int bbv = mq/NOUT, qq = mq - bbv*NOUT;
  const int oy = qq/QW_, ox = qq - oy*QW_;
  const int iy = oy*3-3+ky, ix = ox*3-3+kx;
  const bool aval = (m<MOUT) && iy>=0 && iy<64 && ix>=0 && ix<64;
  const ushort* asrc = xb + ((size_t)bbv*NIN + (aval ? iy*64+ix : 0))*D_ + half*16;
  const ushort* bsrc = wtb + ((size_t)z*D_ + n0 + r)*D_ + half*16;

  const int wv = t>>6;
  const int wr = (wv>>1)*64, wc = (wv&1)*64;
  const int ln = t&15, lq = (t>>4)&3;

  f32x4 acc[4][4];
#pragma unroll
  for (int i=0;i<4;i++)
#pragma unroll
    for (int j=0;j<4;j++) acc[i][j] = (f32x4){0.f,0.f,0.f,0.f};

  for (int dk=0; dk<D_; dk+=32){
    uint4 a0 = {0,0,0,0}, a1 = {0,0,0,0};
    if (aval){ a0 = *(const uint4*)(asrc+dk); a1 = *(const uint4*)(asrc+dk+8); }
    uint4 b0 = *(const uint4*)(bsrc+dk), b1 = *(const uint4*)(bsrc+dk+8);
    *(uint4*)&As[r][half*16]   = a0;  *(uint4*)&As[r][half*16+8] = a1;
    *(uint4*)&Bs[r][half*16]   = b0;  *(uint4*)&Bs[r][half*16+8] = b1;
    __syncthreads();
    bf16x8 af[4], bfr[4];
#pragma unroll
    for (int i=0;i<4;i++) af[i]  = *(const bf16x8*)&As[wr+i*16+ln][lq*8];
#pragma unroll
    for (int j=0;j<4;j++) bfr[j] = *(const bf16x8*)&Bs[wc+j*16+ln][lq*8];
#pragma unroll
    for (int i=0;i<4;i++)
#pragma unroll
      for (int j=0;j<4;j++)
        acc[i][j] = __builtin_amdgcn_mfma_f32_16x16x32_bf16(af[i], bfr[j], acc[i][j], 0,0,0);
    __syncthreads();
  }
#pragma unroll
  for (int i=0;i<4;i++){
    int rowb = m0 + wr + i*16 + lq*4;
#pragma unroll
    for (int j=0;j<4;j++){
      int col = n0 + wc + j*16 + ln;
#pragma unroll
      for (int rg=0; rg<4; rg++){
        int row = rowb + rg;
        if (row < MOUT) part[((size_t)z*MOUT + row)*D_ + col] = acc[i][j][rg];
      }
    }
  }
}

// -------- MFMA GEMM: C = A[M,K]*W[K,N] + bias, W pre-packed as Wb[n][k] bf16 -----
template<int ACT, bool ABF>
__global__ __launch_bounds__(256)
void gemmm(const void* __restrict__ Ain, const ushort* __restrict__ Wb,
           const float* __restrict__ bias, float* __restrict__ C,
           int M, int N, int K){
  __shared__ ushort As[128][40];
  __shared__ ushort Bs[128][40];
  const int t  = threadIdx.x;
  const int m0 = blockIdx.x*128, n0 = blockIdx.y*128;
  const int r = t>>1, half = t&1;
  const int m = m0 + r;
  const bool aval = (m < M);
  const float*  af32 = (const float*)Ain  + (size_t)(aval?m:0)*K + half*16;
  const ushort* ab16 = (const ushort*)Ain + (size_t)(aval?m:0)*K + half*16;
  const ushort* bsrc = Wb + (size_t)(n0 + r)*K + half*16;

  const int wv = t>>6;
  const int wr = (wv>>1)*64, wc = (wv&1)*64;
  const int ln = t&15, lq = (t>>4)&3;

  f32x4 acc[4][4];
#pragma unroll
  for (int i=0;i<4;i++)
#pragma unroll
    for (int j=0;j<4;j++) acc[i][j] = (f32x4){0.f,0.f,0.f,0.f};

  for (int dk=0; dk<K; dk+=32){
    uint4 a0 = {0,0,0,0}, a1 = {0,0,0,0};
    if (aval){
      if (ABF){
        a0 = *(const uint4*)(ab16+dk); a1 = *(const uint4*)(ab16+dk+8);
      } else {
        float4 f0 = *(const float4*)(af32+dk),   f1 = *(const float4*)(af32+dk+4);
        float4 f2 = *(const float4*)(af32+dk+8), f3 = *(const float4*)(af32+dk+12);
        a0.x = f2bf(f0.x)|(f2bf(f0.y)<<16); a0.y = f2bf(f0.z)|(f2bf(f0.w)<<16);
        a0.z = f2bf(f1.x)|(f2bf(f1.y)<<16); a0.w = f2bf(f1.z)|(f2bf(f1.w)<<16);
        a1.x = f2bf(f2.x)|(f2bf(f2.y)<<16); a1.y = f2bf(f2.z)|(f2bf(f2.w)<<16);
        a1.z = f2bf(f3.x)|(f2bf(f3.y)<<16); a1.w = f2bf(f3.z)|(f2bf(f3.w)<<16);
      }
    }
    uint4 b0 = *(const uint4*)(bsrc+dk), b1 = *(const uint4*)(bsrc+dk+8);
    *(uint4*)&As[r][half*16]   = a0;  *(uint4*)&As[r][half*16+8] = a1;
    *(uint4*)&Bs[r][half*16]   = b0;  *(uint4*)&Bs[r][half*16+8] = b1;
    __syncthreads();
    bf16x8 af[4], bfr[4];
#pragma unroll
    for (int i=0;i<4;i++) af[i]  = *(const bf16x8*)&As[wr+i*16+ln][lq*8];
#pragma unroll
    for (int j=0;j<4;j++) bfr[j] = *(const bf16x8*)&Bs[wc+j*16+ln][lq*8];
#pragma unroll
    for (int i=0;i<4;i++)
#pragma unroll
      for (int j=0;j<4;j++)
        acc[i][j] = __builtin_amdgcn_mfma_f32_16x16x32_bf16(af[i], bfr[j], acc[i][j], 0,0,0);
    __syncthreads();
  }
#pragma unroll
  for (int i=0;i<4;i++){
    int rowb = m0 + wr + i*16 + lq*4;
#pragma unroll
    for (int j=0;j<4;j++){
      int col = n0 + wc + j*16 + ln;
      float bv = bias[col];
#pragma unroll
      for (int rg=0; rg<4; rg++){
        int row = rowb + rg;
        if (row < M){
          float v = acc[i][j][rg] + bv;
          if (ACT==1) v = 0.5f*v*(1.f + erff(v*0.7071067811865475f));
          C[(size_t)row*N + col] = v;
        }
      }
    }
  }
}

// -------- mlp2 split-K: part[z] = h1[:, z*384:(z+1)*384] @ W2slice (no bias) -----
__global__ __launch_bounds__(256)
void gemmsk(const float* __restrict__ Ain, const ushort* __restrict__ Wb,
            float* __restrict__ part){
  __shared__ ushort As[128][40];
  __shared__ ushort Bs[128][40];
  const int t  = threadIdx.x;
  const int m0 = blockIdx.x*128, n0 = blockIdx.y*128, z = blockIdx.z;
  const int r = t>>1, half = t&1;
  const int m = m0 + r;
  const bool aval = (m < MOUT);
  const float*  af32 = Ain + (size_t)(aval?m:0)*1536 + z*384 + half*16;
  const ushort* bsrc = Wb + (size_t)(n0 + r)*1536 + z*384 + half*16;

  const int wv = t>>6;
  const int wr = (wv>>1)*64, wc = (wv&1)*64;
  const int ln = t&15, lq = (t>>4)&3;

  f32x4 acc[4][4];
#pragma unroll
  for (int i=0;i<4;i++)
#pragma unroll
    for (int j=0;j<4;j++) acc[i][j] = (f32x4){0.f,0.f,0.f,0.f};

  for (int dk=0; dk<384; dk+=32){
    uint4 a0 = {0,0,0,0}, a1 = {0,0,0,0};
    if (aval){
      float4 f0 = *(const float4*)(af32+dk),   f1 = *(const float4*)(af32+dk+4);
      float4 f2 = *(const float4*)(af32+dk+8), f3 = *(const float4*)(af32+dk+12);
      a0.x = f2bf(f0.x)|(f2bf(f0.y)<<16); a0.y = f2bf(f0.z)|(f2bf(f0.w)<<16);
      a0.z = f2bf(f1.x)|(f2bf(f1.y)<<16); a0.w = f2bf(f1.z)|(f2bf(f1.w)<<16);
      a1.x = f2bf(f2.x)|(f2bf(f2.y)<<16); a1.y = f2bf(f2.z)|(f2bf(f2.w)<<16);
      a1.z = f2bf(f3.x)|(f2bf(f3.y)<<16); a1.w = f2bf(f3.z)|(f2bf(f3.w)<<16);
    }
    uint4 b0 = *(const uint4*)(bsrc+dk), b1 = *(const uint4*)(bsrc+dk+8);
    *(uint4*)&As[r][half*16]   = a0;  *(uint4*)&As[r][half*16+8] = a1;
    *(uint4*)&Bs[r][half*16]   = b0;  *(uint4*)&Bs[r][half*16+8] = b1;
    __syncthreads();
    bf16x8 af[4], bfr[4];
#pragma unroll
    for (int i=0;i<4;i++) af[i]  = *(const bf16x8*)&As[wr+i*16+ln][lq*8];
#pragma unroll
    for (int j=0;j<4;j++) bfr[j] = *(const bf16x8*)&Bs[wc+j*16+ln][lq*8];
#pragma unroll
    for (int i=0;i<4;i++)
#pragma unroll
      for (int j=0;j<4;j++)
        acc[i][j] = __builtin_amdgcn_mfma_f32_16x16x32_bf16(af[i], bfr[j], acc[i][j], 0,0,0);
    __syncthreads();
  }
#pragma unroll
  for (int i=0;i<4;i++){
    int rowb = m0 + wr + i*16 + lq*4;
#pragma unroll
    for (int j=0;j<4;j++){
      int col = n0 + wc + j*16 + ln;
#pragma unroll
      for (int rg=0; rg<4; rg++){
        int row = rowb + rg;
        if (row < MOUT) part[((size_t)z*MOUT + row)*D_ + col] = acc[i][j][rg];
      }
    }
  }
}

// ---------------- block reduction over 384 threads --------------------------
__device__ __forceinline__ float block_sum_384(float v){
  __shared__ float red[6];
#pragma unroll
  for (int o=32;o>0;o>>=1) v += __shfl_down(v,o);
  const int lane = threadIdx.x & 63, w = threadIdx.x >> 6;
  __syncthreads();
  if (lane==0) red[w] = v;
  __syncthreads();
  return red[0]+red[1]+red[2]+red[3]+red[4]+red[5];
}

// LN kernel. MODE 0: in = 49 conv partials (+bias cb) -> write xout
//            MODE 1: in = upd[bh][q][hd] gathered -> xout += LN
//            MODE 2: in = h2[m][d] -> xout += LN
//            MODE 3: in = 4 mlp2 partials (+bias cb) -> xout += LN
template<int MODE>
__global__ __launch_bounds__(384)
void lnk(const float* __restrict__ in, const float* __restrict__ cb,
         const float* __restrict__ gg, const float* __restrict__ bb,
         float* __restrict__ xout){
  const int m = blockIdx.x, d = threadIdx.x;
  float v;
  if (MODE==0){
    v = cb[d];
    for (int z=0; z<NSLICE; z++) v += in[((size_t)z*MOUT + m)*D_ + d];
  } else if (MODE==1){
    int b = m/NOUT, q = m - b*NOUT;
    int h = d>>5, dd2 = d&31;
    v = in[(((size_t)(b*H_ + h))*NOUT + q)*HD + dd2];
  } else if (MODE==2){
    v = in[(size_t)m*D_ + d];
  } else {
    v = cb[d];
#pragma unroll
    for (int z=0; z<4; z++) v += in[((size_t)z*MOUT + m)*D_ + d];
  }
  float mu  = block_sum_384(v) * (1.f/D_);
  float ce  = v - mu;
  float var = block_sum_384(ce*ce) * (1.f/D_);
  float o = ce * rsqrtf(var + LN_EPS) * gg[d] + bb[d];
  float* dst = xout + (size_t)m*D_ + d;
  if (MODE==0) *dst = o;
  else *dst += o;
}

// ------------- rose for K (+ temp scale, bf16 pack) and V gather ------------
__global__ __launch_bounds__(256)
void rosek(const float* __restrict__ kvbuf, const float* __restrict__ rf,
           const float* __restrict__ temp,
           ushort* __restrict__ kb, float* __restrict__ vhb){
  int idx = blockIdx.x*256 + threadIdx.x;
  if (idx >= BB*H_*NIN) return;
  int n  = idx & (NIN-1);
  int bh = idx >> 12;
  int h  = bh % H_;
  int b  = bh / H_;
  float T = temp[0];
  int iy = n >> 6, ix = n & 63;
  const float* src = kvbuf + ((size_t)b*NIN + n)*768 + h*HD;
  float xv[HD];
#pragma unroll
  for (int d4=0; d4<8; d4++){
    float4 v = *(const float4*)(src + d4*4);
    xv[d4*4]=v.x; xv[d4*4+1]=v.y; xv[d4*4+2]=v.z; xv[d4*4+3]=v.w;
  }
  float out[HD];
#pragma unroll
  for (int tp=0; tp<8; tp++){
    int s2 = tp >> 2, p2 = tp & 3;
    float coord = (s2==0) ? (float)iy : (float)ix;
    float ang = coord * rf[(h*2+s2)*4 + p2];
    float sn, cn; sincosf(ang, &sn, &cn);
    float x1 = xv[2*tp], x2 = xv[2*tp+1];
    out[2*tp]   = x1*cn - x2*sn;
    out[2*tp+1] = x1*sn + x2*cn;
  }
#pragma unroll
  for (int d=16; d<HD; d++) out[d] = xv[d];
  ushort* dk = kb + ((size_t)bh*NIN + n)*HD;
#pragma unroll
  for (int g=0; g<4; g++){
    uint4 o;
    o.x = f2bf(T*out[g*8+0]) | (f2bf(T*out[g*8+1])<<16);
    o.y = f2bf(T*out[g*8+2]) | (f2bf(T*out[g*8+3])<<16);
    o.z = f2bf(T*out[g*8+4]) | (f2bf(T*out[g*8+5])<<16);
    o.w = f2bf(T*out[g*8+6]) | (f2bf(T*out[g*8+7])<<16);
    *(uint4*)(dk + g*8) = o;
  }
  const float* vs = src + D_;
  float* dv = vhb + ((size_t)bh*NIN + n)*HD;
#pragma unroll
  for (int d4=0; d4<8; d4++)
    *(float4*)(dv + d4*4) = *(const float4*)(vs + d4*4);
}

// ------------- rose for Q (grid 22x22, spacing 3.0) -> bf16, padded to 512 --
__global__ __launch_bounds__(256)
void roseq(const float* __restrict__ qp, const float* __restrict__ rf,
           ushort* __restrict__ qb){
  int idx = blockIdx.x*256 + threadIdx.x;      // < 24*512
  int q  = idx & 511;
  int bh = idx >> 9;
  int h  = bh % H_;
  int b  = bh / H_;
  ushort* dq = qb + ((size_t)bh*512 + q)*HD;
  if (q >= NOUT){
    uint4 z = {0,0,0,0};
#pragma unroll
    for (int g=0; g<4; g++) *(uint4*)(dq + g*8) = z;
    return;
  }
  int oy = q / QW_, ox = q - oy*QW_;
  const float* src = qp + ((size_t)b*NOUT + q)*D_ + h*HD;
  float xv[HD];
#pragma unroll
  for (int d4=0; d4<8; d4++){
    float4 v = *(const float4*)(src + d4*4);
    xv[d4*4]=v.x; xv[d4*4+1]=v.y; xv[d4*4+2]=v.z; xv[d4*4+3]=v.w;
  }
  float out[HD];
#pragma unroll
  for (int tp=0; tp<8; tp++){
    int s2 = tp >> 2, p2 = tp & 3;
    float coord = (s2==0) ? 3.0f*(float)oy : 3.0f*(float)ox;
    float ang = coord * rf[(h*2+s2)*4 + p2];
    float sn, cn; sincosf(ang, &sn, &cn);
    float x1 = xv[2*tp], x2 = xv[2*tp+1];
    out[2*tp]   = x1*cn - x2*sn;
    out[2*tp+1] = x1*sn + x2*cn;
  }
#pragma unroll
  for (int d=16; d<HD; d++) out[d] = xv[d];
#pragma unroll
  for (int g=0; g<4; g++){
    uint4 o;
    o.x = f2bf(out[g*8+0]) | (f2bf(out[g*8+1])<<16);
    o.y = f2bf(out[g*8+2]) | (f2bf(out[g*8+3])<<16);
    o.z = f2bf(out[g*8+4]) | (f2bf(out[g*8+5])<<16);
    o.w = f2bf(out[g*8+6]) | (f2bf(out[g*8+7])<<16);
    *(uint4*)(dq + g*8) = o;
  }
}

// ------- rowk: MFMA QK^T (64q x 256k), exp, rowsum partials (no E store) ----
__global__ __launch_bounds__(256)
void rowk(const ushort* __restrict__ qb, const ushort* __restrict__ kb,
          float* __restrict__ l0part){
  __shared__ ushort Qs[64][40];
  __shared__ ushort Ks[256][40];
  __shared__ float  red[4][64];
  const int t  = threadIdx.x;
  const int q0 = blockIdx.x*64;
  const int kt = blockIdx.y;
  const int k0 = kt*256;
  const int bh = blockIdx.z;
  {  // stage Q: 64 rows x 32 ush
    int row = t>>2, seg = t&3;
    const ushort* src = qb + ((size_t)bh*512 + q0 + row)*HD + seg*8;
    *(uint4*)&Qs[row][seg*8] = *(const uint4*)src;
  }
  {  // stage K: 256 rows x 32 ush
    const ushort* src = kb + ((size_t)bh*NIN + k0 + t)*HD;
#pragma unroll
    for (int g=0; g<4; g++)
      *(uint4*)&Ks[t][g*8] = *(const uint4*)(src + g*8);
  }
  __syncthreads();
  const int wv = t>>6;
  const int wc = wv*64;
  const int ln = t&15, lq = (t>>4)&3;
  bf16x8 af[4], bfr[4];
#pragma unroll
  for (int i=0;i<4;i++) af[i]  = *(const bf16x8*)&Qs[i*16+ln][lq*8];
#pragma unroll
  for (int j=0;j<4;j++) bfr[j] = *(const bf16x8*)&Ks[wc+j*16+ln][lq*8];
  f32x4 acc[4][4];
  const f32x4 zero = (f32x4){0.f,0.f,0.f,0.f};
#pragma unroll
  for (int i=0;i<4;i++)
#pragma unroll
    for (int j=0;j<4;j++)
      acc[i][j] = __builtin_amdgcn_mfma_f32_16x16x32_bf16(af[i], bfr[j], zero, 0,0,0);
  float rs[4][4];
#pragma unroll
  for (int i=0;i<4;i++){
#pragma unroll
    for (int rg=0; rg<4; rg++){
      float s = 0.f;
#pragma unroll
      for (int j=0;j<4;j++) s += __expf(acc[i][j][rg]);
      rs[i][rg] = s;
    }
  }
#pragma unroll
  for (int i=0;i<4;i++)
#pragma unroll
    for (int rg=0;rg<4;rg++){
      float v = rs[i][rg];
      v += __shfl_xor(v,1); v += __shfl_xor(v,2);
      v += __shfl_xor(v,4); v += __shfl_xor(v,8);
      rs[i][rg] = v;
    }
  if (ln==0){
#pragma unroll
    for (int i=0;i<4;i++)
#pragma unroll
      for (int rg=0;rg<4;rg++)
        red[wv][i*16+lq*4+rg] = rs[i][rg];
  }
  __syncthreads();
  if (t < 64){
    float tot = red[0][t]+red[1][t]+red[2][t]+red[3][t];
    l0part[((size_t)bh*512 + q0 + t)*16 + kt] = tot;
  }
}

// ------- l0red: l0inv[bh][q] = 1 / sum over 16 k-tile partials --------------
__global__ __launch_bounds__(256)
void l0red(const float* __restrict__ lp, float* __restrict__ l0inv){
  int i = blockIdx.x*256 + threadIdx.x;          // < 24*512
  const float4* p = (const float4*)(lp + (size_t)i*16);
  float4 a=p[0], b=p[1], c=p[2], d=p[3];
  float s = a.x+a.y+a.z+a.w + b.x+b.y+b.z+b.w + c.x+c.y+c.z+c.w + d.x+d.y+d.z+d.w;
  l0inv[i] = 1.f/s;
}

// ------- colk_f: recompute S^T via MFMA (A=K, B=Q); csinv[k]=1/(sum_q E*li+EPS)
__global__ __launch_bounds__(256)
void colk_f(const ushort* __restrict__ qb, const ushort* __restrict__ kb,
            const float* __restrict__ l0inv, float* __restrict__ csinv){
  __shared__ ushort Ks[256][40];
  __shared__ ushort Qs[64][40];
  __shared__ float  lis[64];
  const int t  = threadIdx.x;
  const int k0 = blockIdx.x*256;
  const int bh = blockIdx.y;
  {  // stage K tile once: 256 rows x 32 ush
    const ushort* src = kb + ((size_t)bh*NIN + k0 + t)*HD;
#pragma unroll
    for (int g=0; g<4; g++)
      *(uint4*)&Ks[t][g*8] = *(const uint4*)(src + g*8);
  }
  const int wv = t>>6, ln = t&15, lq = (t>>4)&3;
  const f32x4 zero = (f32x4){0.f,0.f,0.f,0.f};
  f32x4 colacc[4];
#pragma unroll
  for (int i=0;i<4;i++) colacc[i] = zero;
  for (int qc=0; qc<512; qc+=64){
    __syncthreads();
    {  // stage Q chunk: 64 rows x 32 ush
      int row = t>>2, seg = t&3;
      *(uint4*)&Qs[row][seg*8] =
        *(const uint4*)(qb + ((size_t)bh*512 + qc + row)*HD + seg*8);
    }
    if (t < 64){
      int q = qc + t;
      lis[t] = (q < NOUT) ? l0inv[(size_t)bh*512 + q] : 0.f;
    }
    __syncthreads();
    bf16x8 af[4], bfr[4];
#pragma unroll
    for (int i=0;i<4;i++) af[i]  = *(const bf16x8*)&Ks[wv*64+i*16+ln][lq*8];
#pragma unroll
    for (int j=0;j<4;j++) bfr[j] = *(const bf16x8*)&Qs[j*16+ln][lq*8];
#pragma unroll
    for (int j=0;j<4;j++){
      float liv = lis[j*16+ln];
#pragma unroll
      for (int i=0;i<4;i++){
        f32x4 c = __builtin_amdgcn_mfma_f32_16x16x32_bf16(af[i], bfr[j], zero, 0,0,0);
#pragma unroll
        for (int rg=0;rg<4;rg++)
          colacc[i][rg] += __expf(c[rg]) * liv;
      }
    }
  }
#pragma unroll
  for (int i=0;i<4;i++)
#pragma unroll
    for (int rg=0;rg<4;rg++){
      float v = colacc[i][rg];
      v += __shfl_xor(v,1); v += __shfl_xor(v,2);
      v += __shfl_xor(v,4); v += __shfl_xor(v,8);
      colacc[i][rg] = v;
    }
  if (ln==0){
#pragma unroll
    for (int i=0;i<4;i++){
      float4 o;
      o.x = 1.f/(colacc[i][0] + EPS_);
      o.y = 1.f/(colacc[i][1] + EPS_);
      o.z = 1.f/(colacc[i][2] + EPS_);
      o.w = 1.f/(colacc[i][3] + EPS_);
      *(float4*)(csinv + (size_t)bh*NIN + k0 + wv*64 + i*16 + lq*4) = o;
    }
  }
}

// ------- pv_f: recompute S via MFMA (K frags from L2); P=exp(S)*li fp32 in LDS;
//         PV via 3-term bf16x2-split MFMA (Phi*Vhi + Phi*Vlo + Plo*Vhi ~ fp32);
//         each wave owns k-quarter (S write, Vt write, PV read all wave-local);
//         LAST: write attnk = P, attnq = P*ci (cross-wave, needs barriers) ----
template<bool LAST>
__global__ __launch_bounds__(256)
void pv_f(const ushort* __restrict__ qb, const ushort* __restrict__ kb,
          const float* __restrict__ vh, const float* __restrict__ l0inv,
          const float* __restrict__ csinv, float* __restrict__ upd,
          float* __restrict__ attnq, float* __restrict__ attnk){
  __shared__ ushort   Qs[32][40];     // Q tile bf16
  __shared__ float    Ps[128][36];    // P fp32 [k][q]; reused as Ured at end
  __shared__ unsigned Vt[32][132];    // ci*V transposed [d][k], (bf16hi<<16)|bf16lo
  __shared__ float    lis[32];
  __shared__ float    cis[128];
  const int t  = threadIdx.x;
  const int q0 = blockIdx.x*32;
  const int bh = blockIdx.y;
  {  // stage Q bf16 once: 32 rows x 32 ush
    int row = t>>3, seg = t&7;
    *(uint2*)&Qs[row][seg*4] =
      *(const uint2*)(qb + ((size_t)bh*512 + q0 + row)*HD + seg*4);
  }
  if (t < 32){
    int q = q0 + t;
    lis[t] = (q < NOUT) ? l0inv[(size_t)bh*512 + q] : 0.f;
  }
  __syncthreads();
  const int wv = t>>6, ln = t&15, lq = (t>>4)&3;
  const bf16x8 af0 = *(const bf16x8*)&Qs[ln][lq*8];        // hoisted Q frags
  const bf16x8 af1 = *(const bf16x8*)&Qs[16+ln][lq*8];
  float lr[2][4];
#pragma unroll
  for (int i=0;i<2;i++)
#pragma unroll
    for (int rg=0;rg<4;rg++) lr[i][rg] = lis[i*16 + lq*4 + rg];
  const f32x4 zero = (f32x4){0.f,0.f,0.f,0.f};
  f32x4 acc[2][2];
  acc[0][0]=zero; acc[0][1]=zero; acc[1][0]=zero; acc[1][1]=zero;
  const ushort* kfrag = kb + ((size_t)bh*NIN)*HD;
  for (int kc=0; kc<NIN; kc+=128){
    if (LAST) __syncthreads();   // prev tile's cross-wave Ps/cis reads done
    {  // stage ci*V transposed, packed bf16 hi/lo; thread t covers col r=t>>1
      int r = t>>1, half = t&1;
      float civ = csinv[(size_t)bh*NIN + kc + r];
      if (half==0) cis[r] = civ;
      const float* pv = vh + ((size_t)bh*NIN + kc + r)*HD + half*16;
      float4 b0=*(const float4*)pv, b1=*(const float4*)(pv+4),
             b2=*(const float4*)(pv+8), b3=*(const float4*)(pv+12);
      float w[16] = {civ*b0.x, civ*b0.y, civ*b0.z, civ*b0.w,
                     civ*b1.x, civ*b1.y, civ*b1.z, civ*b1.w,
                     civ*b2.x, civ*b2.y, civ*b2.z, civ*b2.w,
                     civ*b3.x, civ*b3.y, civ*b3.z, civ*b3.w};
      int dbase = half*16;
#pragma unroll
      for (int i2=0;i2<16;i2++){
        unsigned hi = f2bf(w[i2]);
        float hif = __uint_as_float(hi<<16);
        unsigned lo = f2bf(w[i2] - hif);
        Vt[dbase+i2][r] = (hi<<16) | lo;
      }
    }
    // S via MFMA, wave-local rows wv*32..wv*32+31 of Ps
    bf16x8 bf0 = *(const bf16x8*)(kfrag + (size_t)(kc + wv*32 +      ln)*HD + lq*8);
    bf16x8 bf1 = *(const bf16x8*)(kfrag + (size_t)(kc + wv*32 + 16 + ln)*HD + lq*8);
    {
      f32x4 c; float4 pw;
      c = __builtin_amdgcn_mfma_f32_16x16x32_bf16(af0, bf0, zero, 0,0,0);
      pw.x=__expf(c[0])*lr[0][0]; pw.y=__expf(c[1])*lr[0][1];
      pw.z=__expf(c[2])*lr[0][2]; pw.w=__expf(c[3])*lr[0][3];
      *(float4*)&Ps[wv*32 +      ln][      lq*4] = pw;
      c = __builtin_amdgcn_mfma_f32_16x16x32_bf16(af1, bf0, zero, 0,0,0);
      pw.x=__expf(c[0])*lr[1][0]; pw.y=__expf(c[1])*lr[1][1];
      pw.z=__expf(c[2])*lr[1][2]; pw.w=__expf(c[3])*lr[1][3];
      *(float4*)&Ps[wv*32 +      ln][16 + lq*4] = pw;
      c = __builtin_amdgcn_mfma_f32_16x16x32_bf16(af0, bf1, zero, 0,0,0);
      pw.x=__expf(c[0])*lr[0][0]; pw.y=__expf(c[1])*lr[0][1];
      pw.z=__expf(c[2])*lr[0][2]; pw.w=__expf(c[3])*lr[0][3];
      *(float4*)&Ps[wv*32 + 16 + ln][      lq*4] = pw;
      c = __builtin_amdgcn_mfma_f32_16x16x32_bf16(af1, bf1, zero, 0,0,0);
      pw.x=__expf(c[0])*lr[1][0]; pw.y=__expf(c[1])*lr[1][1];
      pw.z=__expf(c[2])*lr[1][2]; pw.w=__expf(c[3])*lr[1][3];
      *(float4*)&Ps[wv*32 + 16 + ln][16 + lq*4] = pw;
    }
    if (LAST){
      __syncthreads();   // cross-wave Ps/cis for the coalesced output bounce
      int row = t>>3, seg = t&7;
      int q = q0 + row;
      if (q < NOUT){
        float* ak = attnk + ((size_t)bh*NOUT + q)*NIN + kc + seg*16;
        float* aq = attnq + ((size_t)bh*NOUT + q)*NIN + kc + seg*16;
#pragma unroll
        for (int s=0;s<4;s++){
          int kk = seg*16 + s*4;
          float4 p = make_float4(Ps[kk][row], Ps[kk+1][row], Ps[kk+2][row], Ps[kk+3][row]);
          float4 c4 = *(const float4*)&cis[kk];
          *(float4*)(ak + s*4) = p;
          float4 pq;
          pq.x = p.x*c4.x; pq.y = p.y*c4.y; pq.z = p.z*c4.z; pq.w = p.w*c4.w;
          *(float4*)(aq + s*4) = pq;
        }
      }
    }
    // PV via MFMA on this wave's 32-k chunk (Ps/Vt wave-local; compiler orders
    // same-wave ds_write->ds_read via lgkmcnt)
    bf16x8 bhi[2], blo[2];
#pragma unroll
    for (int nf=0;nf<2;nf++){
#pragma unroll
      for (int j=0;j<8;j++){
        float p = Ps[wv*32 + lq*8 + j][nf*16 + ln];
        unsigned hi = f2bf(p);
        float hif = __uint_as_float(hi<<16);
        unsigned lo = f2bf(p - hif);
        bhi[nf][j] = (short)hi;
        blo[nf][j] = (short)lo;
      }
    }
    bf16x8 ahi[2], alo[2];
#pragma unroll
    for (int mf=0;mf<2;mf++){
      const unsigned* vrow = &Vt[mf*16+ln][wv*32 + lq*8];
      uint4 wa = *(const uint4*)vrow;
      uint4 wb = *(const uint4*)(vrow+4);
      ahi[mf][0]=(short)(wa.x>>16); alo[mf][0]=(short)(wa.x&0xffffu);
      ahi[mf][1]=(short)(wa.y>>16); alo[mf][1]=(short)(wa.y&0xffffu);
      ahi[mf][2]=(short)(wa.z>>16); alo[mf][2]=(short)(wa.z&0xffffu);
      ahi[mf][3]=(short)(wa.w>>16); alo[mf][3]=(short)(wa.w&0xffffu);
      ahi[mf][4]=(short)(wb.x>>16); alo[mf][4]=(short)(wb.x&0xffffu);
      ahi[mf][5]=(short)(wb.y>>16); alo[mf][5]=(short)(wb.y&0xffffu);
      ahi[mf][6]=(short)(wb.z>>16); alo[mf][6]=(short)(wb.z&0xffffu);
      ahi[mf][7]=(short)(wb.w>>16); alo[mf][7]=(short)(wb.w&0xffffu);
    }
#pragma unroll
    for (int mf=0;mf<2;mf++)
#pragma unroll
      for (int nf=0;nf<2;nf++){
        acc[mf][nf] = __builtin_amdgcn_mfma_f32_16x16x32_bf16(ahi[mf], bhi[nf], acc[mf][nf], 0,0,0);
        acc[mf][nf] = __builtin_amdgcn_mfma_f32_16x16x32_bf16(ahi[mf], blo[nf], acc[mf][nf], 0,0,0);
        acc[mf][nf] = __builtin_amdgcn_mfma_f32_16x16x32_bf16(alo[mf], bhi[nf], acc[mf][nf], 0,0,0);
      }
  }
  // reduce the 4 per-wave k-quarter partials of U[d32][q32] via LDS (alias Ps)
  __syncthreads();
  float* Ured = &Ps[0][0];           // 4608 floats available, 4096 needed
  {
    int lane = t & 63;
#pragma unroll
    for (int mf=0;mf<2;mf++)
#pragma unroll
      for (int nf=0;nf<2;nf++)
#pragma unroll
        for (int rg=0;rg<4;rg++)
          Ured[wv*1024 + (mf*2+nf)*256 + rg*64 + lane] = acc[mf][nf][rg];
  }
  __syncthreads();
#pragma unroll
  for (int i=0;i<4;i++){
    int s = i*256 + t;
    float u = Ured[s] + Ured[1024+s] + Ured[2048+s] + Ured[3072+s];
    int grp = s>>8, rg = (s>>6)&3, lane = s&63;
    int mf = grp>>1, nf = grp&1;
    int q = q0 + nf*16 + (lane&15);
    int d = mf*16 + (lane>>4)*4 + rg;
    if (q < NOUT) upd[((size_t)bh*NOUT + q)*HD + d] = u;
  }
}

__global__ __launch_bounds__(256)
void copyk(const float* __restrict__ src, float* __restrict__ dst, int n){
  int i = blockIdx.x*256 + threadIdx.x;
  if (i < n) dst[i] = src[i];
}

// --------------------------------------------------------------------------
extern "C" void kernel_launch(void* const* d_in, const int* in_sizes, int n_in,
                              void* d_out, int out_size, void* d_ws, size_t ws_size,
                              hipStream_t stream){
  (void)in_sizes; (void)n_in; (void)out_size; (void)ws_size;
  const float* px    = (const float*)d_in[0];
  const float* pcw   = (const float*)d_in[1];
  const float* pcb   = (const float*)d_in[2];
  const float* pkvw  = (const float*)d_in[3];
  const float* pkvb  = (const float*)d_in[4];
  const float* pqw   = (const float*)d_in[5];
  const float* pqb   = (const float*)d_in[6];
  const float* pw1   = (const float*)d_in[7];
  const float* pb1   = (const float*)d_in[8];
  const float* pw2   = (const float*)d_in[9];
  const float* pb2   = (const float*)d_in[10];
  const float* pg1   = (const float*)d_in[11];
  const float* pbe1  = (const float*)d_in[12];
  const float* pg2   = (const float*)d_in[13];
  const float* pbe2  = (const float*)d_in[14];
  const float* pg3   = (const float*)d_in[15];
  const float* pbe3  = (const float*)d_in[16];
  const float* ptemp = (const float*)d_in[17];
  const float* prf   = (const float*)d_in[18];

  float* out = (float*)d_out;
  float* ws  = (float*)d_ws;

  float* xout   = ws + OXOUT;
  ushort* kb    = (ushort*)(ws + OKB);
  float* vhb    = ws + OVH;
  ushort* qb    = (ushort*)(ws + OQB);
  float* qp     = ws + OQP;
  float* l0inv  = ws + OL0;
  float* csinv  = ws + OCS;
  float* l0part = ws + OLP;
  float* updb   = ws + OUPD;
  float* h1     = ws + OH1;
  float* h2p    = ws + OH2;
  ushort* qwb   = (ushort*)(ws + OQWB);
  ushort* w1b   = (ushort*)(ws + OW1B);
  ushort* w2b   = (ushort*)(ws + OW2B);

  // d_out regions double as scratch until the attn outputs are written (it==2)
  float* attnq = out + 371712;
  float* attnk = out + 371712 + 47579136;
  float* kvbuf = attnq;                         // dead before attn_q written
  float* cpart = attnq + 8388608;               // 49*968*384 f, dead after ln1
  ushort* wtb  = (ushort*)attnk;                // dead after conv
  ushort* xb16 = (ushort*)(attnk + 3612672);    // dead after kv gemm
  ushort* kvwb = (ushort*)(attnk + 3612672 + 1572864);  // dead after kv gemm

  // ---- packing (loop-invariant) ----
  packxk<<<dim3((MIN_*D_/4 + 255)/256), 256, 0, stream>>>(px, xb16);
  wtk2  <<<dim3((CK*D_ + 255)/256), 256, 0, stream>>>(pcw, wtb);
  packwk<<<dim3((384*768 + 255)/256), 256, 0, stream>>>(pkvw, kvwb, 384, 768);
  packwk<<<dim3((384*384 + 255)/256), 256, 0, stream>>>(pqw,  qwb,  384, 384);
  packwk<<<dim3((384*1536 + 255)/256), 256, 0, stream>>>(pw1, w1b, 384, 1536);
  packwk<<<dim3((1536*384 + 255)/256), 256, 0, stream>>>(pw2, w2b, 1536, 384);

  // ---- precompute (loop-invariant) ----
  convm<<<dim3(8,3,NSLICE), 256, 0, stream>>>(xb16, wtb, cpart);
  lnk<0><<<dim3(MOUT), 384, 0, stream>>>(cpart, pcb, pg1, pbe1, xout);
  gemmm<0,true><<<dim3(64,6), 256, 0, stream>>>(xb16, kvwb, pkvb, kvbuf, MIN_, 768, 384);
  rosek<<<dim3((BB*H_*NIN+255)/256), 256, 0, stream>>>(kvbuf, prf, ptemp, kb, vhb);

  // ---- 3 iterations ----
  for (int it=0; it<3; ++it){
    gemmm<0,false><<<dim3(8,3), 256, 0, stream>>>(xout, qwb, pqb, qp, MOUT, 384, 384);
    roseq<<<dim3(48), 256, 0, stream>>>(qp, prf, qb);
    rowk<<<dim3(8,16,24), 256, 0, stream>>>(qb, kb, l0part);
    l0red<<<dim3(48), 256, 0, stream>>>(l0part, l0inv);
    colk_f<<<dim3(16,24), 256, 0, stream>>>(qb, kb, l0inv, csinv);
    if (it==2){
      pv_f<true ><<<dim3(16,24), 256, 0, stream>>>(qb, kb, vhb, l0inv, csinv, updb, attnq, attnk);
    } else {
      pv_f<false><<<dim3(16,24), 256, 0, stream>>>(qb, kb, vhb, l0inv, csinv, updb, attnq, attnk);
    }
    lnk<1><<<dim3(MOUT), 384, 0, stream>>>(updb, pcb, pg2, pbe2, xout);
    gemmm<1,false><<<dim3(8,12), 256, 0, stream>>>(xout, w1b, pb1, h1, MOUT, 1536, 384);
    gemmsk<<<dim3(8,3,4), 256, 0, stream>>>(h1, w2b, h2p);
    lnk<3><<<dim3(MOUT), 384, 0, stream>>>(h2p, pb2, pg3, pbe3, xout);
  }

  copyk<<<dim3((371712+255)/256), 256, 0, stream>>>(xout, out, 371712);
}

// Round 12
// 1067.362 us; speedup vs baseline: 1.9411x; 1.0975x over previous
//
#include <hip/hip_runtime.h>
#include <math.h>

// ---------------- problem constants ----------------
#define BB 2
#define D_ 384
#define H_ 12
#define HD 32
#define NIN 4096            // 64*64
#define NOUT 484            // 22*22
#define MOUT (BB*NOUT)      // 968
#define MIN_ (BB*NIN)       // 8192
#define QW_ 22
#define CK 18816            // D*7*7
#define NSLICE 49           // conv split-K: one slice per (ky,kx), K=384 each
#define LN_EPS 1e-5f
#define EPS_ 1.1920929e-07f

typedef short bf16x8 __attribute__((ext_vector_type(8)));
typedef float f32x4  __attribute__((ext_vector_type(4)));

__device__ __forceinline__ unsigned f2bf(float f){   // RNE fp32->bf16 bits
  unsigned u = __float_as_uint(f);
  u += 0x7fffu + ((u>>16)&1u);
  return u>>16;
}

// ---------------- ws layout (floats) ----------------
static const size_t OXOUT = 0;                       // 371712
static const size_t OKB   = 371712;                  // K bf16: 24*4096*32 ush = 1572864 f
static const size_t OVH   = OKB + 1572864;           // V fp32: 3145728
static const size_t OQB   = OVH + 3145728;           // Q bf16: 24*512*32 ush = 196608 f
static const size_t OQP   = OQB + 196608;            // 371712
static const size_t OL0   = OQP + 371712;            // 12288 (unused, kept for layout)
static const size_t OCS   = OL0 + 12288;             // 98304
static const size_t OLP   = OCS + 98304;             // 196608
static const size_t OUPD  = OLP + 196608;            // 371712
static const size_t OH1   = OUPD + 371712;           // 1486848
static const size_t OH2   = OH1 + 1486848;           // 4*371712 = 1486848 (mlp2 split-K parts)
static const size_t OQWB  = OH2 + 1486848;           // 73728
static const size_t OW1B  = OQWB + 73728;            // 294912
static const size_t OW2B  = OW1B + 294912;           // 294912
// total = 9,974,784 floats = 39.9 MB

// ---------------- fused packing kernel --------------------------------------
// block ranges: [0,3072) packxk | [3072,31296) wtk2 | [31296,32448) kv
//               [32448,33024) q | [33024,35328) w1 | [35328,37632) w2
__global__ __launch_bounds__(256)
void packall(const float* __restrict__ px,  ushort* __restrict__ xb,
             const float* __restrict__ cw,  ushort* __restrict__ wtb,
             const float* __restrict__ wkv, ushort* __restrict__ kvwb,
             const float* __restrict__ wq,  ushort* __restrict__ qwb,
             const float* __restrict__ w1,  ushort* __restrict__ w1b,
             const float* __restrict__ w2,  ushort* __restrict__ w2b){
  const int bid = blockIdx.x, t = threadIdx.x;
  if (bid < 3072){                       // x -> bf16, 4 floats/thread
    int base = (bid*256 + t)*4;
    float4 v = *(const float4*)(px + base);
    uint2 o;
    o.x = f2bf(v.x) | (f2bf(v.y)<<16);
    o.y = f2bf(v.z) | (f2bf(v.w)<<16);
    *(uint2*)(xb + base) = o;
  } else if (bid < 31296){               // conv_w [n][di][ky][kx] -> [kyx][n][di]
    int i = (bid-3072)*256 + t;
    int n = i / CK;
    int r = i - n*CK;
    int di = r/49, kyx = r - di*49;
    wtb[((size_t)kyx*D_ + n)*D_ + di] = (ushort)f2bf(cw[i]);
  } else if (bid < 32448){               // kv_w [384][768] -> [n][k]
    int i = (bid-31296)*256 + t;
    int k = i/768, n = i - k*768;
    kvwb[(size_t)n*384 + k] = (ushort)f2bf(wkv[i]);
  } else if (bid < 33024){               // q_w [384][384] -> [n][k]
    int i = (bid-32448)*256 + t;
    int k = i/384, n = i - k*384;
    qwb[(size_t)n*384 + k] = (ushort)f2bf(wq[i]);
  } else if (bid < 35328){               // w1 [384][1536] -> [n][k]
    int i = (bid-33024)*256 + t;
    int k = i/1536, n = i - k*1536;
    w1b[(size_t)n*384 + k] = (ushort)f2bf(w1[i]);
  } else {                               // w2 [1536][384] -> [n][k]
    int i = (bid-35328)*256 + t;
    int k = i/384, n = i - k*384;
    w2b[(size_t)n*1536 + k] = (ushort)f2bf(w2[i]);
  }
}

// -------- MFMA conv: per-slice GEMM, 128x128 tile, 4 waves x (4x4) 16x16x32 --------
__global__ __launch_bounds__(256)
void convm(const ushort* __restrict__ xb, const ushort* __restrict__ wtb,
           float* __restrict__ part){
  __shared__ ushort As[128][40];
  __shared__ ushort Bs[128][40];
  const int t  = threadIdx.x;
  const int m0 = blockIdx.x*128, n0 = blockIdx.y*128, z = blockIdx.z;
  const int ky = z/7, kx = z - ky*7;
  const int r = t>>1, half = t&1;
  const int m = m0 + r;
  const int mq = (m < MOUT) ? m : 0;
  const int bbv = mq/NOUT, qq = mq - bbv*NOUT;
  const int oy = qq/QW_, ox = qq - oy*QW_;
  const int iy = oy*3-3+ky, ix = ox*3-3+kx;
  const bool aval = (m<MOUT) && iy>=0 && iy<64 && ix>=0 && ix<64;
  const ushort* asrc = xb + ((size_t)bbv*NIN + (aval ? iy*64+ix : 0))*D_ + half*16;
  const ushort* bsrc = wtb + ((size_t)z*D_ + n0 + r)*D_ + half*16;

  const int wv = t>>6;
  const int wr = (wv>>1)*64, wc = (wv&1)*64;
  const int ln = t&15, lq = (t>>4)&3;

  f32x4 acc[4][4];
#pragma unroll
  for (int i=0;i<4;i++)
#pragma unroll
    for (int j=0;j<4;j++) acc[i][j] = (f32x4){0.f,0.f,0.f,0.f};

  for (int dk=0; dk<D_; dk+=32){
    uint4 a0 = {0,0,0,0}, a1 = {0,0,0,0};
    if (aval){ a0 = *(const uint4*)(asrc+dk); a1 = *(const uint4*)(asrc+dk+8); }
    uint4 b0 = *(const uint4*)(bsrc+dk), b1 = *(const uint4*)(bsrc+dk+8);
    *(uint4*)&As[r][half*16]   = a0;  *(uint4*)&As[r][half*16+8] = a1;
    *(uint4*)&Bs[r][half*16]   = b0;  *(uint4*)&Bs[r][half*16+8] = b1;
    __syncthreads();
    bf16x8 af[4], bfr[4];
#pragma unroll
    for (int i=0;i<4;i++) af[i]  = *(const bf16x8*)&As[wr+i*16+ln][lq*8];
#pragma unroll
    for (int j=0;j<4;j++) bfr[j] = *(const bf16x8*)&Bs[wc+j*16+ln][lq*8];
#pragma unroll
    for (int i=0;i<4;i++)
#pragma unroll
      for (int j=0;j<4;j++)
        acc[i][j] = __builtin_amdgcn_mfma_f32_16x16x32_bf16(af[i], bfr[j], acc[i][j], 0,0,0);
    __syncthreads();
  }
#pragma unroll
  for (int i=0;i<4;i++){
    int rowb = m0 + wr + i*16 + lq*4;
#pragma unroll
    for (int j=0;j<4;j++){
      int col = n0 + wc + j*16 + ln;
#pragma unroll
      for (int rg=0; rg<4; rg++){
        int row = rowb + rg;
        if (row < MOUT) part[((size_t)z*MOUT + row)*D_ + col] = acc[i][j][rg];
      }
    }
  }
}

// -------- MFMA GEMM (128x128 tile) — used for the large KV projection ----------
template<int ACT, bool ABF>
__global__ __launch_bounds__(256)
void gemmm(const void* __restrict__ Ain, const ushort* __restrict__ Wb,
           const float* __restrict__ bias, float* __restrict__ C,
           int M, int N, int K){
  __shared__ ushort As[128][40];
  __shared__ ushort Bs[128][40];
  const int t  = threadIdx.x;
  const int m0 = blockIdx.x*128, n0 = blockIdx.y*128;
  const int r = t>>1, half = t&1;
  const int m = m0 + r;
  const bool aval = (m < M);
  const float*  af32 = (const float*)Ain  + (size_t)(aval?m:0)*K + half*16;
  const ushort* ab16 = (const ushort*)Ain + (size_t)(aval?m:0)*K + half*16;
  const ushort* bsrc = Wb + (size_t)(n0 + r)*K + half*16;

  const int wv = t>>6;
  const int wr = (wv>>1)*64, wc = (wv&1)*64;
  const int ln = t&15, lq = (t>>4)&3;

  f32x4 acc[4][4];
#pragma unroll
  for (int i=0;i<4;i++)
#pragma unroll
    for (int j=0;j<4;j++) acc[i][j] = (f32x4){0.f,0.f,0.f,0.f};

  for (int dk=0; dk<K; dk+=32){
    uint4 a0 = {0,0,0,0}, a1 = {0,0,0,0};
    if (aval){
      if (ABF){
        a0 = *(const uint4*)(ab16+dk); a1 = *(const uint4*)(ab16+dk+8);
      } else {
        float4 f0 = *(const float4*)(af32+dk),   f1 = *(const float4*)(af32+dk+4);
        float4 f2 = *(const float4*)(af32+dk+8), f3 = *(const float4*)(af32+dk+12);
        a0.x = f2bf(f0.x)|(f2bf(f0.y)<<16); a0.y = f2bf(f0.z)|(f2bf(f0.w)<<16);
        a0.z = f2bf(f1.x)|(f2bf(f1.y)<<16); a0.w = f2bf(f1.z)|(f2bf(f1.w)<<16);
        a1.x = f2bf(f2.x)|(f2bf(f2.y)<<16); a1.y = f2bf(f2.z)|(f2bf(f2.w)<<16);
        a1.z = f2bf(f3.x)|(f2bf(f3.y)<<16); a1.w = f2bf(f3.z)|(f2bf(f3.w)<<16);
      }
    }
    uint4 b0 = *(const uint4*)(bsrc+dk), b1 = *(const uint4*)(bsrc+dk+8);
    *(uint4*)&As[r][half*16]   = a0;  *(uint4*)&As[r][half*16+8] = a1;
    *(uint4*)&Bs[r][half*16]   = b0;  *(uint4*)&Bs[r][half*16+8] = b1;
    __syncthreads();
    bf16x8 af[4], bfr[4];
#pragma unroll
    for (int i=0;i<4;i++) af[i]  = *(const bf16x8*)&As[wr+i*16+ln][lq*8];
#pragma unroll
    for (int j=0;j<4;j++) bfr[j] = *(const bf16x8*)&Bs[wc+j*16+ln][lq*8];
#pragma unroll
    for (int i=0;i<4;i++)
#pragma unroll
      for (int j=0;j<4;j++)
        acc[i][j] = __builtin_amdgcn_mfma_f32_16x16x32_bf16(af[i], bfr[j], acc[i][j], 0,0,0);
    __syncthreads();
  }
#pragma unroll
  for (int i=0;i<4;i++){
    int rowb = m0 + wr + i*16 + lq*4;
#pragma unroll
    for (int j=0;j<4;j++){
      int col = n0 + wc + j*16 + ln;
      float bv = bias[col];
#pragma unroll
      for (int rg=0; rg<4; rg++){
        int row = rowb + rg;
        if (row < M){
          float v = acc[i][j][rg] + bv;
          if (ACT==1) v = 0.5f*v*(1.f + erff(v*0.7071067811865475f));
          C[(size_t)row*N + col] = v;
        }
      }
    }
  }
}

// -------- gemm64: 64x64 tile, 4 waves x (2x2) 16x16x32 — for M=968 GEMMs ------
template<int ACT>
__global__ __launch_bounds__(256)
void gemm64(const float* __restrict__ Ain, const ushort* __restrict__ Wb,
            const float* __restrict__ bias, float* __restrict__ C,
            int M, int N, int K){
  __shared__ ushort As[64][40];
  __shared__ ushort Bs[64][40];
  const int t  = threadIdx.x;
  const int m0 = blockIdx.x*64, n0 = blockIdx.y*64;
  const int r = t>>2, seg = t&3;          // stage: row r, 8-ush chunk seg
  const int m = m0 + r;
  const bool aval = (m < M);
  const float*  asrc = Ain + (size_t)(aval?m:0)*K + seg*8;
  const ushort* bsrc = Wb + (size_t)(n0 + r)*K + seg*8;

  const int wv = t>>6;
  const int wr = (wv>>1)*32, wc = (wv&1)*32;
  const int ln = t&15, lq = (t>>4)&3;

  f32x4 acc[2][2];
  acc[0][0]=(f32x4){0,0,0,0}; acc[0][1]=(f32x4){0,0,0,0};
  acc[1][0]=(f32x4){0,0,0,0}; acc[1][1]=(f32x4){0,0,0,0};

  for (int dk=0; dk<K; dk+=32){
    uint4 a0 = {0,0,0,0};
    if (aval){
      float4 f0 = *(const float4*)(asrc+dk), f1 = *(const float4*)(asrc+dk+4);
      a0.x = f2bf(f0.x)|(f2bf(f0.y)<<16); a0.y = f2bf(f0.z)|(f2bf(f0.w)<<16);
      a0.z = f2bf(f1.x)|(f2bf(f1.y)<<16); a0.w = f2bf(f1.z)|(f2bf(f1.w)<<16);
    }
    uint4 b0 = *(const uint4*)(bsrc+dk);
    *(uint4*)&As[r][seg*8] = a0;
    *(uint4*)&Bs[r][seg*8] = b0;
    __syncthreads();
    bf16x8 af[2], bfr[2];
#pragma unroll
    for (int i=0;i<2;i++) af[i]  = *(const bf16x8*)&As[wr+i*16+ln][lq*8];
#pragma unroll
    for (int j=0;j<2;j++) bfr[j] = *(const bf16x8*)&Bs[wc+j*16+ln][lq*8];
#pragma unroll
    for (int i=0;i<2;i++)
#pragma unroll
      for (int j=0;j<2;j++)
        acc[i][j] = __builtin_amdgcn_mfma_f32_16x16x32_bf16(af[i], bfr[j], acc[i][j], 0,0,0);
    __syncthreads();
  }
#pragma unroll
  for (int i=0;i<2;i++){
    int rowb = m0 + wr + i*16 + lq*4;
#pragma unroll
    for (int j=0;j<2;j++){
      int col = n0 + wc + j*16 + ln;
      float bv = bias[col];
#pragma unroll
      for (int rg=0; rg<4; rg++){
        int row = rowb + rg;
        if (row < M){
          float v = acc[i][j][rg] + bv;
          if (ACT==1) v = 0.5f*v*(1.f + erff(v*0.7071067811865475f));
          C[(size_t)row*N + col] = v;
        }
      }
    }
  }
}

// -------- gemm64sk: mlp2 split-K, 64x64 tile, part[z] = h1[:,z*384:]*W2slice ----
__global__ __launch_bounds__(256)
void gemm64sk(const float* __restrict__ Ain, const ushort* __restrict__ Wb,
              float* __restrict__ part){
  __shared__ ushort As[64][40];
  __shared__ ushort Bs[64][40];
  const int t  = threadIdx.x;
  const int m0 = blockIdx.x*64, n0 = blockIdx.y*64, z = blockIdx.z;
  const int r = t>>2, seg = t&3;
  const int m = m0 + r;
  const bool aval = (m < MOUT);
  const float*  asrc = Ain + (size_t)(aval?m:0)*1536 + z*384 + seg*8;
  const ushort* bsrc = Wb + (size_t)(n0 + r)*1536 + z*384 + seg*8;

  const int wv = t>>6;
  const int wr = (wv>>1)*32, wc = (wv&1)*32;
  const int ln = t&15, lq = (t>>4)&3;

  f32x4 acc[2][2];
  acc[0][0]=(f32x4){0,0,0,0}; acc[0][1]=(f32x4){0,0,0,0};
  acc[1][0]=(f32x4){0,0,0,0}; acc[1][1]=(f32x4){0,0,0,0};

  for (int dk=0; dk<384; dk+=32){
    uint4 a0 = {0,0,0,0};
    if (aval){
      float4 f0 = *(const float4*)(asrc+dk), f1 = *(const float4*)(asrc+dk+4);
      a0.x = f2bf(f0.x)|(f2bf(f0.y)<<16); a0.y = f2bf(f0.z)|(f2bf(f0.w)<<16);
      a0.z = f2bf(f1.x)|(f2bf(f1.y)<<16); a0.w = f2bf(f1.z)|(f2bf(f1.w)<<16);
    }
    uint4 b0 = *(const uint4*)(bsrc+dk);
    *(uint4*)&As[r][seg*8] = a0;
    *(uint4*)&Bs[r][seg*8] = b0;
    __syncthreads();
    bf16x8 af[2], bfr[2];
#pragma unroll
    for (int i=0;i<2;i++) af[i]  = *(const bf16x8*)&As[wr+i*16+ln][lq*8];
#pragma unroll
    for (int j=0;j<2;j++) bfr[j] = *(const bf16x8*)&Bs[wc+j*16+ln][lq*8];
#pragma unroll
    for (int i=0;i<2;i++)
#pragma unroll
      for (int j=0;j<2;j++)
        acc[i][j] = __builtin_amdgcn_mfma_f32_16x16x32_bf16(af[i], bfr[j], acc[i][j], 0,0,0);
    __syncthreads();
  }
#pragma unroll
  for (int i=0;i<2;i++){
    int rowb = m0 + wr + i*16 + lq*4;
#pragma unroll
    for (int j=0;j<2;j++){
      int col = n0 + wc + j*16 + ln;
#pragma unroll
      for (int rg=0; rg<4; rg++){
        int row = rowb + rg;
        if (row < MOUT) part[((size_t)z*MOUT + row)*D_ + col] = acc[i][j][rg];
      }
    }
  }
}

// ---------------- block reduction over 384 threads --------------------------
__device__ __forceinline__ float block_sum_384(float v){
  __shared__ float red[6];
#pragma unroll
  for (int o=32;o>0;o>>=1) v += __shfl_down(v,o);
  const int lane = threadIdx.x & 63, w = threadIdx.x >> 6;
  __syncthreads();
  if (lane==0) red[w] = v;
  __syncthreads();
  return red[0]+red[1]+red[2]+red[3]+red[4]+red[5];
}

// LN kernel. MODE 0: in = 49 conv partials (+bias cb) -> write xout
//            MODE 1: in = upd[bh][q][hd] gathered -> xout += LN
//            MODE 3: in = 4 mlp2 partials (+bias cb) -> xout += LN
template<int MODE>
__global__ __launch_bounds__(384)
void lnk(const float* __restrict__ in, const float* __restrict__ cb,
         const float* __restrict__ gg, const float* __restrict__ bb,
         float* __restrict__ xout){
  const int m = blockIdx.x, d = threadIdx.x;
  float v;
  if (MODE==0){
    v = cb[d];
    for (int z=0; z<NSLICE; z++) v += in[((size_t)z*MOUT + m)*D_ + d];
  } else if (MODE==1){
    int b = m/NOUT, q = m - b*NOUT;
    int h = d>>5, dd2 = d&31;
    v = in[(((size_t)(b*H_ + h))*NOUT + q)*HD + dd2];
  } else {
    v = cb[d];
#pragma unroll
    for (int z=0; z<4; z++) v += in[((size_t)z*MOUT + m)*D_ + d];
  }
  float mu  = block_sum_384(v) * (1.f/D_);
  float ce  = v - mu;
  float var = block_sum_384(ce*ce) * (1.f/D_);
  float o = ce * rsqrtf(var + LN_EPS) * gg[d] + bb[d];
  float* dst = xout + (size_t)m*D_ + d;
  if (MODE==0) *dst = o;
  else *dst += o;
}

// ------------- rose for K (+ temp scale, bf16 pack) and V gather ------------
__global__ __launch_bounds__(256)
void rosek(const float* __restrict__ kvbuf, const float* __restrict__ rf,
           const float* __restrict__ temp,
           ushort* __restrict__ kb, float* __restrict__ vhb){
  int idx = blockIdx.x*256 + threadIdx.x;
  if (idx >= BB*H_*NIN) return;
  int n  = idx & (NIN-1);
  int bh = idx >> 12;
  int h  = bh % H_;
  int b  = bh / H_;
  float T = temp[0];
  int iy = n >> 6, ix = n & 63;
  const float* src = kvbuf + ((size_t)b*NIN + n)*768 + h*HD;
  float xv[HD];
#pragma unroll
  for (int d4=0; d4<8; d4++){
    float4 v = *(const float4*)(src + d4*4);
    xv[d4*4]=v.x; xv[d4*4+1]=v.y; xv[d4*4+2]=v.z; xv[d4*4+3]=v.w;
  }
  float out[HD];
#pragma unroll
  for (int tp=0; tp<8; tp++){
    int s2 = tp >> 2, p2 = tp & 3;
    float coord = (s2==0) ? (float)iy : (float)ix;
    float ang = coord * rf[(h*2+s2)*4 + p2];
    float sn, cn; sincosf(ang, &sn, &cn);
    float x1 = xv[2*tp], x2 = xv[2*tp+1];
    out[2*tp]   = x1*cn - x2*sn;
    out[2*tp+1] = x1*sn + x2*cn;
  }
#pragma unroll
  for (int d=16; d<HD; d++) out[d] = xv[d];
  ushort* dk = kb + ((size_t)bh*NIN + n)*HD;
#pragma unroll
  for (int g=0; g<4; g++){
    uint4 o;
    o.x = f2bf(T*out[g*8+0]) | (f2bf(T*out[g*8+1])<<16);
    o.y = f2bf(T*out[g*8+2]) | (f2bf(T*out[g*8+3])<<16);
    o.z = f2bf(T*out[g*8+4]) | (f2bf(T*out[g*8+5])<<16);
    o.w = f2bf(T*out[g*8+6]) | (f2bf(T*out[g*8+7])<<16);
    *(uint4*)(dk + g*8) = o;
  }
  const float* vs = src + D_;
  float* dv = vhb + ((size_t)bh*NIN + n)*HD;
#pragma unroll
  for (int d4=0; d4<8; d4++)
    *(float4*)(dv + d4*4) = *(const float4*)(vs + d4*4);
}

// ------------- rose for Q (grid 22x22, spacing 3.0) -> bf16, padded to 512 --
__global__ __launch_bounds__(256)
void roseq(const float* __restrict__ qp, const float* __restrict__ rf,
           ushort* __restrict__ qb){
  int idx = blockIdx.x*256 + threadIdx.x;      // < 24*512
  int q  = idx & 511;
  int bh = idx >> 9;
  int h  = bh % H_;
  int b  = bh / H_;
  ushort* dq = qb + ((size_t)bh*512 + q)*HD;
  if (q >= NOUT){
    uint4 z = {0,0,0,0};
#pragma unroll
    for (int g=0; g<4; g++) *(uint4*)(dq + g*8) = z;
    return;
  }
  int oy = q / QW_, ox = q - oy*QW_;
  const float* src = qp + ((size_t)b*NOUT + q)*D_ + h*HD;
  float xv[HD];
#pragma unroll
  for (int d4=0; d4<8; d4++){
    float4 v = *(const float4*)(src + d4*4);
    xv[d4*4]=v.x; xv[d4*4+1]=v.y; xv[d4*4+2]=v.z; xv[d4*4+3]=v.w;
  }
  float out[HD];
#pragma unroll
  for (int tp=0; tp<8; tp++){
    int s2 = tp >> 2, p2 = tp & 3;
    float coord = (s2==0) ? 3.0f*(float)oy : 3.0f*(float)ox;
    float ang = coord * rf[(h*2+s2)*4 + p2];
    float sn, cn; sincosf(ang, &sn, &cn);
    float x1 = xv[2*tp], x2 = xv[2*tp+1];
    out[2*tp]   = x1*cn - x2*sn;
    out[2*tp+1] = x1*sn + x2*cn;
  }
#pragma unroll
  for (int d=16; d<HD; d++) out[d] = xv[d];
#pragma unroll
  for (int g=0; g<4; g++){
    uint4 o;
    o.x = f2bf(out[g*8+0]) | (f2bf(out[g*8+1])<<16);
    o.y = f2bf(out[g*8+2]) | (f2bf(out[g*8+3])<<16);
    o.z = f2bf(out[g*8+4]) | (f2bf(out[g*8+5])<<16);
    o.w = f2bf(out[g*8+6]) | (f2bf(out[g*8+7])<<16);
    *(uint4*)(dq + g*8) = o;
  }
}

// ------- rowk: MFMA QK^T (64q x 256k), exp, rowsum partials (no E store) ----
__global__ __launch_bounds__(256)
void rowk(const ushort* __restrict__ qb, const ushort* __restrict__ kb,
          float* __restrict__ l0part){
  __shared__ ushort Qs[64][40];
  __shared__ ushort Ks[256][40];
  __shared__ float  red[4][64];
  const int t  = threadIdx.x;
  const int q0 = blockIdx.x*64;
  const int kt = blockIdx.y;
  const int k0 = kt*256;
  const int bh = blockIdx.z;
  {  // stage Q: 64 rows x 32 ush
    int row = t>>2, seg = t&3;
    const ushort* src = qb + ((size_t)bh*512 + q0 + row)*HD + seg*8;
    *(uint4*)&Qs[row][seg*8] = *(const uint4*)src;
  }
  {  // stage K: 256 rows x 32 ush
    const ushort* src = kb + ((size_t)bh*NIN + k0 + t)*HD;
#pragma unroll
    for (int g=0; g<4; g++)
      *(uint4*)&Ks[t][g*8] = *(const uint4*)(src + g*8);
  }
  __syncthreads();
  const int wv = t>>6;
  const int wc = wv*64;
  const int ln = t&15, lq = (t>>4)&3;
  bf16x8 af[4], bfr[4];
#pragma unroll
  for (int i=0;i<4;i++) af[i]  = *(const bf16x8*)&Qs[i*16+ln][lq*8];
#pragma unroll
  for (int j=0;j<4;j++) bfr[j] = *(const bf16x8*)&Ks[wc+j*16+ln][lq*8];
  f32x4 acc[4][4];
  const f32x4 zero = (f32x4){0.f,0.f,0.f,0.f};
#pragma unroll
  for (int i=0;i<4;i++)
#pragma unroll
    for (int j=0;j<4;j++)
      acc[i][j] = __builtin_amdgcn_mfma_f32_16x16x32_bf16(af[i], bfr[j], zero, 0,0,0);
  float rs[4][4];
#pragma unroll
  for (int i=0;i<4;i++){
#pragma unroll
    for (int rg=0; rg<4; rg++){
      float s = 0.f;
#pragma unroll
      for (int j=0;j<4;j++) s += __expf(acc[i][j][rg]);
      rs[i][rg] = s;
    }
  }
#pragma unroll
  for (int i=0;i<4;i++)
#pragma unroll
    for (int rg=0;rg<4;rg++){
      float v = rs[i][rg];
      v += __shfl_xor(v,1); v += __shfl_xor(v,2);
      v += __shfl_xor(v,4); v += __shfl_xor(v,8);
      rs[i][rg] = v;
    }
  if (ln==0){
#pragma unroll
    for (int i=0;i<4;i++)
#pragma unroll
      for (int rg=0;rg<4;rg++)
        red[wv][i*16+lq*4+rg] = rs[i][rg];
  }
  __syncthreads();
  if (t < 64){
    float tot = red[0][t]+red[1][t]+red[2][t]+red[3][t];
    l0part[((size_t)bh*512 + q0 + t)*16 + kt] = tot;
  }
}

// ------- colk_f: recompute S^T via MFMA (A=K, B=Q); csinv[k]=1/(sum_q E*li+EPS)
//         l0inv reduced inline from l0part (16 k-tile partials) ---------------
__global__ __launch_bounds__(256)
void colk_f(const ushort* __restrict__ qb, const ushort* __restrict__ kb,
            const float* __restrict__ l0part, float* __restrict__ csinv){
  __shared__ ushort Ks[256][40];
  __shared__ ushort Qs[64][40];
  __shared__ float  lis[64];
  const int t  = threadIdx.x;
  const int k0 = blockIdx.x*256;
  const int bh = blockIdx.y;
  {  // stage K tile once: 256 rows x 32 ush
    const ushort* src = kb + ((size_t)bh*NIN + k0 + t)*HD;
#pragma unroll
    for (int g=0; g<4; g++)
      *(uint4*)&Ks[t][g*8] = *(const uint4*)(src + g*8);
  }
  const int wv = t>>6, ln = t&15, lq = (t>>4)&3;
  const f32x4 zero = (f32x4){0.f,0.f,0.f,0.f};
  f32x4 colacc[4];
#pragma unroll
  for (int i=0;i<4;i++) colacc[i] = zero;
  for (int qc=0; qc<512; qc+=64){
    __syncthreads();
    {  // stage Q chunk: 64 rows x 32 ush
      int row = t>>2, seg = t&3;
      *(uint4*)&Qs[row][seg*8] =
        *(const uint4*)(qb + ((size_t)bh*512 + qc + row)*HD + seg*8);
    }
    if (t < 64){
      int q = qc + t;
      const float* lp = l0part + ((size_t)bh*512 + q)*16;
      float s = 0.f;
#pragma unroll
      for (int j=0;j<16;j++) s += lp[j];
      lis[t] = (q < NOUT) ? 1.f/s : 0.f;
    }
    __syncthreads();
    bf16x8 af[4], bfr[4];
#pragma unroll
    for (int i=0;i<4;i++) af[i]  = *(const bf16x8*)&Ks[wv*64+i*16+ln][lq*8];
#pragma unroll
    for (int j=0;j<4;j++) bfr[j] = *(const bf16x8*)&Qs[j*16+ln][lq*8];
#pragma unroll
    for (int j=0;j<4;j++){
      float liv = lis[j*16+ln];
#pragma unroll
      for (int i=0;i<4;i++){
        f32x4 c = __builtin_amdgcn_mfma_f32_16x16x32_bf16(af[i], bfr[j], zero, 0,0,0);
#pragma unroll
        for (int rg=0;rg<4;rg++)
          colacc[i][rg] += __expf(c[rg]) * liv;
      }
    }
  }
#pragma unroll
  for (int i=0;i<4;i++)
#pragma unroll
    for (int rg=0;rg<4;rg++){
      float v = colacc[i][rg];
      v += __shfl_xor(v,1); v += __shfl_xor(v,2);
      v += __shfl_xor(v,4); v += __shfl_xor(v,8);
      colacc[i][rg] = v;
    }
  if (ln==0){
#pragma unroll
    for (int i=0;i<4;i++){
      float4 o;
      o.x = 1.f/(colacc[i][0] + EPS_);
      o.y = 1.f/(colacc[i][1] + EPS_);
      o.z = 1.f/(colacc[i][2] + EPS_);
      o.w = 1.f/(colacc[i][3] + EPS_);
      *(float4*)(csinv + (size_t)bh*NIN + k0 + wv*64 + i*16 + lq*4) = o;
    }
  }
}

// ------- pv_f: recompute S via MFMA (K frags from L2); P=exp(S)*li fp32 in LDS;
//         PV via 3-term bf16x2-split MFMA; l0inv reduced inline from l0part;
//         LAST: write attnk = P, attnq = P*ci -------------------------------
template<bool LAST>
__global__ __launch_bounds__(256)
void pv_f(const ushort* __restrict__ qb, const ushort* __restrict__ kb,
          const float* __restrict__ vh, const float* __restrict__ l0part,
          const float* __restrict__ csinv, float* __restrict__ upd,
          float* __restrict__ attnq, float* __restrict__ attnk){
  __shared__ ushort   Qs[32][40];     // Q tile bf16
  __shared__ float    Ps[128][36];    // P fp32 [k][q]; reused as Ured at end
  __shared__ unsigned Vt[32][132];    // ci*V transposed [d][k], (bf16hi<<16)|bf16lo
  __shared__ float    lis[32];
  __shared__ float    cis[128];
  const int t  = threadIdx.x;
  const int q0 = blockIdx.x*32;
  const int bh = blockIdx.y;
  {  // stage Q bf16 once: 32 rows x 32 ush
    int row = t>>3, seg = t&7;
    *(uint2*)&Qs[row][seg*4] =
      *(const uint2*)(qb + ((size_t)bh*512 + q0 + row)*HD + seg*4);
  }
  if (t < 32){
    int q = q0 + t;
    const float* lp = l0part + ((size_t)bh*512 + q)*16;
    float s = 0.f;
#pragma unroll
    for (int j=0;j<16;j++) s += lp[j];
    lis[t] = (q < NOUT) ? 1.f/s : 0.f;
  }
  __syncthreads();
  const int wv = t>>6, ln = t&15, lq = (t>>4)&3;
  const bf16x8 af0 = *(const bf16x8*)&Qs[ln][lq*8];        // hoisted Q frags
  const bf16x8 af1 = *(const bf16x8*)&Qs[16+ln][lq*8];
  float lr[2][4];
#pragma unroll
  for (int i=0;i<2;i++)
#pragma unroll
    for (int rg=0;rg<4;rg++) lr[i][rg] = lis[i*16 + lq*4 + rg];
  const f32x4 zero = (f32x4){0.f,0.f,0.f,0.f};
  f32x4 acc[2][2];
  acc[0][0]=zero; acc[0][1]=zero; acc[1][0]=zero; acc[1][1]=zero;
  const ushort* kfrag = kb + ((size_t)bh*NIN)*HD;
  for (int kc=0; kc<NIN; kc+=128){
    if (LAST) __syncthreads();   // prev tile's cross-wave Ps/cis reads done
    {  // stage ci*V transposed, packed bf16 hi/lo; thread t covers col r=t>>1
      int r = t>>1, half = t&1;
      float civ = csinv[(size_t)bh*NIN + kc + r];
      if (half==0) cis[r] = civ;
      const float* pv = vh + ((size_t)bh*NIN + kc + r)*HD + half*16;
      float4 b0=*(const float4*)pv, b1=*(const float4*)(pv+4),
             b2=*(const float4*)(pv+8), b3=*(const float4*)(pv+12);
      float w[16] = {civ*b0.x, civ*b0.y, civ*b0.z, civ*b0.w,
                     civ*b1.x, civ*b1.y, civ*b1.z, civ*b1.w,
                     civ*b2.x, civ*b2.y, civ*b2.z, civ*b2.w,
                     civ*b3.x, civ*b3.y, civ*b3.z, civ*b3.w};
      int dbase = half*16;
#pragma unroll
      for (int i2=0;i2<16;i2++){
        unsigned hi = f2bf(w[i2]);
        float hif = __uint_as_float(hi<<16);
        unsigned lo = f2bf(w[i2] - hif);
        Vt[dbase+i2][r] = (hi<<16) | lo;
      }
    }
    // S via MFMA, wave-local rows wv*32..wv*32+31 of Ps
    bf16x8 bf0 = *(const bf16x8*)(kfrag + (size_t)(kc + wv*32 +      ln)*HD + lq*8);
    bf16x8 bf1 = *(const bf16x8*)(kfrag + (size_t)(kc + wv*32 + 16 + ln)*HD + lq*8);
    {
      f32x4 c; float4 pw;
      c = __builtin_amdgcn_mfma_f32_16x16x32_bf16(af0, bf0, zero, 0,0,0);
      pw.x=__expf(c[0])*lr[0][0]; pw.y=__expf(c[1])*lr[0][1];
      pw.z=__expf(c[2])*lr[0][2]; pw.w=__expf(c[3])*lr[0][3];
      *(float4*)&Ps[wv*32 +      ln][      lq*4] = pw;
      c = __builtin_amdgcn_mfma_f32_16x16x32_bf16(af1, bf0, zero, 0,0,0);
      pw.x=__expf(c[0])*lr[1][0]; pw.y=__expf(c[1])*lr[1][1];
      pw.z=__expf(c[2])*lr[1][2]; pw.w=__expf(c[3])*lr[1][3];
      *(float4*)&Ps[wv*32 +      ln][16 + lq*4] = pw;
      c = __builtin_amdgcn_mfma_f32_16x16x32_bf16(af0, bf1, zero, 0,0,0);
      pw.x=__expf(c[0])*lr[0][0]; pw.y=__expf(c[1])*lr[0][1];
      pw.z=__expf(c[2])*lr[0][2]; pw.w=__expf(c[3])*lr[0][3];
      *(float4*)&Ps[wv*32 + 16 + ln][      lq*4] = pw;
      c = __builtin_amdgcn_mfma_f32_16x16x32_bf16(af1, bf1, zero, 0,0,0);
      pw.x=__expf(c[0])*lr[1][0]; pw.y=__expf(c[1])*lr[1][1];
      pw.z=__expf(c[2])*lr[1][2]; pw.w=__expf(c[3])*lr[1][3];
      *(float4*)&Ps[wv*32 + 16 + ln][16 + lq*4] = pw;
    }
    if (LAST){
      __syncthreads();   // cross-wave Ps/cis for the coalesced output bounce
      int row = t>>3, seg = t&7;
      int q = q0 + row;
      if (q < NOUT){
        float* ak = attnk + ((size_t)bh*NOUT + q)*NIN + kc + seg*16;
        float* aq = attnq + ((size_t)bh*NOUT + q)*NIN + kc + seg*16;
#pragma unroll
        for (int s=0;s<4;s++){
          int kk = seg*16 + s*4;
          float4 p = make_float4(Ps[kk][row], Ps[kk+1][row], Ps[kk+2][row], Ps[kk+3][row]);
          float4 c4 = *(const float4*)&cis[kk];
          *(float4*)(ak + s*4) = p;
          float4 pq;
          pq.x = p.x*c4.x; pq.y = p.y*c4.y; pq.z = p.z*c4.z; pq.w = p.w*c4.w;
          *(float4*)(aq + s*4) = pq;
        }
      }
    }
    // PV via MFMA on this wave's 32-k chunk (Ps/Vt wave-local)
    bf16x8 bhi[2], blo[2];
#pragma unroll
    for (int nf=0;nf<2;nf++){
#pragma unroll
      for (int j=0;j<8;j++){
        float p = Ps[wv*32 + lq*8 + j][nf*16 + ln];
        unsigned hi = f2bf(p);
        float hif = __uint_as_float(hi<<16);
        unsigned lo = f2bf(p - hif);
        bhi[nf][j] = (short)hi;
        blo[nf][j] = (short)lo;
      }
    }
    bf16x8 ahi[2], alo[2];
#pragma unroll
    for (int mf=0;mf<2;mf++){
      const unsigned* vrow = &Vt[mf*16+ln][wv*32 + lq*8];
      uint4 wa = *(const uint4*)vrow;
      uint4 wb = *(const uint4*)(vrow+4);
      ahi[mf][0]=(short)(wa.x>>16); alo[mf][0]=(short)(wa.x&0xffffu);
      ahi[mf][1]=(short)(wa.y>>16); alo[mf][1]=(short)(wa.y&0xffffu);
      ahi[mf][2]=(short)(wa.z>>16); alo[mf][2]=(short)(wa.z&0xffffu);
      ahi[mf][3]=(short)(wa.w>>16); alo[mf][3]=(short)(wa.w&0xffffu);
      ahi[mf][4]=(short)(wb.x>>16); alo[mf][4]=(short)(wb.x&0xffffu);
      ahi[mf][5]=(short)(wb.y>>16); alo[mf][5]=(short)(wb.y&0xffffu);
      ahi[mf][6]=(short)(wb.z>>16); alo[mf][6]=(short)(wb.z&0xffffu);
      ahi[mf][7]=(short)(wb.w>>16); alo[mf][7]=(short)(wb.w&0xffffu);
    }
#pragma unroll
    for (int mf=0;mf<2;mf++)
#pragma unroll
      for (int nf=0;nf<2;nf++){
        acc[mf][nf] = __builtin_amdgcn_mfma_f32_16x16x32_bf16(ahi[mf], bhi[nf], acc[mf][nf], 0,0,0);
        acc[mf][nf] = __builtin_amdgcn_mfma_f32_16x16x32_bf16(ahi[mf], blo[nf], acc[mf][nf], 0,0,0);
        acc[mf][nf] = __builtin_amdgcn_mfma_f32_16x16x32_bf16(alo[mf], bhi[nf], acc[mf][nf], 0,0,0);
      }
  }
  // reduce the 4 per-wave k-quarter partials of U[d32][q32] via LDS (alias Ps)
  __syncthreads();
  float* Ured = &Ps[0][0];           // 4608 floats available, 4096 needed
  {
    int lane = t & 63;
#pragma unroll
    for (int mf=0;mf<2;mf++)
#pragma unroll
      for (int nf=0;nf<2;nf++)
#pragma unroll
        for (int rg=0;rg<4;rg++)
          Ured[wv*1024 + (mf*2+nf)*256 + rg*64 + lane] = acc[mf][nf][rg];
  }
  __syncthreads();
#pragma unroll
  for (int i=0;i<4;i++){
    int s = i*256 + t;
    float u = Ured[s] + Ured[1024+s] + Ured[2048+s] + Ured[3072+s];
    int grp = s>>8, rg = (s>>6)&3, lane = s&63;
    int mf = grp>>1, nf = grp&1;
    int q = q0 + nf*16 + (lane&15);
    int d = mf*16 + (lane>>4)*4 + rg;
    if (q < NOUT) upd[((size_t)bh*NOUT + q)*HD + d] = u;
  }
}

__global__ __launch_bounds__(256)
void copyk(const float* __restrict__ src, float* __restrict__ dst, int n){
  int i = blockIdx.x*256 + threadIdx.x;
  if (i < n) dst[i] = src[i];
}

// --------------------------------------------------------------------------
extern "C" void kernel_launch(void* const* d_in, const int* in_sizes, int n_in,
                              void* d_out, int out_size, void* d_ws, size_t ws_size,
                              hipStream_t stream){
  (void)in_sizes; (void)n_in; (void)out_size; (void)ws_size;
  const float* px    = (const float*)d_in[0];
  const float* pcw   = (const float*)d_in[1];
  const float* pcb   = (const float*)d_in[2];
  const float* pkvw  = (const float*)d_in[3];
  const float* pkvb  = (const float*)d_in[4];
  const float* pqw   = (const float*)d_in[5];
  const float* pqb   = (const float*)d_in[6];
  const float* pw1   = (const float*)d_in[7];
  const float* pb1   = (const float*)d_in[8];
  const float* pw2   = (const float*)d_in[9];
  const float* pb2   = (const float*)d_in[10];
  const float* pg1   = (const float*)d_in[11];
  const float* pbe1  = (const float*)d_in[12];
  const float* pg2   = (const float*)d_in[13];
  const float* pbe2  = (const float*)d_in[14];
  const float* pg3   = (const float*)d_in[15];
  const float* pbe3  = (const float*)d_in[16];
  const float* ptemp = (const float*)d_in[17];
  const float* prf   = (const float*)d_in[18];

  float* out = (float*)d_out;
  float* ws  = (float*)d_ws;

  float* xout   = ws + OXOUT;
  ushort* kb    = (ushort*)(ws + OKB);
  float* vhb    = ws + OVH;
  ushort* qb    = (ushort*)(ws + OQB);
  float* qp     = ws + OQP;
  float* csinv  = ws + OCS;
  float* l0part = ws + OLP;
  float* updb   = ws + OUPD;
  float* h1     = ws + OH1;
  float* h2p    = ws + OH2;
  ushort* qwb   = (ushort*)(ws + OQWB);
  ushort* w1b   = (ushort*)(ws + OW1B);
  ushort* w2b   = (ushort*)(ws + OW2B);

  // d_out regions double as scratch until the attn outputs are written (it==2)
  float* attnq = out + 371712;
  float* attnk = out + 371712 + 47579136;
  float* kvbuf = attnq;                         // dead before attn_q written
  float* cpart = attnq + 8388608;               // 49*968*384 f, dead after ln1
  ushort* wtb  = (ushort*)attnk;                // dead after conv
  ushort* xb16 = (ushort*)(attnk + 3612672);    // dead after kv gemm
  ushort* kvwb = (ushort*)(attnk + 3612672 + 1572864);  // dead after kv gemm

  // ---- packing (loop-invariant, single fused launch) ----
  packall<<<dim3(37632), 256, 0, stream>>>(px, xb16, pcw, wtb, pkvw, kvwb,
                                           pqw, qwb, pw1, w1b, pw2, w2b);

  // ---- precompute (loop-invariant) ----
  convm<<<dim3(8,3,NSLICE), 256, 0, stream>>>(xb16, wtb, cpart);
  lnk<0><<<dim3(MOUT), 384, 0, stream>>>(cpart, pcb, pg1, pbe1, xout);
  gemmm<0,true><<<dim3(64,6), 256, 0, stream>>>(xb16, kvwb, pkvb, kvbuf, MIN_, 768, 384);
  rosek<<<dim3((BB*H_*NIN+255)/256), 256, 0, stream>>>(kvbuf, prf, ptemp, kb, vhb);

  // ---- 3 iterations ----
  for (int it=0; it<3; ++it){
    gemm64<0><<<dim3(16,6), 256, 0, stream>>>(xout, qwb, pqb, qp, MOUT, 384, 384);
    roseq<<<dim3(48), 256, 0, stream>>>(qp, prf, qb);
    rowk<<<dim3(8,16,24), 256, 0, stream>>>(qb, kb, l0part);
    colk_f<<<dim3(16,24), 256, 0, stream>>>(qb, kb, l0part, csinv);
    if (it==2){
      pv_f<true ><<<dim3(16,24), 256, 0, stream>>>(qb, kb, vhb, l0part, csinv, updb, attnq, attnk);
    } else {
      pv_f<false><<<dim3(16,24), 256, 0, stream>>>(qb, kb, vhb, l0part, csinv, updb, attnq, attnk);
    }
    lnk<1><<<dim3(MOUT), 384, 0, stream>>>(updb, pcb, pg2, pbe2, xout);
    gemm64<1><<<dim3(16,24), 256, 0, stream>>>(xout, w1b, pb1, h1, MOUT, 1536, 384);
    gemm64sk<<<dim3(16,6,4), 256, 0, stream>>>(h1, w2b, h2p);
    lnk<3><<<dim3(MOUT), 384, 0, stream>>>(h2p, pb2, pg3, pbe3, xout);
  }

  copyk<<<dim3((371712+255)/256), 256, 0, stream>>>(xout, out, 371712);
}

// Round 15
// 1053.957 us; speedup vs baseline: 1.9658x; 1.0127x over previous
//
#include <hip/hip_runtime.h>
#include <math.h>

// ---------------- problem constants ----------------
#define BB 2
#define D_ 384
#define H_ 12
#define HD 32
#define NIN 4096            // 64*64
#define NOUT 484            // 22*22
#define MOUT (BB*NOUT)      // 968
#define MIN_ (BB*NIN)       // 8192
#define QW_ 22
#define CK 18816            // D*7*7
#define NSLICE 49           // conv split-K: one slice per (ky,kx), K=384 each
#define LN_EPS 1e-5f
#define EPS_ 1.1920929e-07f

typedef short bf16x8 __attribute__((ext_vector_type(8)));
typedef float f32x4  __attribute__((ext_vector_type(4)));

__device__ __forceinline__ unsigned f2bf(float f){   // RNE fp32->bf16 bits
  unsigned u = __float_as_uint(f);
  u += 0x7fffu + ((u>>16)&1u);
  return u>>16;
}

// ---------------- ws layout (floats) ----------------
static const size_t OXOUT = 0;                       // 371712
static const size_t OKB   = 371712;                  // K bf16: 24*4096*32 ush = 1572864 f
static const size_t OVH   = OKB + 1572864;           // V fp32: 3145728
static const size_t OQB   = OVH + 3145728;           // Q bf16: 24*512*32 ush = 196608 f
static const size_t OQP   = OQB + 196608;            // 371712 (unused, kept for layout)
static const size_t OL0   = OQP + 371712;            // 12288 (unused, kept for layout)
static const size_t OCS   = OL0 + 12288;             // 98304
static const size_t OLP   = OCS + 98304;             // 196608
static const size_t OUPD  = OLP + 196608;            // 371712
static const size_t OH1   = OUPD + 371712;           // 1486848
static const size_t OH2   = OH1 + 1486848;           // 4*371712 = 1486848 (mlp2 split-K parts)
static const size_t OQWB  = OH2 + 1486848;           // 73728
static const size_t OW1B  = OQWB + 73728;            // 294912
static const size_t OW2B  = OW1B + 294912;           // 294912
// total = 9,974,784 floats = 39.9 MB

// ---------------- fused packing kernel --------------------------------------
// block ranges: [0,3072) packxk | [3072,31296) wtk2 | [31296,32448) kv
//               [32448,33024) q | [33024,35328) w1 | [35328,37632) w2
//               [37632,37674) qb pad-zero (q in [484,512), loop-invariant)
__global__ __launch_bounds__(256)
void packall(const float* __restrict__ px,  ushort* __restrict__ xb,
             const float* __restrict__ cw,  ushort* __restrict__ wtb,
             const float* __restrict__ wkv, ushort* __restrict__ kvwb,
             const float* __restrict__ wq,  ushort* __restrict__ qwb,
             const float* __restrict__ w1,  ushort* __restrict__ w1b,
             const float* __restrict__ w2,  ushort* __restrict__ w2b,
             ushort* __restrict__ qbpad){
  const int bid = blockIdx.x, t = threadIdx.x;
  if (bid < 3072){                       // x -> bf16, 4 floats/thread
    int base = (bid*256 + t)*4;
    float4 v = *(const float4*)(px + base);
    uint2 o;
    o.x = f2bf(v.x) | (f2bf(v.y)<<16);
    o.y = f2bf(v.z) | (f2bf(v.w)<<16);
    *(uint2*)(xb + base) = o;
  } else if (bid < 31296){               // conv_w [n][di][ky][kx] -> [kyx][n][di]
    int i = (bid-3072)*256 + t;
    int n = i / CK;
    int r = i - n*CK;
    int di = r/49, kyx = r - di*49;
    wtb[((size_t)kyx*D_ + n)*D_ + di] = (ushort)f2bf(cw[i]);
  } else if (bid < 32448){               // kv_w [384][768] -> [n][k]
    int i = (bid-31296)*256 + t;
    int k = i/768, n = i - k*768;
    kvwb[(size_t)n*384 + k] = (ushort)f2bf(wkv[i]);
  } else if (bid < 33024){               // q_w [384][384] -> [n][k]
    int i = (bid-32448)*256 + t;
    int k = i/384, n = i - k*384;
    qwb[(size_t)n*384 + k] = (ushort)f2bf(wq[i]);
  } else if (bid < 35328){               // w1 [384][1536] -> [n][k]
    int i = (bid-33024)*256 + t;
    int k = i/1536, n = i - k*1536;
    w1b[(size_t)n*384 + k] = (ushort)f2bf(w1[i]);
  } else if (bid < 37632){               // w2 [1536][384] -> [n][k]
    int i = (bid-35328)*256 + t;
    int k = i/384, n = i - k*384;
    w2b[(size_t)n*1536 + k] = (ushort)f2bf(w2[i]);
  } else {                               // qb pad-zero: 24bh x 28q x 32d ush = 10752 uints
    int idx = (bid-37632)*256 + t;       // < 10752 exactly (42 blocks)
    int e  = idx*2;
    int bh = e / 896;                    // 28*32
    int rm = e - bh*896;
    int rr = rm >> 5, d = rm & 31;
    *(unsigned*)(qbpad + ((size_t)bh*512 + 484 + rr)*HD + d) = 0u;
  }
}

// -------- MFMA conv: per-slice GEMM, 128x128 tile, 4 waves x (4x4) 16x16x32 --------
__global__ __launch_bounds__(256)
void convm(const ushort* __restrict__ xb, const ushort* __restrict__ wtb,
           float* __restrict__ part){
  __shared__ ushort As[128][40];
  __shared__ ushort Bs[128][40];
  const int t  = threadIdx.x;
  const int m0 = blockIdx.x*128, n0 = blockIdx.y*128, z = blockIdx.z;
  const int ky = z/7, kx = z - ky*7;
  const int r = t>>1, half = t&1;
  const int m = m0 + r;
  const int mq = (m < MOUT) ? m : 0;
  const int bbv = mq/NOUT, qq = mq - bbv*NOUT;
  const int oy = qq/QW_, ox = qq - oy*QW_;
  const int iy = oy*3-3+ky, ix = ox*3-3+kx;
  const bool aval = (m<MOUT) && iy>=0 && iy<64 && ix>=0 && ix<64;
  const ushort* asrc = xb + ((size_t)bbv*NIN + (aval ? iy*64+ix : 0))*D_ + half*16;
  const ushort* bsrc = wtb + ((size_t)z*D_ + n0 + r)*D_ + half*16;

  const int wv = t>>6;
  const int wr = (wv>>1)*64, wc = (wv&1)*64;
  const int ln = t&15, lq = (t>>4)&3;

  f32x4 acc[4][4];
#pragma unroll
  for (int i=0;i<4;i++)
#pragma unroll
    for (int j=0;j<4;j++) acc[i][j] = (f32x4){0.f,0.f,0.f,0.f};

  for (int dk=0; dk<D_; dk+=32){
    uint4 a0 = {0,0,0,0}, a1 = {0,0,0,0};
    if (aval){ a0 = *(const uint4*)(asrc+dk); a1 = *(const uint4*)(asrc+dk+8); }
    uint4 b0 = *(const uint4*)(bsrc+dk), b1 = *(const uint4*)(bsrc+dk+8);
    *(uint4*)&As[r][half*16]   = a0;  *(uint4*)&As[r][half*16+8] = a1;
    *(uint4*)&Bs[r][half*16]   = b0;  *(uint4*)&Bs[r][half*16+8] = b1;
    __syncthreads();
    bf16x8 af[4], bfr[4];
#pragma unroll
    for (int i=0;i<4;i++) af[i]  = *(const bf16x8*)&As[wr+i*16+ln][lq*8];
#pragma unroll
    for (int j=0;j<4;j++) bfr[j] = *(const bf16x8*)&Bs[wc+j*16+ln][lq*8];
#pragma unroll
    for (int i=0;i<4;i++)
#pragma unroll
      for (int j=0;j<4;j++)
        acc[i][j] = __builtin_amdgcn_mfma_f32_16x16x32_bf16(af[i], bfr[j], acc[i][j], 0,0,0);
    __syncthreads();
  }
#pragma unroll
  for (int i=0;i<4;i++){
    int rowb = m0 + wr + i*16 + lq*4;
#pragma unroll
    for (int j=0;j<4;j++){
      int col = n0 + wc + j*16 + ln;
#pragma unroll
      for (int rg=0; rg<4; rg++){
        int row = rowb + rg;
        if (row < MOUT) part[((size_t)z*MOUT + row)*D_ + col] = acc[i][j][rg];
      }
    }
  }
}

// -------- gemmkv: KV GEMM (128x128 tile) + fused rose-K / V-gather epilogue ----
// A = xb bf16 [8192][384]; W = kvwb [768][384]; out: kb bf16, vhb fp32
__global__ __launch_bounds__(256)
void gemmkv(const ushort* __restrict__ Ain, const ushort* __restrict__ Wb,
            const float* __restrict__ bias, const float* __restrict__ rf,
            const float* __restrict__ temp,
            ushort* __restrict__ kb, float* __restrict__ vhb){
  __shared__ ushort As[128][40];
  __shared__ ushort Bs[128][40];
  const int t  = threadIdx.x;
  const int m0 = blockIdx.x*128, n0 = blockIdx.y*128;
  const int r = t>>1, half = t&1;
  const int m = m0 + r;
  const ushort* ab16 = Ain + (size_t)m*384 + half*16;
  const ushort* bsrc = Wb + (size_t)(n0 + r)*384 + half*16;

  const int wv = t>>6;
  const int wr = (wv>>1)*64, wc = (wv&1)*64;
  const int ln = t&15, lq = (t>>4)&3;

  f32x4 acc[4][4];
#pragma unroll
  for (int i=0;i<4;i++)
#pragma unroll
    for (int j=0;j<4;j++) acc[i][j] = (f32x4){0.f,0.f,0.f,0.f};

  for (int dk=0; dk<384; dk+=32){
    uint4 a0 = *(const uint4*)(ab16+dk), a1 = *(const uint4*)(ab16+dk+8);
    uint4 b0 = *(const uint4*)(bsrc+dk), b1 = *(const uint4*)(bsrc+dk+8);
    *(uint4*)&As[r][half*16]   = a0;  *(uint4*)&As[r][half*16+8] = a1;
    *(uint4*)&Bs[r][half*16]   = b0;  *(uint4*)&Bs[r][half*16+8] = b1;
    __syncthreads();
    bf16x8 af[4], bfr[4];
#pragma unroll
    for (int i=0;i<4;i++) af[i]  = *(const bf16x8*)&As[wr+i*16+ln][lq*8];
#pragma unroll
    for (int j=0;j<4;j++) bfr[j] = *(const bf16x8*)&Bs[wc+j*16+ln][lq*8];
#pragma unroll
    for (int i=0;i<4;i++)
#pragma unroll
      for (int j=0;j<4;j++)
        acc[i][j] = __builtin_amdgcn_mfma_f32_16x16x32_bf16(af[i], bfr[j], acc[i][j], 0,0,0);
    __syncthreads();
  }
  const float T = temp[0];
#pragma unroll
  for (int i=0;i<4;i++){
    int rowb = m0 + wr + i*16 + lq*4;
#pragma unroll
    for (int j=0;j<4;j++){
      int col = n0 + wc + j*16 + ln;
      float bv = bias[col];
#pragma unroll
      for (int rg=0; rg<4; rg++){
        int row = rowb + rg;                    // < 8192 always (exact tiling)
        float v = acc[i][j][rg] + bv;
        float partner = __shfl_xor(v, 1);       // col^1, same row
        int b = row >> 12, n = row & 4095;
        int iy = n >> 6, ix = n & 63;
        if (col < 384){                         // K path: rose + temp + bf16
          int h = col >> 5, d = col & 31;
          float res = v;
          if (d < 16){
            int tp = d >> 1, s2 = tp >> 2, p2 = tp & 3;
            float coord = (s2==0) ? (float)iy : (float)ix;
            float ang = coord * rf[(h*2+s2)*4 + p2];
            float sn, cn; sincosf(ang, &sn, &cn);
            res = (d & 1) ? (partner*sn + v*cn) : (v*cn - partner*sn);
          }
          kb[((size_t)(b*H_ + h)*NIN + n)*HD + d] = (ushort)f2bf(T*res);
        } else {                                // V path: fp32 gather
          int c2 = col - 384;
          int h = c2 >> 5, d = c2 & 31;
          vhb[((size_t)(b*H_ + h)*NIN + n)*HD + d] = v;
        }
      }
    }
  }
}

// -------- gemm64q: q-GEMM 64x64 tile + fused rose-Q epilogue -> qb bf16 --------
__global__ __launch_bounds__(256)
void gemm64q(const float* __restrict__ Ain, const ushort* __restrict__ Wb,
             const float* __restrict__ bias, const float* __restrict__ rf,
             ushort* __restrict__ qb){
  __shared__ ushort As[64][40];
  __shared__ ushort Bs[64][40];
  const int t  = threadIdx.x;
  const int m0 = blockIdx.x*64, n0 = blockIdx.y*64;
  const int r = t>>2, seg = t&3;
  const int m = m0 + r;
  const bool aval = (m < MOUT);
  const float*  asrc = Ain + (size_t)(aval?m:0)*384 + seg*8;
  const ushort* bsrc = Wb + (size_t)(n0 + r)*384 + seg*8;

  const int wv = t>>6;
  const int wr = (wv>>1)*32, wc = (wv&1)*32;
  const int ln = t&15, lq = (t>>4)&3;

  f32x4 acc[2][2];
  acc[0][0]=(f32x4){0,0,0,0}; acc[0][1]=(f32x4){0,0,0,0};
  acc[1][0]=(f32x4){0,0,0,0}; acc[1][1]=(f32x4){0,0,0,0};

  for (int dk=0; dk<384; dk+=32){
    uint4 a0 = {0,0,0,0};
    if (aval){
      float4 f0 = *(const float4*)(asrc+dk), f1 = *(const float4*)(asrc+dk+4);
      a0.x = f2bf(f0.x)|(f2bf(f0.y)<<16); a0.y = f2bf(f0.z)|(f2bf(f0.w)<<16);
      a0.z = f2bf(f1.x)|(f2bf(f1.y)<<16); a0.w = f2bf(f1.z)|(f2bf(f1.w)<<16);
    }
    uint4 b0 = *(const uint4*)(bsrc+dk);
    *(uint4*)&As[r][seg*8] = a0;
    *(uint4*)&Bs[r][seg*8] = b0;
    __syncthreads();
    bf16x8 af[2], bfr[2];
#pragma unroll
    for (int i=0;i<2;i++) af[i]  = *(const bf16x8*)&As[wr+i*16+ln][lq*8];
#pragma unroll
    for (int j=0;j<2;j++) bfr[j] = *(const bf16x8*)&Bs[wc+j*16+ln][lq*8];
#pragma unroll
    for (int i=0;i<2;i++)
#pragma unroll
      for (int j=0;j<2;j++)
        acc[i][j] = __builtin_amdgcn_mfma_f32_16x16x32_bf16(af[i], bfr[j], acc[i][j], 0,0,0);
    __syncthreads();
  }
#pragma unroll
  for (int i=0;i<2;i++){
    int rowb = m0 + wr + i*16 + lq*4;
#pragma unroll
    for (int j=0;j<2;j++){
      int col = n0 + wc + j*16 + ln;
      float bv = bias[col];
#pragma unroll
      for (int rg=0; rg<4; rg++){
        int row = rowb + rg;
        float v = acc[i][j][rg] + bv;
        float partner = __shfl_xor(v, 1);       // col^1, same row
        if (row < MOUT){
          int b = (row >= NOUT) ? 1 : 0;
          int q = row - b*NOUT;
          int oy = q / QW_, ox = q - oy*QW_;
          int h = col >> 5, d = col & 31;
          float res = v;
          if (d < 16){
            int tp = d >> 1, s2 = tp >> 2, p2 = tp & 3;
            float coord = (s2==0) ? 3.0f*(float)oy : 3.0f*(float)ox;
            float ang = coord * rf[(h*2+s2)*4 + p2];
            float sn, cn; sincosf(ang, &sn, &cn);
            res = (d & 1) ? (partner*sn + v*cn) : (v*cn - partner*sn);
          }
          qb[((size_t)(b*H_ + h)*512 + q)*HD + d] = (ushort)f2bf(res);
        }
      }
    }
  }
}

// -------- gemm64: 64x64 tile, 4 waves x (2x2) 16x16x32 — MLP1 (gelu) ----------
template<int ACT>
__global__ __launch_bounds__(256)
void gemm64(const float* __restrict__ Ain, const ushort* __restrict__ Wb,
            const float* __restrict__ bias, float* __restrict__ C,
            int M, int N, int K){
  __shared__ ushort As[64][40];
  __shared__ ushort Bs[64][40];
  const int t  = threadIdx.x;
  const int m0 = blockIdx.x*64, n0 = blockIdx.y*64;
  const int r = t>>2, seg = t&3;
  const int m = m0 + r;
  const bool aval = (m < M);
  const float*  asrc = Ain + (size_t)(aval?m:0)*K + seg*8;
  const ushort* bsrc = Wb + (size_t)(n0 + r)*K + seg*8;

  const int wv = t>>6;
  const int wr = (wv>>1)*32, wc = (wv&1)*32;
  const int ln = t&15, lq = (t>>4)&3;

  f32x4 acc[2][2];
  acc[0][0]=(f32x4){0,0,0,0}; acc[0][1]=(f32x4){0,0,0,0};
  acc[1][0]=(f32x4){0,0,0,0}; acc[1][1]=(f32x4){0,0,0,0};

  for (int dk=0; dk<K; dk+=32){
    uint4 a0 = {0,0,0,0};
    if (aval){
      float4 f0 = *(const float4*)(asrc+dk), f1 = *(const float4*)(asrc+dk+4);
      a0.x = f2bf(f0.x)|(f2bf(f0.y)<<16); a0.y = f2bf(f0.z)|(f2bf(f0.w)<<16);
      a0.z = f2bf(f1.x)|(f2bf(f1.y)<<16); a0.w = f2bf(f1.z)|(f2bf(f1.w)<<16);
    }
    uint4 b0 = *(const uint4*)(bsrc+dk);
    *(uint4*)&As[r][seg*8] = a0;
    *(uint4*)&Bs[r][seg*8] = b0;
    __syncthreads();
    bf16x8 af[2], bfr[2];
#pragma unroll
    for (int i=0;i<2;i++) af[i]  = *(const bf16x8*)&As[wr+i*16+ln][lq*8];
#pragma unroll
    for (int j=0;j<2;j++) bfr[j] = *(const bf16x8*)&Bs[wc+j*16+ln][lq*8];
#pragma unroll
    for (int i=0;i<2;i++)
#pragma unroll
      for (int j=0;j<2;j++)
        acc[i][j] = __builtin_amdgcn_mfma_f32_16x16x32_bf16(af[i], bfr[j], acc[i][j], 0,0,0);
    __syncthreads();
  }
#pragma unroll
  for (int i=0;i<2;i++){
    int rowb = m0 + wr + i*16 + lq*4;
#pragma unroll
    for (int j=0;j<2;j++){
      int col = n0 + wc + j*16 + ln;
      float bv = bias[col];
#pragma unroll
      for (int rg=0; rg<4; rg++){
        int row = rowb + rg;
        if (row < M){
          float v = acc[i][j][rg] + bv;
          if (ACT==1) v = 0.5f*v*(1.f + erff(v*0.7071067811865475f));
          C[(size_t)row*N + col] = v;
        }
      }
    }
  }
}

// -------- gemm64sk: mlp2 split-K, 64x64 tile, part[z] = h1[:,z*384:]*W2slice ----
__global__ __launch_bounds__(256)
void gemm64sk(const float* __restrict__ Ain, const ushort* __restrict__ Wb,
              float* __restrict__ part){
  __shared__ ushort As[64][40];
  __shared__ ushort Bs[64][40];
  const int t  = threadIdx.x;
  const int m0 = blockIdx.x*64, n0 = blockIdx.y*64, z = blockIdx.z;
  const int r = t>>2, seg = t&3;
  const int m = m0 + r;
  const bool aval = (m < MOUT);
  const float*  asrc = Ain + (size_t)(aval?m:0)*1536 + z*384 + seg*8;
  const ushort* bsrc = Wb + (size_t)(n0 + r)*1536 + z*384 + seg*8;

  const int wv = t>>6;
  const int wr = (wv>>1)*32, wc = (wv&1)*32;
  const int ln = t&15, lq = (t>>4)&3;

  f32x4 acc[2][2];
  acc[0][0]=(f32x4){0,0,0,0}; acc[0][1]=(f32x4){0,0,0,0};
  acc[1][0]=(f32x4){0,0,0,0}; acc[1][1]=(f32x4){0,0,0,0};

  for (int dk=0; dk<384; dk+=32){
    uint4 a0 = {0,0,0,0};
    if (aval){
      float4 f0 = *(const float4*)(asrc+dk), f1 = *(const float4*)(asrc+dk+4);
      a0.x = f2bf(f0.x)|(f2bf(f0.y)<<16); a0.y = f2bf(f0.z)|(f2bf(f0.w)<<16);
      a0.z = f2bf(f1.x)|(f2bf(f1.y)<<16); a0.w = f2bf(f1.z)|(f2bf(f1.w)<<16);
    }
    uint4 b0 = *(const uint4*)(bsrc+dk);
    *(uint4*)&As[r][seg*8] = a0;
    *(uint4*)&Bs[r][seg*8] = b0;
    __syncthreads();
    bf16x8 af[2], bfr[2];
#pragma unroll
    for (int i=0;i<2;i++) af[i]  = *(const bf16x8*)&As[wr+i*16+ln][lq*8];
#pragma unroll
    for (int j=0;j<2;j++) bfr[j] = *(const bf16x8*)&Bs[wc+j*16+ln][lq*8];
#pragma unroll
    for (int i=0;i<2;i++)
#pragma unroll
      for (int j=0;j<2;j++)
        acc[i][j] = __builtin_amdgcn_mfma_f32_16x16x32_bf16(af[i], bfr[j], acc[i][j], 0,0,0);
    __syncthreads();
  }
#pragma unroll
  for (int i=0;i<2;i++){
    int rowb = m0 + wr + i*16 + lq*4;
#pragma unroll
    for (int j=0;j<2;j++){
      int col = n0 + wc + j*16 + ln;
#pragma unroll
      for (int rg=0; rg<4; rg++){
        int row = rowb + rg;
        if (row < MOUT) part[((size_t)z*MOUT + row)*D_ + col] = acc[i][j][rg];
      }
    }
  }
}

// ---------------- block reduction over 384 threads --------------------------
__device__ __forceinline__ float block_sum_384(float v){
  __shared__ float red[6];
#pragma unroll
  for (int o=32;o>0;o>>=1) v += __shfl_down(v,o);
  const int lane = threadIdx.x & 63, w = threadIdx.x >> 6;
  __syncthreads();
  if (lane==0) red[w] = v;
  __syncthreads();
  return red[0]+red[1]+red[2]+red[3]+red[4]+red[5];
}

// LN kernel. MODE 0: in = 49 conv partials (+bias cb) -> write xout
//            MODE 1: in = upd[bh][q][hd] gathered -> xout += LN
//            MODE 3: in = 4 mlp2 partials (+bias cb) -> xout += LN
// FINAL (MODE 3 only): write xout+LN into fout instead of updating xout
template<int MODE, bool FINAL>
__global__ __launch_bounds__(384)
void lnk(const float* __restrict__ in, const float* __restrict__ cb,
         const float* __restrict__ gg, const float* __restrict__ bb,
         float* __restrict__ xout, float* __restrict__ fout){
  const int m = blockIdx.x, d = threadIdx.x;
  float v;
  if (MODE==0){
    v = cb[d];
    for (int z=0; z<NSLICE; z++) v += in[((size_t)z*MOUT + m)*D_ + d];
  } else if (MODE==1){
    int b = m/NOUT, q = m - b*NOUT;
    int h = d>>5, dd2 = d&31;
    v = in[(((size_t)(b*H_ + h))*NOUT + q)*HD + dd2];
  } else {
    v = cb[d];
#pragma unroll
    for (int z=0; z<4; z++) v += in[((size_t)z*MOUT + m)*D_ + d];
  }
  float mu  = block_sum_384(v) * (1.f/D_);
  float ce  = v - mu;
  float var = block_sum_384(ce*ce) * (1.f/D_);
  float o = ce * rsqrtf(var + LN_EPS) * gg[d] + bb[d];
  float* dst = xout + (size_t)m*D_ + d;
  if (MODE==0)       *dst = o;
  else if (FINAL)    fout[(size_t)m*D_ + d] = *dst + o;
  else               *dst += o;
}

// ------- rowk: MFMA QK^T (64q x 256k), exp, rowsum partials (no E store) ----
__global__ __launch_bounds__(256)
void rowk(const ushort* __restrict__ qb, const ushort* __restrict__ kb,
          float* __restrict__ l0part){
  __shared__ ushort Qs[64][40];
  __shared__ ushort Ks[256][40];
  __shared__ float  red[4][64];
  const int t  = threadIdx.x;
  const int q0 = blockIdx.x*64;
  const int kt = blockIdx.y;
  const int k0 = kt*256;
  const int bh = blockIdx.z;
  {  // stage Q: 64 rows x 32 ush
    int row = t>>2, seg = t&3;
    const ushort* src = qb + ((size_t)bh*512 + q0 + row)*HD + seg*8;
    *(uint4*)&Qs[row][seg*8] = *(const uint4*)src;
  }
  {  // stage K: 256 rows x 32 ush
    const ushort* src = kb + ((size_t)bh*NIN + k0 + t)*HD;
#pragma unroll
    for (int g=0; g<4; g++)
      *(uint4*)&Ks[t][g*8] = *(const uint4*)(src + g*8);
  }
  __syncthreads();
  const int wv = t>>6;
  const int wc = wv*64;
  const int ln = t&15, lq = (t>>4)&3;
  bf16x8 af[4], bfr[4];
#pragma unroll
  for (int i=0;i<4;i++) af[i]  = *(const bf16x8*)&Qs[i*16+ln][lq*8];
#pragma unroll
  for (int j=0;j<4;j++) bfr[j] = *(const bf16x8*)&Ks[wc+j*16+ln][lq*8];
  f32x4 acc[4][4];
  const f32x4 zero = (f32x4){0.f,0.f,0.f,0.f};
#pragma unroll
  for (int i=0;i<4;i++)
#pragma unroll
    for (int j=0;j<4;j++)
      acc[i][j] = __builtin_amdgcn_mfma_f32_16x16x32_bf16(af[i], bfr[j], zero, 0,0,0);
  float rs[4][4];
#pragma unroll
  for (int i=0;i<4;i++){
#pragma unroll
    for (int rg=0; rg<4; rg++){
      float s = 0.f;
#pragma unroll
      for (int j=0;j<4;j++) s += __expf(acc[i][j][rg]);
      rs[i][rg] = s;
    }
  }
#pragma unroll
  for (int i=0;i<4;i++)
#pragma unroll
    for (int rg=0;rg<4;rg++){
      float v = rs[i][rg];
      v += __shfl_xor(v,1); v += __shfl_xor(v,2);
      v += __shfl_xor(v,4); v += __shfl_xor(v,8);
      rs[i][rg] = v;
    }
  if (ln==0){
#pragma unroll
    for (int i=0;i<4;i++)
#pragma unroll
      for (int rg=0;rg<4;rg++)
        red[wv][i*16+lq*4+rg] = rs[i][rg];
  }
  __syncthreads();
  if (t < 64){
    float tot = red[0][t]+red[1][t]+red[2][t]+red[3][t];
    l0part[((size_t)bh*512 + q0 + t)*16 + kt] = tot;
  }
}

// ------- colk_f: recompute S^T via MFMA (A=K, B=Q); csinv[k]=1/(sum_q E*li+EPS)
//         l0inv reduced inline from l0part (16 k-tile partials) ---------------
__global__ __launch_bounds__(256)
void colk_f(const ushort* __restrict__ qb, const ushort* __restrict__ kb,
            const float* __restrict__ l0part, float* __restrict__ csinv){
  __shared__ ushort Ks[256][40];
  __shared__ ushort Qs[64][40];
  __shared__ float  lis[64];
  const int t  = threadIdx.x;
  const int k0 = blockIdx.x*256;
  const int bh = blockIdx.y;
  {  // stage K tile once: 256 rows x 32 ush
    const ushort* src = kb + ((size_t)bh*NIN + k0 + t)*HD;
#pragma unroll
    for (int g=0; g<4; g++)
      *(uint4*)&Ks[t][g*8] = *(const uint4*)(src + g*8);
  }
  const int wv = t>>6, ln = t&15, lq = (t>>4)&3;
  const f32x4 zero = (f32x4){0.f,0.f,0.f,0.f};
  f32x4 colacc[4];
#pragma unroll
  for (int i=0;i<4;i++) colacc[i] = zero;
  for (int qc=0; qc<512; qc+=64){
    __syncthreads();
    {  // stage Q chunk: 64 rows x 32 ush
      int row = t>>2, seg = t&3;
      *(uint4*)&Qs[row][seg*8] =
        *(const uint4*)(qb + ((size_t)bh*512 + qc + row)*HD + seg*8);
    }
    if (t < 64){
      int q = qc + t;
      const float* lp = l0part + ((size_t)bh*512 + q)*16;
      float s = 0.f;
#pragma unroll
      for (int j=0;j<16;j++) s += lp[j];
      lis[t] = (q < NOUT) ? 1.f/s : 0.f;
    }
    __syncthreads();
    bf16x8 af[4], bfr[4];
#pragma unroll
    for (int i=0;i<4;i++) af[i]  = *(const bf16x8*)&Ks[wv*64+i*16+ln][lq*8];
#pragma unroll
    for (int j=0;j<4;j++) bfr[j] = *(const bf16x8*)&Qs[j*16+ln][lq*8];
#pragma unroll
    for (int j=0;j<4;j++){
      float liv = lis[j*16+ln];
#pragma unroll
      for (int i=0;i<4;i++){
        f32x4 c = __builtin_amdgcn_mfma_f32_16x16x32_bf16(af[i], bfr[j], zero, 0,0,0);
#pragma unroll
        for (int rg=0;rg<4;rg++)
          colacc[i][rg] += __expf(c[rg]) * liv;
      }
    }
  }
#pragma unroll
  for (int i=0;i<4;i++)
#pragma unroll
    for (int rg=0;rg<4;rg++){
      float v = colacc[i][rg];
      v += __shfl_xor(v,1); v += __shfl_xor(v,2);
      v += __shfl_xor(v,4); v += __shfl_xor(v,8);
      colacc[i][rg] = v;
    }
  if (ln==0){
#pragma unroll
    for (int i=0;i<4;i++){
      float4 o;
      o.x = 1.f/(colacc[i][0] + EPS_);
      o.y = 1.f/(colacc[i][1] + EPS_);
      o.z = 1.f/(colacc[i][2] + EPS_);
      o.w = 1.f/(colacc[i][3] + EPS_);
      *(float4*)(csinv + (size_t)bh*NIN + k0 + wv*64 + i*16 + lq*4) = o;
    }
  }
}

// ------- pv_f: recompute S via MFMA (K frags from L2); P=exp(S)*li fp32 in LDS;
//         PV via 3-term bf16x2-split MFMA; l0inv reduced inline from l0part;
//         LAST: write attnk = P, attnq = P*ci -------------------------------
template<bool LAST>
__global__ __launch_bounds__(256)
void pv_f(const ushort* __restrict__ qb, const ushort* __restrict__ kb,
          const float* __restrict__ vh, const float* __restrict__ l0part,
          const float* __restrict__ csinv, float* __restrict__ upd,
          float* __restrict__ attnq, float* __restrict__ attnk){
  __shared__ ushort   Qs[32][40];     // Q tile bf16
  __shared__ float    Ps[128][36];    // P fp32 [k][q]; reused as Ured at end
  __shared__ unsigned Vt[32][132];    // ci*V transposed [d][k], (bf16hi<<16)|bf16lo
  __shared__ float    lis[32];
  __shared__ float    cis[128];
  const int t  = threadIdx.x;
  const int q0 = blockIdx.x*32;
  const int bh = blockIdx.y;
  {  // stage Q bf16 once: 32 rows x 32 ush
    int row = t>>3, seg = t&7;
    *(uint2*)&Qs[row][seg*4] =
      *(const uint2*)(qb + ((size_t)bh*512 + q0 + row)*HD + seg*4);
  }
  if (t < 32){
    int q = q0 + t;
    const float* lp = l0part + ((size_t)bh*512 + q)*16;
    float s = 0.f;
#pragma unroll
    for (int j=0;j<16;j++) s += lp[j];
    lis[t] = (q < NOUT) ? 1.f/s : 0.f;
  }
  __syncthreads();
  const int wv = t>>6, ln = t&15, lq = (t>>4)&3;
  const bf16x8 af0 = *(const bf16x8*)&Qs[ln][lq*8];        // hoisted Q frags
  const bf16x8 af1 = *(const bf16x8*)&Qs[16+ln][lq*8];
  float lr[2][4];
#pragma unroll
  for (int i=0;i<2;i++)
#pragma unroll
    for (int rg=0;rg<4;rg++) lr[i][rg] = lis[i*16 + lq*4 + rg];
  const f32x4 zero = (f32x4){0.f,0.f,0.f,0.f};
  f32x4 acc[2][2];
  acc[0][0]=zero; acc[0][1]=zero; acc[1][0]=zero; acc[1][1]=zero;
  const ushort* kfrag = kb + ((size_t)bh*NIN)*HD;
  for (int kc=0; kc<NIN; kc+=128){
    if (LAST) __syncthreads();   // prev tile's cross-wave Ps/cis reads done
    {  // stage ci*V transposed, packed bf16 hi/lo; thread t covers col r=t>>1
      int r = t>>1, half = t&1;
      float civ = csinv[(size_t)bh*NIN + kc + r];
      if (half==0) cis[r] = civ;
      const float* pv = vh + ((size_t)bh*NIN + kc + r)*HD + half*16;
      float4 b0=*(const float4*)pv, b1=*(const float4*)(pv+4),
             b2=*(const float4*)(pv+8), b3=*(const float4*)(pv+12);
      float w[16] = {civ*b0.x, civ*b0.y, civ*b0.z, civ*b0.w,
                     civ*b1.x, civ*b1.y, civ*b1.z, civ*b1.w,
                     civ*b2.x, civ*b2.y, civ*b2.z, civ*b2.w,
                     civ*b3.x, civ*b3.y, civ*b3.z, civ*b3.w};
      int dbase = half*16;
#pragma unroll
      for (int i2=0;i2<16;i2++){
        unsigned hi = f2bf(w[i2]);
        float hif = __uint_as_float(hi<<16);
        unsigned lo = f2bf(w[i2] - hif);
        Vt[dbase+i2][r] = (hi<<16) | lo;
      }
    }
    // S via MFMA, wave-local rows wv*32..wv*32+31 of Ps
    bf16x8 bf0 = *(const bf16x8*)(kfrag + (size_t)(kc + wv*32 +      ln)*HD + lq*8);
    bf16x8 bf1 = *(const bf16x8*)(kfrag + (size_t)(kc + wv*32 + 16 + ln)*HD + lq*8);
    {
      f32x4 c; float4 pw;
      c = __builtin_amdgcn_mfma_f32_16x16x32_bf16(af0, bf0, zero, 0,0,0);
      pw.x=__expf(c[0])*lr[0][0]; pw.y=__expf(c[1])*lr[0][1];
      pw.z=__expf(c[2])*lr[0][2]; pw.w=__expf(c[3])*lr[0][3];
      *(float4*)&Ps[wv*32 +      ln][      lq*4] = pw;
      c = __builtin_amdgcn_mfma_f32_16x16x32_bf16(af1, bf0, zero, 0,0,0);
      pw.x=__expf(c[0])*lr[1][0]; pw.y=__expf(c[1])*lr[1][1];
      pw.z=__expf(c[2])*lr[1][2]; pw.w=__expf(c[3])*lr[1][3];
      *(float4*)&Ps[wv*32 +      ln][16 + lq*4] = pw;
      c = __builtin_amdgcn_mfma_f32_16x16x32_bf16(af0, bf1, zero, 0,0,0);
      pw.x=__expf(c[0])*lr[0][0]; pw.y=__expf(c[1])*lr[0][1];
      pw.z=__expf(c[2])*lr[0][2]; pw.w=__expf(c[3])*lr[0][3];
      *(float4*)&Ps[wv*32 + 16 + ln][      lq*4] = pw;
      c = __builtin_amdgcn_mfma_f32_16x16x32_bf16(af1, bf1, zero, 0,0,0);
      pw.x=__expf(c[0])*lr[1][0]; pw.y=__expf(c[1])*lr[1][1];
      pw.z=__expf(c[2])*lr[1][2]; pw.w=__expf(c[3])*lr[1][3];
      *(float4*)&Ps[wv*32 + 16 + ln][16 + lq*4] = pw;
    }
    if (LAST){
      __syncthreads();   // cross-wave Ps/cis for the coalesced output bounce
      int row = t>>3, seg = t&7;
      int q = q0 + row;
      if (q < NOUT){
        float* ak = attnk + ((size_t)bh*NOUT + q)*NIN + kc + seg*16;
        float* aq = attnq + ((size_t)bh*NOUT + q)*NIN + kc + seg*16;
#pragma unroll
        for (int s=0;s<4;s++){
          int kk = seg*16 + s*4;
          float4 p = make_float4(Ps[kk][row], Ps[kk+1][row], Ps[kk+2][row], Ps[kk+3][row]);
          float4 c4 = *(const float4*)&cis[kk];
          *(float4*)(ak + s*4) = p;
          float4 pq;
          pq.x = p.x*c4.x; pq.y = p.y*c4.y; pq.z = p.z*c4.z; pq.w = p.w*c4.w;
          *(float4*)(aq + s*4) = pq;
        }
      }
    }
    // PV via MFMA on this wave's 32-k chunk (Ps/Vt wave-local)
    bf16x8 bhi[2], blo[2];
#pragma unroll
    for (int nf=0;nf<2;nf++){
#pragma unroll
      for (int j=0;j<8;j++){
        float p = Ps[wv*32 + lq*8 + j][nf*16 + ln];
        unsigned hi = f2bf(p);
        float hif = __uint_as_float(hi<<16);
        unsigned lo = f2bf(p - hif);
        bhi[nf][j] = (short)hi;
        blo[nf][j] = (short)lo;
      }
    }
    bf16x8 ahi[2], alo[2];
#pragma unroll
    for (int mf=0;mf<2;mf++){
      const unsigned* vrow = &Vt[mf*16+ln][wv*32 + lq*8];
      uint4 wa = *(const uint4*)vrow;
      uint4 wb = *(const uint4*)(vrow+4);
      ahi[mf][0]=(short)(wa.x>>16); alo[mf][0]=(short)(wa.x&0xffffu);
      ahi[mf][1]=(short)(wa.y>>16); alo[mf][1]=(short)(wa.y&0xffffu);
      ahi[mf][2]=(short)(wa.z>>16); alo[mf][2]=(short)(wa.z&0xffffu);
      ahi[mf][3]=(short)(wa.w>>16); alo[mf][3]=(short)(wa.w&0xffffu);
      ahi[mf][4]=(short)(wb.x>>16); alo[mf][4]=(short)(wb.x&0xffffu);
      ahi[mf][5]=(short)(wb.y>>16); alo[mf][5]=(short)(wb.y&0xffffu);
      ahi[mf][6]=(short)(wb.z>>16); alo[mf][6]=(short)(wb.z&0xffffu);
      ahi[mf][7]=(short)(wb.w>>16); alo[mf][7]=(short)(wb.w&0xffffu);
    }
#pragma unroll
    for (int mf=0;mf<2;mf++)
#pragma unroll
      for (int nf=0;nf<2;nf++){
        acc[mf][nf] = __builtin_amdgcn_mfma_f32_16x16x32_bf16(ahi[mf], bhi[nf], acc[mf][nf], 0,0,0);
        acc[mf][nf] = __builtin_amdgcn_mfma_f32_16x16x32_bf16(ahi[mf], blo[nf], acc[mf][nf], 0,0,0);
        acc[mf][nf] = __builtin_amdgcn_mfma_f32_16x16x32_bf16(alo[mf], bhi[nf], acc[mf][nf], 0,0,0);
      }
  }
  // reduce the 4 per-wave k-quarter partials of U[d32][q32] via LDS (alias Ps)
  __syncthreads();
  float* Ured = &Ps[0][0];           // 4608 floats available, 4096 needed
  {
    int lane = t & 63;
#pragma unroll
    for (int mf=0;mf<2;mf++)
#pragma unroll
      for (int nf=0;nf<2;nf++)
#pragma unroll
        for (int rg=0;rg<4;rg++)
          Ured[wv*1024 + (mf*2+nf)*256 + rg*64 + lane] = acc[mf][nf][rg];
  }
  __syncthreads();
#pragma unroll
  for (int i=0;i<4;i++){
    int s = i*256 + t;
    float u = Ured[s] + Ured[1024+s] + Ured[2048+s] + Ured[3072+s];
    int grp = s>>8, rg = (s>>6)&3, lane = s&63;
    int mf = grp>>1, nf = grp&1;
    int q = q0 + nf*16 + (lane&15);
    int d = mf*16 + (lane>>4)*4 + rg;
    if (q < NOUT) upd[((size_t)bh*NOUT + q)*HD + d] = u;
  }
}

// --------------------------------------------------------------------------
extern "C" void kernel_launch(void* const* d_in, const int* in_sizes, int n_in,
                              void* d_out, int out_size, void* d_ws, size_t ws_size,
                              hipStream_t stream){
  (void)in_sizes; (void)n_in; (void)out_size; (void)ws_size;
  const float* px    = (const float*)d_in[0];
  const float* pcw   = (const float*)d_in[1];
  const float* pcb   = (const float*)d_in[2];
  const float* pkvw  = (const float*)d_in[3];
  const float* pkvb  = (const float*)d_in[4];
  const float* pqw   = (const float*)d_in[5];
  const float* pqb   = (const float*)d_in[6];
  const float* pw1   = (const float*)d_in[7];
  const float* pb1   = (const float*)d_in[8];
  const float* pw2   = (const float*)d_in[9];
  const float* pb2   = (const float*)d_in[10];
  const float* pg1   = (const float*)d_in[11];
  const float* pbe1  = (const float*)d_in[12];
  const float* pg2   = (const float*)d_in[13];
  const float* pbe2  = (const float*)d_in[14];
  const float* pg3   = (const float*)d_in[15];
  const float* pbe3  = (const float*)d_in[16];
  const float* ptemp = (const float*)d_in[17];
  const float* prf   = (const float*)d_in[18];

  float* out = (float*)d_out;
  float* ws  = (float*)d_ws;

  float* xout   = ws + OXOUT;
  ushort* kb    = (ushort*)(ws + OKB);
  float* vhb    = ws + OVH;
  ushort* qb    = (ushort*)(ws + OQB);
  float* csinv  = ws + OCS;
  float* l0part = ws + OLP;
  float* updb   = ws + OUPD;
  float* h1     = ws + OH1;
  float* h2p    = ws + OH2;
  ushort* qwb   = (ushort*)(ws + OQWB);
  ushort* w1b   = (ushort*)(ws + OW1B);
  ushort* w2b   = (ushort*)(ws + OW2B);

  // d_out regions double as scratch until the attn outputs are written (it==2)
  float* attnq = out + 371712;
  float* attnk = out + 371712 + 47579136;
  float* cpart = attnq + 8388608;               // 49*968*384 f, dead after ln1
  ushort* wtb  = (ushort*)attnk;                // dead after conv
  ushort* xb16 = (ushort*)(attnk + 3612672);    // dead after kv gemm
  ushort* kvwb = (ushort*)(attnk + 3612672 + 1572864);  // dead after kv gemm

  // ---- packing (loop-invariant, single fused launch; includes qb pad-zero) ----
  packall<<<dim3(37674), 256, 0, stream>>>(px, xb16, pcw, wtb, pkvw, kvwb,
                                           pqw, qwb, pw1, w1b, pw2, w2b, qb);

  // ---- precompute (loop-invariant) ----
  convm<<<dim3(8,3,NSLICE), 256, 0, stream>>>(xb16, wtb, cpart);
  lnk<0,false><<<dim3(MOUT), 384, 0, stream>>>(cpart, pcb, pg1, pbe1, xout, nullptr);
  gemmkv<<<dim3(64,6), 256, 0, stream>>>(xb16, kvwb, pkvb, prf, ptemp, kb, vhb);

  // ---- 3 iterations ----
  for (int it=0; it<3; ++it){
    gemm64q<<<dim3(16,6), 256, 0, stream>>>(xout, qwb, pqb, prf, qb);
    rowk<<<dim3(8,16,24), 256, 0, stream>>>(qb, kb, l0part);
    colk_f<<<dim3(16,24), 256, 0, stream>>>(qb, kb, l0part, csinv);
    if (it==2){
      pv_f<true ><<<dim3(16,24), 256, 0, stream>>>(qb, kb, vhb, l0part, csinv, updb, attnq, attnk);
    } else {
      pv_f<false><<<dim3(16,24), 256, 0, stream>>>(qb, kb, vhb, l0part, csinv, updb, attnq, attnk);
    }
    lnk<1,false><<<dim3(MOUT), 384, 0, stream>>>(updb, pcb, pg2, pbe2, xout, nullptr);
    gemm64<1><<<dim3(16,24), 256, 0, stream>>>(xout, w1b, pb1, h1, MOUT, 1536, 384);
    gemm64sk<<<dim3(16,6,4), 256, 0, stream>>>(h1, w2b, h2p);
    if (it==2){
      lnk<3,true ><<<dim3(MOUT), 384, 0, stream>>>(h2p, pb2, pg3, pbe3, xout, out);
    } else {
      lnk<3,false><<<dim3(MOUT), 384, 0, stream>>>(h2p, pb2, pg3, pbe3, xout, nullptr);
    }
  }
}